// Round 3
// baseline (519.379 us; speedup 1.0000x reference)
//
#include <hip/hip_runtime.h>
#include <stdint.h>
#include <stddef.h>

typedef __bf16 bf16;
typedef __attribute__((ext_vector_type(8))) __bf16 bf16x8;
typedef __attribute__((ext_vector_type(4))) float floatx4;

#define GAS __attribute__((address_space(1)))
#define LAS __attribute__((address_space(3)))

__device__ __forceinline__ void async16(const void* g, void* l) {
  __builtin_amdgcn_global_load_lds((const GAS void*)g, (LAS void*)l, 16, 0, 0);
}

__device__ __forceinline__ bf16x8 cvt8(const float* p) {
  floatx4 a = *(const floatx4*)p;
  floatx4 b = *(const floatx4*)(p + 4);
  bf16x8 r;
  r[0] = (bf16)a[0]; r[1] = (bf16)a[1]; r[2] = (bf16)a[2]; r[3] = (bf16)a[3];
  r[4] = (bf16)b[0]; r[5] = (bf16)b[1]; r[6] = (bf16)b[2]; r[7] = (bf16)b[3];
  return r;
}

// ---------------------------------------------------------------------------
// 256x256 8-phase GEMM (HK-template port, learn_hip m194-m204 structure):
// C[M,N](bf16) = A[M,K](bf16) @ B[N,K](bf16)^T. 512 thr = 8 waves (2M x 4N).
// BK=64 in two K-halves of 32. LDS 128 KiB: [2 dbuf][2 kh][256 rows][32 k]
// per operand.
//
// SWIZZLE (round-2 fix): for a [256][32]-elem half-tile (64-B rows), bank
// position of a 16-B slot is (4*row + slot) mod 8. XOR slot with (row>>1)&3
// so 16 consecutive rows (the lr lanes) cover all 8 positions twice -> 2
// lanes/bank-group = free (m136). Applied on BOTH sides (rule #21): staging
// pre-swizzles the GLOBAL source k (LDS dest stays linear for
// global_load_lds), ds_read XORs the same bits. row bits 1-2 == lr bits 1-2
// (wm, m*16 are 16-aligned) and (srow+128)>>1 & 3 == (srow>>1)&3, so one
// formula serves both staging instrs and all m-indices.
//
// RACE-FREE stage rotation (round-1 fix): each phase stages ONLY the region
// whose last read ended in the previous phase.
//   PH1 reads B00,A00  stages A11(T1)    PH5 reads B10,A10  stages A01(T0+2)
//   PH2 reads A00      stages B00(T0+2)  PH6 reads A10      stages B10(T1+2)
//   PH3 reads B01,A01  stages A00(T0+2)  PH7 reads B11,A11  stages A10(T1+2)
//   PH4 reads A01      stages B01(T0+2)  PH8 reads A11      stages B11(T1+2)
// vmcnt(6) at PH4 drains {B10,A10,B11,A11} (read PH5-PH8); at PH8 drains
// {B00,A00,B01,A01} (read next-iter PH1-PH4). 3 half-tiles stay in flight.
// Requires M%256==0, N%256==0, K%128==0, gridDim.x == (M/256)*(N/256).
// ---------------------------------------------------------------------------
__global__ __launch_bounds__(512, 2) void gemm256_8p(
    const bf16* __restrict__ A, const bf16* __restrict__ B,
    bf16* __restrict__ C, int M, int N, int K, int lda, int ldb) {
  __shared__ __attribute__((aligned(16))) bf16 SA[2][2][8192];
  __shared__ __attribute__((aligned(16))) bf16 SB[2][2][8192];

  const int tid = threadIdx.x;
  const int wave = tid >> 6;
  const int lane = tid & 63;
  const int lr = lane & 15;
  const int kg = lane >> 4;
  const int wm = (wave >> 2) * 128;  // wave row-block (2)
  const int wn = (wave & 3) * 64;    // wave col-block (4)

  // XCD-aware mapping: blocks co-resident on an XCD share the A panel.
  const int tilesM = M >> 8;
  const int tm = blockIdx.x % tilesM;
  const int tn = blockIdx.x / tilesM;
  const int rowBase = tm * 256;
  const int colBase = tn * 256;

  // per-thread staging geometry: one global_load_lds = 512 thr x 16 B = 8 KB
  // = 128 rows x 32 k. Source k pre-swizzled (slot ^= (row>>1)&3) so linear
  // LDS dest ends up swizzled identically to the ds_read XOR.
  const int srow = tid >> 2;                 // 0..127 (+128 for 2nd instr)
  const int ske = (tid & 3) << 3;            // elem offset 0/8/16/24
  const int skel = ske ^ (((srow >> 1) & 3) << 3);
  const size_t aRow0 = (size_t)(rowBase + srow) * lda;
  const size_t aRow1 = aRow0 + (size_t)128 * lda;
  const size_t bRow0 = (size_t)(colBase + srow) * ldb;
  const size_t bRow1 = bRow0 + (size_t)128 * ldb;

  const int NT = K >> 6;  // K-tiles of 64

  // frag-read swizzled k offset (elements) within a [256][32] region
  const int keSh = (kg << 3) ^ (((lr >> 1) & 3) << 3);

  floatx4 acc[8][4] = {};

  auto stA = [&](int buf, int kh, int kt) {
    const int gk = kt * 64 + kh * 32 + skel;
    bf16* d = &SA[buf][kh][0];
    async16(A + aRow0 + gk, d + tid * 8);
    async16(A + aRow1 + gk, d + 4096 + tid * 8);
  };
  auto stB = [&](int buf, int kh, int kt) {
    const int gk = kt * 64 + kh * 32 + skel;
    bf16* d = &SB[buf][kh][0];
    async16(B + bRow0 + gk, d + tid * 8);
    async16(B + bRow1 + gk, d + 4096 + tid * 8);
  };

  // ---- prologue: tile0 complete (drained) + tile1 {B-k0, A-k0, B-k1} in
  // flight (A-k1 of tile1 staged at it=0 PH1 — matches steady state). ----
  stB(0, 0, 0); stA(0, 0, 0); stB(0, 1, 0); stA(0, 1, 0);
  stB(1, 0, 1); stA(1, 0, 1); stB(1, 1, 1);
  asm volatile("s_waitcnt vmcnt(6)" ::: "memory");
  __builtin_amdgcn_s_barrier();

  bf16x8 bg[4], af[4];

// Phase: [ds_read frags | stage 1 half-tile] -> barrier -> lgkmcnt(0) ->
//        setprio(1) 16xMFMA setprio(0) -> [vmcnt(6) at drain phases] -> barrier
#define PH(BUF, KH, MH, DOB, STG, VM)                                          \
  {                                                                            \
    const bf16* Ar_ = &SA[BUF][KH][0];                                         \
    if constexpr (DOB) {                                                       \
      const bf16* Br_ = &SB[BUF][KH][0];                                       \
      _Pragma("unroll") for (int n = 0; n < 4; ++n)                            \
          bg[n] = *(const bf16x8*)&Br_[(wn + n * 16 + lr) * 32 + keSh];        \
    }                                                                          \
    _Pragma("unroll") for (int m = 0; m < 4; ++m)                              \
        af[m] =                                                                \
            *(const bf16x8*)&Ar_[(wm + ((MH)*4 + m) * 16 + lr) * 32 + keSh];   \
    STG;                                                                       \
    __builtin_amdgcn_s_barrier();                                              \
    asm volatile("s_waitcnt lgkmcnt(0)" ::: "memory");                         \
    __builtin_amdgcn_sched_barrier(0);                                         \
    __builtin_amdgcn_s_setprio(1);                                             \
    _Pragma("unroll") for (int m = 0; m < 4; ++m)                              \
      _Pragma("unroll") for (int n = 0; n < 4; ++n)                            \
          acc[(MH)*4 + m][n] = __builtin_amdgcn_mfma_f32_16x16x32_bf16(        \
              af[m], bg[n], acc[(MH)*4 + m][n], 0, 0, 0);                      \
    __builtin_amdgcn_s_setprio(0);                                             \
    if constexpr (VM) asm volatile("s_waitcnt vmcnt(6)" ::: "memory");         \
    __builtin_amdgcn_s_barrier();                                              \
  }

  for (int it = 0; it < (NT >> 1); ++it) {
    const int T0 = it * 2;
    const int T1 = T0 + 1;
    // tail clamps: last-iter stages become idempotent rewrites / dead-region
    // writes, always landing after the region's final read.
    const int s1 = (T0 + 2 < NT) ? T0 + 2 : NT - 1;
    const int s2 = (T1 + 2 < NT) ? T1 + 2 : NT - 1;

    // ---- tile T0 (buf0) ----
    PH(0, 0, 0, true,  stA(1, 1, T1), false)  // stage A-k1(T1)   -> buf1
    PH(0, 0, 1, false, stB(0, 0, s1), false)  // stage B-k0(T0+2) -> buf0
    PH(0, 1, 0, true,  stA(0, 0, s1), false)  // stage A-k0(T0+2) -> buf0
    PH(0, 1, 1, false, stB(0, 1, s1), true)   // stage B-k1(T0+2) -> buf0
    // ---- tile T1 (buf1) ----
    PH(1, 0, 0, true,  stA(0, 1, s1), false)  // stage A-k1(T0+2) -> buf0
    PH(1, 0, 1, false, stB(1, 0, s2), false)  // stage B-k0(T1+2) -> buf1
    PH(1, 1, 0, true,  stA(1, 0, s2), false)  // stage A-k0(T1+2) -> buf1
    PH(1, 1, 1, false, stB(1, 1, s2), true)   // stage B-k1(T1+2) -> buf1
  }
#undef PH

  // drain outstanding LDS-DMA before LDS goes away / kernel end
  asm volatile("s_waitcnt vmcnt(0)" ::: "memory");

  // epilogue: C/D layout col = lane&15, row = (lane>>4)*4 + reg  [m89]
#pragma unroll
  for (int m = 0; m < 8; ++m) {
#pragma unroll
    for (int n = 0; n < 4; ++n) {
      const int col = colBase + wn + n * 16 + lr;
#pragma unroll
      for (int r = 0; r < 4; ++r) {
        const int row = rowBase + wm + m * 16 + kg * 4 + r;
        C[(size_t)row * N + col] = (bf16)acc[m][n][r];
      }
    }
  }
}

// ---------------------------------------------------------------------------
// Generic "bt" GEMM: C[M,N] = A[M,K_eff] @ B[N,K_eff]^T with row strides
// lda/ldb (elements). AF/BF: f32 operand (VGPR+cvt+ds_write staging) vs bf16
// (async global_load_lds). TM: 128 (4 waves 2x2 of 64x64) or 64 (4 waves 1x4
// of 64x32). BK=32, 256 thr, mfma_f32_16x16x32_bf16.
// EPI: 0 bf16 store | 1 f32 atomicAdd | 2 bf16 softplus(v+bias) |
//      3 f32 (v+bias) | 4 f32 store to per-z partial slab (split-K, no atomics)
// ---------------------------------------------------------------------------
template <int EPI, int AF, int BF, int TM>
__global__ __launch_bounds__(256, 4) void gemm_bt(
    const void* __restrict__ Aptr, const void* __restrict__ Bptr,
    void* __restrict__ Cout, const float* __restrict__ bias,
    int M, int N, int K, int lda, int ldb) {
  __shared__ bf16 As[TM * 32];
  __shared__ bf16 Bs[128 * 32];
  const int tid = threadIdx.x;

  const int rowBase = blockIdx.x * TM;
  const int colBase = blockIdx.y * 128;
  const int kLen = K / gridDim.z;
  const int k0 = blockIdx.z * kLen;
  const int kIters = kLen / 32;

  const int sRow = tid >> 2;
  const int sCol = (tid & 3) << 3;
  const int wave = tid >> 6;
  const int lane = tid & 63;
  constexpr int MI = 4;
  constexpr int NJ = (TM == 128) ? 4 : 2;
  const int wm = (TM == 128) ? ((wave >> 1) << 6) : 0;
  const int wn = (TM == 128) ? ((wave & 1) << 6) : (wave << 5);
  const int lr = lane & 15;
  const int kg = lane >> 4;

  floatx4 acc[MI][NJ] = {};

  for (int kt = 0; kt < kIters; ++kt) {
    const int kk = k0 + kt * 32;
    __syncthreads();  // prev iter's LDS reads done before overwrite
    if constexpr (AF) {
      const float* pa =
          (const float*)Aptr + (size_t)(rowBase + sRow) * lda + kk + sCol;
      *(bf16x8*)&As[tid * 8] = cvt8(pa);
      if constexpr (TM == 128)
        *(bf16x8*)&As[2048 + tid * 8] = cvt8(pa + (size_t)64 * lda);
    } else {
      const bf16* pa =
          (const bf16*)Aptr + (size_t)(rowBase + sRow) * lda + kk + sCol;
      async16(pa, &As[tid * 8]);
      if constexpr (TM == 128)
        async16(pa + (size_t)64 * lda, &As[2048 + tid * 8]);
    }
    if constexpr (BF) {
      const float* pb =
          (const float*)Bptr + (size_t)(colBase + sRow) * ldb + kk + sCol;
      *(bf16x8*)&Bs[tid * 8] = cvt8(pb);
      *(bf16x8*)&Bs[2048 + tid * 8] = cvt8(pb + (size_t)64 * ldb);
    } else {
      const bf16* pb =
          (const bf16*)Bptr + (size_t)(colBase + sRow) * ldb + kk + sCol;
      async16(pb, &Bs[tid * 8]);
      async16(pb + (size_t)64 * ldb, &Bs[2048 + tid * 8]);
    }
    __syncthreads();  // staging complete -> tile visible

    bf16x8 af[MI], bg[NJ];
#pragma unroll
    for (int i = 0; i < MI; ++i)
      af[i] = *(const bf16x8*)&As[(wm + i * 16 + lr) * 32 + kg * 8];
#pragma unroll
    for (int j = 0; j < NJ; ++j)
      bg[j] = *(const bf16x8*)&Bs[(wn + j * 16 + lr) * 32 + kg * 8];
#pragma unroll
    for (int i = 0; i < MI; ++i)
#pragma unroll
      for (int j = 0; j < NJ; ++j)
        acc[i][j] = __builtin_amdgcn_mfma_f32_16x16x32_bf16(af[i], bg[j],
                                                            acc[i][j], 0, 0, 0);
  }

  // epilogue: C/D layout col = lane&15, row = (lane>>4)*4 + reg  [m89]
#pragma unroll
  for (int i = 0; i < MI; ++i) {
#pragma unroll
    for (int j = 0; j < NJ; ++j) {
      const int col = colBase + wn + j * 16 + lr;
      float bv = 0.f;
      if constexpr (EPI == 2 || EPI == 3) bv = bias[col];
#pragma unroll
      for (int r = 0; r < 4; ++r) {
        const int row = rowBase + wm + i * 16 + kg * 4 + r;
        const size_t idx = (size_t)row * N + col;
        float v = acc[i][j][r];
        if constexpr (EPI == 0) {
          ((bf16*)Cout)[idx] = (bf16)v;
        } else if constexpr (EPI == 1) {
          atomicAdd((float*)Cout + idx, v);
        } else if constexpr (EPI == 2) {
          v += bv;
          // softplus = ln(1+e^v); for v>20, ln(1+e^v)==v to f32 precision.
          const float t = __expf(v);
          const float sp = (v > 20.f) ? v : __logf(1.f + t);
          ((bf16*)Cout)[idx] = (bf16)sp;
        } else if constexpr (EPI == 3) {
          ((float*)Cout)[idx] = v + bv;
        } else {
          // split-K partial: distinct slab per z, no contention
          ((float*)Cout)[(size_t)blockIdx.z * 524288 + idx] = v;
        }
      }
    }
  }
}

// sum 8 split-K partial slabs -> XDBL (2048x256 f32)
__global__ __launch_bounds__(256) void reduce_xdbl(
    const float* __restrict__ part, float* __restrict__ xdbl) {
  const size_t i4 = ((size_t)blockIdx.x * 256 + threadIdx.x) * 4;  // 524288/4
  floatx4 s = {};
#pragma unroll
  for (int z = 0; z < 8; ++z) {
    const floatx4 v = *(const floatx4*)&part[(size_t)z * 524288 + i4];
    s[0] += v[0]; s[1] += v[1]; s[2] += v[2]; s[3] += v[3];
  }
  *(floatx4*)&xdbl[i4] = s;
}

// ---------------------------------------------------------------------------
// Fused prep: f32->bf16 casts (hidden|W_in|W_dt|W_out) + W_x pad-cast.
// ---------------------------------------------------------------------------
#define PC0 524288UL    // hidden chunks
#define PC1 2621440UL   // +W_in
#define PC2 2686976UL   // +W_dt
#define PC3 3735552UL   // +W_out
#define PC4 3866624UL   // +WXPAD (dest 256x4096)
__global__ __launch_bounds__(256) void prep_all(
    const float* __restrict__ h, const float* __restrict__ wi,
    const float* __restrict__ wd, const float* __restrict__ wo,
    const float* __restrict__ wx, bf16* __restrict__ hb,
    bf16* __restrict__ wib, bf16* __restrict__ wdb, bf16* __restrict__ wob,
    bf16* __restrict__ wxp) {
  const size_t c = (size_t)blockIdx.x * 256 + threadIdx.x;
  if (c < PC0) {
    const size_t e = c * 8;
    *(bf16x8*)&hb[e] = cvt8(&h[e]);
  } else if (c < PC1) {
    const size_t e = (c - PC0) * 8;
    *(bf16x8*)&wib[e] = cvt8(&wi[e]);
  } else if (c < PC2) {
    const size_t e = (c - PC1) * 8;
    *(bf16x8*)&wdb[e] = cvt8(&wd[e]);
  } else if (c < PC3) {
    const size_t e = (c - PC2) * 8;
    *(bf16x8*)&wob[e] = cvt8(&wo[e]);
  } else if (c < PC4) {
    const size_t e = (c - PC3) * 8;
    if ((e >> 12) < 160) {
      *(bf16x8*)&wxp[e] = cvt8(&wx[e]);
    } else {
      bf16x8 z = {};
      *(bf16x8*)&wxp[e] = z;
    }
  }
}

// W_x pad (fallback path only)
__global__ void wxpad_prep(const float* __restrict__ Wx,
                           bf16* __restrict__ WXPAD) {
  const int idx = blockIdx.x * 256 + threadIdx.x;
  const int row = idx >> 12;
  WXPAD[idx] = (row < 160) ? (bf16)Wx[idx] : (bf16)0.f;
}

// Depthwise causal conv (K=4) + bias + SiLU; fused conv_state output.
__global__ void conv_kernel(const bf16* __restrict__ XZ,
                            const float* __restrict__ conv_w,
                            const float* __restrict__ conv_b,
                            bf16* __restrict__ XC,
                            float* __restrict__ outConv) {
  const int idx = blockIdx.x * 256 + threadIdx.x;  // 2048*4096
  const int d = idx & 4095;
  const int row = idx >> 12;
  const int l = row & 1023;
  float acc = conv_b[d];
#pragma unroll
  for (int k = 0; k < 4; ++k) {
    if (l - 3 + k >= 0)
      acc += conv_w[d * 4 + k] * (float)XZ[(size_t)(row - 3 + k) * 8192 + d];
  }
  const float s = acc / (1.f + __expf(-acc));
  XC[(size_t)row * 4096 + d] = (bf16)s;
  if (idx < 32768) {  // conv_state: out[b,dd,k] = x[b, 1020+k, dd]
    const int k = idx & 3;
    const int dd = (idx >> 2) & 4095;
    const int b = idx >> 14;
    outConv[idx] = (float)XZ[(size_t)(b * 1024 + 1020 + k) * 8192 + dd];
  }
}

// ---------------------------------------------------------------------------
// Chunked parallel scan (32 chunks of 32).
// ---------------------------------------------------------------------------
#define NCH 32
#define CLEN 32
#define LOG2E 1.44269504088896f

__global__ __launch_bounds__(256) void scan_phase1(
    const bf16* __restrict__ DELTA, const bf16* __restrict__ XC,
    const float* __restrict__ XDBL, const float* __restrict__ A_log,
    bf16* __restrict__ P, bf16* __restrict__ Lc) {
  const int bd = blockIdx.x * 256 + threadIdx.x;  // 0..8191
  const int c = blockIdx.y;
  const int b = bd >> 12;
  const int d = bd & 4095;
  float A2[16], st[16], p[16];
#pragma unroll
  for (int n = 0; n < 16; ++n) {
    A2[n] = -__expf(A_log[d * 16 + n]) * LOG2E;
    st[n] = 0.f;
    p[n] = 1.f;
  }
  size_t row = (size_t)b * 1024 + (size_t)c * CLEN;
  for (int t = 0; t < CLEN; ++t, ++row) {
    const float dlt = (float)DELTA[row * 4096 + d];
    const float u = (float)XC[row * 4096 + d];
    const float* __restrict__ Bp = XDBL + row * 256 + 128;  // wave-uniform
    const float du = dlt * u;
#pragma unroll
    for (int n = 0; n < 16; ++n) {
      const float dA = exp2f(dlt * A2[n]);
      st[n] = dA * st[n] + du * Bp[n];
      p[n] *= dA;
    }
  }
  const size_t o = ((size_t)c * 8192 + bd) * 16;
  bf16x8 pk[2], lk[2];
#pragma unroll
  for (int n = 0; n < 16; ++n) {
    pk[n >> 3][n & 7] = (bf16)p[n];
    lk[n >> 3][n & 7] = (bf16)st[n];
  }
  *(bf16x8*)&P[o] = pk[0];
  *(bf16x8*)&P[o + 8] = pk[1];
  *(bf16x8*)&Lc[o] = lk[0];
  *(bf16x8*)&Lc[o + 8] = lk[1];
}

__global__ __launch_bounds__(256) void scan_phase2(
    const bf16* __restrict__ P, const bf16* __restrict__ Lc,
    float* __restrict__ In, float* __restrict__ lastOut) {
  const int bd = blockIdx.x * 256 + threadIdx.x;  // 0..8191
  float st[16] = {};
  for (int c = 0; c < NCH; ++c) {
    const size_t o = ((size_t)c * 8192 + bd) * 16;
    const bf16x8 p0 = *(const bf16x8*)&P[o];
    const bf16x8 p1 = *(const bf16x8*)&P[o + 8];
    const bf16x8 l0 = *(const bf16x8*)&Lc[o];
    const bf16x8 l1 = *(const bf16x8*)&Lc[o + 8];
    floatx4 w[4];
#pragma unroll
    for (int n = 0; n < 16; ++n) w[n >> 2][n & 3] = st[n];
#pragma unroll
    for (int q = 0; q < 4; ++q) *(floatx4*)&In[o + q * 4] = w[q];
#pragma unroll
    for (int n = 0; n < 8; ++n) {
      st[n] = (float)p0[n] * st[n] + (float)l0[n];
      st[8 + n] = (float)p1[n] * st[8 + n] + (float)l1[n];
    }
  }
  const int b = bd >> 12;
  const int d = bd & 4095;
#pragma unroll
  for (int n = 0; n < 16; ++n)
    lastOut[(size_t)b * 65536 + d * 16 + n] = st[n];
}

__global__ __launch_bounds__(256) void scan_phase3(
    const bf16* __restrict__ DELTA, const bf16* __restrict__ XC,
    const bf16* __restrict__ XZ, const float* __restrict__ XDBL,
    const float* __restrict__ A_log, const float* __restrict__ Dp,
    const float* __restrict__ In, bf16* __restrict__ Y) {
  const int bd = blockIdx.x * 256 + threadIdx.x;
  const int c = blockIdx.y;
  const int b = bd >> 12;
  const int d = bd & 4095;
  float A2[16], st[16];
  const size_t o = ((size_t)c * 8192 + bd) * 16;
#pragma unroll
  for (int q = 0; q < 4; ++q) {
    const floatx4 v = *(const floatx4*)&In[o + q * 4];
#pragma unroll
    for (int j = 0; j < 4; ++j) st[q * 4 + j] = v[j];
  }
#pragma unroll
  for (int n = 0; n < 16; ++n)
    A2[n] = -__expf(A_log[d * 16 + n]) * LOG2E;
  const float Dd = Dp[d];
  size_t row = (size_t)b * 1024 + (size_t)c * CLEN;
  for (int t = 0; t < CLEN; ++t, ++row) {
    const float dlt = (float)DELTA[row * 4096 + d];
    const float u = (float)XC[row * 4096 + d];
    const float z = (float)XZ[row * 8192 + 4096 + d];
    const float* __restrict__ Bp = XDBL + row * 256 + 128;
    const float du = dlt * u;
    float y = 0.f;
#pragma unroll
    for (int n = 0; n < 16; ++n) {
      const float dA = exp2f(dlt * A2[n]);
      st[n] = dA * st[n] + du * Bp[n];
      y += st[n] * Bp[16 + n];
    }
    const float sig = 1.f / (1.f + __expf(-z));
    Y[row * 4096 + d] = (bf16)((y + Dd * u) * (z * sig));
  }
}

// ---------------------------------------------------------------------------
// Workspace layout (bytes). DELTA slot holds bf16 DELTA (lower 16.8 MB) and
// the GEMM2 split-K partials (upper 16.8 MB; 8 slabs x 2 MB) — partials are
// consumed by reduce_xdbl before DELTA is written.
// ---------------------------------------------------------------------------
#define OFF_XZ 0UL                 // bf16 2048x8192
#define OFF_XC 33554432UL          // bf16 2048x4096
#define OFF_DELTA 50331648UL       // bf16 2048x4096 | +16777216: PART f32 8x524288
#define OFF_Y 83886080UL           // bf16 2048x4096
#define OFF_XDBL 100663296UL       // f32  2048x256
#define OFF_WXPAD 103284736UL      // bf16 256x4096
#define OFF_P 105381888UL          // bf16 32x8192x16
#define OFF_L 113770496UL          // bf16 32x8192x16
#define OFF_HBF 122159104UL        // bf16 2048x2048
#define OFF_WINBF 130547712UL      // bf16 8192x2048
#define OFF_WDTBF 164102144UL      // bf16 4096x128
#define OFF_WOUTBF 165150720UL     // bf16 2048x4096
#define WS_NEED_CAST 181927936UL   // ~173.5 MB

extern "C" void kernel_launch(void* const* d_in, const int* in_sizes, int n_in,
                              void* d_out, int out_size, void* d_ws,
                              size_t ws_size, hipStream_t stream) {
  const float* hidden = (const float*)d_in[0];
  const float* W_in = (const float*)d_in[1];
  const float* conv_w = (const float*)d_in[2];
  const float* conv_b = (const float*)d_in[3];
  const float* W_x = (const float*)d_in[4];
  const float* W_dt = (const float*)d_in[5];
  const float* b_dt = (const float*)d_in[6];
  const float* A_log = (const float*)d_in[7];
  const float* Dvec = (const float*)d_in[8];
  const float* W_out = (const float*)d_in[9];
  const float* b_out = (const float*)d_in[10];

  char* ws = (char*)d_ws;
  bf16* XZ = (bf16*)(ws + OFF_XZ);
  bf16* XC = (bf16*)(ws + OFF_XC);
  bf16* DELTA = (bf16*)(ws + OFF_DELTA);
  float* PART = (float*)(ws + OFF_DELTA + 16777216UL);
  bf16* Y = (bf16*)(ws + OFF_Y);
  float* XDBL = (float*)(ws + OFF_XDBL);
  bf16* WXPAD = (bf16*)(ws + OFF_WXPAD);
  bf16* P = (bf16*)(ws + OFF_P);
  bf16* Lc = (bf16*)(ws + OFF_L);

  float* out = (float*)d_out;             // (2,1024,2048) = 4194304 f32
  float* out_conv = out + 4194304;        // (2,4096,4)
  float* out_last = out + 4227072;        // (2,4096,16)
  // In (f32, 16.78 MB) parks in the `out` region: written by phase2, read by
  // phase3, then fully overwritten by GEMM3 (same-stream ordering).
  float* In = out;

  const bool castOK = ws_size >= WS_NEED_CAST;
  if (castOK) {
    bf16* HBF = (bf16*)(ws + OFF_HBF);
    bf16* WINBF = (bf16*)(ws + OFF_WINBF);
    bf16* WDTBF = (bf16*)(ws + OFF_WDTBF);
    bf16* WOUTBF = (bf16*)(ws + OFF_WOUTBF);
    prep_all<<<15104, 256, 0, stream>>>(hidden, W_in, W_dt, W_out, W_x, HBF,
                                        WINBF, WDTBF, WOUTBF, WXPAD);
    // GEMM1: XZ = HBF @ WINBF^T — 8-phase 256^2 template, 256 WGs (1/CU)
    gemm256_8p<<<dim3(256), 512, 0, stream>>>(HBF, WINBF, XZ, 2048, 8192,
                                              2048, 2048, 2048);
    conv_kernel<<<32768, 256, 0, stream>>>(XZ, conv_w, conv_b, XC, out_conv);
    // GEMM2 (split-K=8 -> partial slabs, no atomics): PART[z] = XC @ WXPAD^T
    gemm_bt<4, 0, 0, 64><<<dim3(32, 2, 8), 256, 0, stream>>>(
        XC, WXPAD, PART, nullptr, 2048, 256, 4096, 4096, 4096);
    reduce_xdbl<<<512, 256, 0, stream>>>(PART, XDBL);
    // GEMM_dt (TM=64, A = XDBL dt-cols f32 lda=256): DELTA = softplus(.)
    gemm_bt<2, 1, 0, 64><<<dim3(32, 32, 1), 256, 0, stream>>>(
        XDBL, WDTBF, DELTA, b_dt, 2048, 4096, 128, 256, 128);
    scan_phase1<<<dim3(32, NCH), 256, 0, stream>>>(DELTA, XC, XDBL, A_log, P,
                                                   Lc);
    scan_phase2<<<32, 256, 0, stream>>>(P, Lc, In, out_last);
    scan_phase3<<<dim3(32, NCH), 256, 0, stream>>>(DELTA, XC, XZ, XDBL, A_log,
                                                   Dvec, In, Y);
    // GEMM3 (TM=64, grid 32x16 = 512 WGs -> 8 waves/CU; was TM=128 @ 256 WGs
    // = 1 wave/SIMD, latency-bound at 412 TF): out = Y @ WOUTBF^T + b_out
    gemm_bt<3, 0, 0, 64><<<dim3(32, 16, 1), 256, 0, stream>>>(
        Y, WOUTBF, out, b_out, 2048, 2048, 4096, 4096, 4096);
  } else {
    // fallback: f32-staged GEMMs, no cast buffers
    wxpad_prep<<<4096, 256, 0, stream>>>(W_x, WXPAD);
    gemm_bt<0, 1, 1, 128><<<dim3(16, 64, 1), 256, 0, stream>>>(
        hidden, W_in, XZ, nullptr, 2048, 8192, 2048, 2048, 2048);
    conv_kernel<<<32768, 256, 0, stream>>>(XZ, conv_w, conv_b, XC, out_conv);
    gemm_bt<4, 0, 0, 64><<<dim3(32, 2, 8), 256, 0, stream>>>(
        XC, WXPAD, PART, nullptr, 2048, 256, 4096, 4096, 4096);
    reduce_xdbl<<<512, 256, 0, stream>>>(PART, XDBL);
    gemm_bt<2, 1, 1, 64><<<dim3(32, 32, 1), 256, 0, stream>>>(
        XDBL, W_dt, DELTA, b_dt, 2048, 4096, 128, 256, 128);
    scan_phase1<<<dim3(32, NCH), 256, 0, stream>>>(DELTA, XC, XDBL, A_log, P,
                                                   Lc);
    scan_phase2<<<32, 256, 0, stream>>>(P, Lc, In, out_last);
    scan_phase3<<<dim3(32, NCH), 256, 0, stream>>>(DELTA, XC, XZ, XDBL, A_log,
                                                   Dvec, In, Y);
    gemm_bt<3, 0, 1, 64><<<dim3(32, 16, 1), 256, 0, stream>>>(
        Y, W_out, out, b_out, 2048, 2048, 4096, 4096, 4096);
  }
}

// Round 4
// 501.781 us; speedup vs baseline: 1.0351x; 1.0351x over previous
//
#include <hip/hip_runtime.h>
#include <stdint.h>
#include <stddef.h>

typedef __bf16 bf16;
typedef __attribute__((ext_vector_type(8))) __bf16 bf16x8;
typedef __attribute__((ext_vector_type(4))) float floatx4;

#define GAS __attribute__((address_space(1)))
#define LAS __attribute__((address_space(3)))

__device__ __forceinline__ void async16(const void* g, void* l) {
  __builtin_amdgcn_global_load_lds((const GAS void*)g, (LAS void*)l, 16, 0, 0);
}

__device__ __forceinline__ bf16x8 cvt8(const float* p) {
  floatx4 a = *(const floatx4*)p;
  floatx4 b = *(const floatx4*)(p + 4);
  bf16x8 r;
  r[0] = (bf16)a[0]; r[1] = (bf16)a[1]; r[2] = (bf16)a[2]; r[3] = (bf16)a[3];
  r[4] = (bf16)b[0]; r[5] = (bf16)b[1]; r[6] = (bf16)b[2]; r[7] = (bf16)b[3];
  return r;
}

// ---------------------------------------------------------------------------
// 256x256 8-phase GEMM, read-ahead pipelined (round-3 restructure):
// C[M,N](bf16) = A[M,K](bf16) @ B[N,K](bf16)^T. 512 thr = 8 waves (2M x 4N).
// BK=64 in two K-halves of 32. LDS 128 KiB: [2 dbuf][2 kh][256 rows][32 k].
// Swizzle (r2): slot ^= (row>>1)&3 on both stage-source and ds_read.
//
// READ-AHEAD (r3): fragment regs double-buffered (af0/af1, bgA/bgB). Phase p
// issues the ds_reads for phase p+1 and waits only lgkmcnt(c_p) (c_p = reads
// issued this phase; LDS returns in-order) before its MFMA — each read gets a
// full phase of latency cover instead of a serial lgkmcnt(0) burst-wait.
//   reads issued:  PH1:af1(A00m47)[4] PH2:bgB(B01)+af0(A01m03)[8]
//                  PH3:af1(A01m47)[4] PH4:bgA(B10)+af0(A10m03)[8]
//                  PH5:af1(A10m47)[4] PH6:bgB(B11)+af0(A11m03)[8]
//                  PH7:af1(A11m47)[4] PH8:bgA(B00')+af0(A00'm03)[8]
//   MFMA:          PH1:bgA*af0 MH0    PH2:bgA*af1 MH1   PH3:bgB*af0 MH0
//                  PH4:bgB*af1 MH1    PH5:bgA*af0 MH0   PH6:bgA*af1 MH1
//                  PH7:bgB*af0 MH0    PH8:bgB*af1 MH1
// Stage rotation (r1, unchanged): PH1:A11(T1) PH2:B00(+2) PH3:A00(+2)
//   PH4:B01(+2) PH5:A01(+2) PH6:B10(+2) PH7:A10(+2) PH8:B11(+2).
// vmcnt(8) at ends of PH1,3,5,7 — FIFO-verified: each drain releases exactly
// the two half-tiles whose reads are issued next phase (PH1-end: B01,A01;
// PH3-end: B10,A10; PH5-end: B11,A11; PH7-end: B00',A00'), >=4 phases of DMA
// flight. Every stage targets a region whose reads completed (lgkm+barrier)
// in an earlier phase — ledger verified region-by-region incl. it=0 and tail.
// Requires M%256==0, N%256==0, K%128==0, gridDim.x == (M/256)*(N/256).
// ---------------------------------------------------------------------------
__global__ __launch_bounds__(512, 2) void gemm256_8p(
    const bf16* __restrict__ A, const bf16* __restrict__ B,
    bf16* __restrict__ C, int M, int N, int K, int lda, int ldb) {
  __shared__ __attribute__((aligned(16))) bf16 SA[2][2][8192];
  __shared__ __attribute__((aligned(16))) bf16 SB[2][2][8192];

  const int tid = threadIdx.x;
  const int wave = tid >> 6;
  const int lane = tid & 63;
  const int lr = lane & 15;
  const int kg = lane >> 4;
  const int wm = (wave >> 2) * 128;  // wave row-block (2)
  const int wn = (wave & 3) * 64;    // wave col-block (4)

  // XCD-aware mapping: blocks co-resident on an XCD share the A panel.
  const int tilesM = M >> 8;
  const int tm = blockIdx.x % tilesM;
  const int tn = blockIdx.x / tilesM;
  const int rowBase = tm * 256;
  const int colBase = tn * 256;

  // staging geometry: one global_load_lds = 512 thr x 16 B = 8 KB = 128 rows
  // x 32 k; source k pre-swizzled so linear LDS dest matches ds_read XOR.
  const int srow = tid >> 2;
  const int ske = (tid & 3) << 3;
  const int skel = ske ^ (((srow >> 1) & 3) << 3);
  const size_t aRow0 = (size_t)(rowBase + srow) * lda;
  const size_t aRow1 = aRow0 + (size_t)128 * lda;
  const size_t bRow0 = (size_t)(colBase + srow) * ldb;
  const size_t bRow1 = bRow0 + (size_t)128 * ldb;

  const int NT = K >> 6;  // K-tiles of 64

  // frag-read swizzled k offset within a [256][32] region
  const int keSh = (kg << 3) ^ (((lr >> 1) & 3) << 3);

  floatx4 acc[8][4] = {};
  bf16x8 af0[4], af1[4], bgA[4], bgB[4];

  auto stA = [&](int buf, int kh, int kt) {
    const int gk = kt * 64 + kh * 32 + skel;
    bf16* d = &SA[buf][kh][0];
    async16(A + aRow0 + gk, d + tid * 8);
    async16(A + aRow1 + gk, d + 4096 + tid * 8);
  };
  auto stB = [&](int buf, int kh, int kt) {
    const int gk = kt * 64 + kh * 32 + skel;
    bf16* d = &SB[buf][kh][0];
    async16(B + bRow0 + gk, d + tid * 8);
    async16(B + bRow1 + gk, d + 4096 + tid * 8);
  };

#define RD_B(DST, BUF, KH)                                                     \
  _Pragma("unroll") for (int n = 0; n < 4; ++n)                                \
      DST[n] = *(const bf16x8*)&SB[BUF][KH][(wn + n * 16 + lr) * 32 + keSh];
#define RD_A(DST, BUF, KH, MH)                                                 \
  _Pragma("unroll") for (int m = 0; m < 4; ++m)                                \
      DST[m] =                                                                 \
          *(const bf16x8*)&SA[BUF][KH][(wm + ((MH)*4 + m) * 16 + lr) * 32 +    \
                                       keSh];

  // ---- prologue: tile0 landed; tile1 {B10,A10,B11} in flight; PH1 operands
  // (bgA=B00, af0=A00m03) pre-read. ----
  stB(0, 0, 0); stA(0, 0, 0); stB(0, 1, 0); stA(0, 1, 0);
  asm volatile("s_waitcnt vmcnt(0)" ::: "memory");
  __builtin_amdgcn_s_barrier();
  stB(1, 0, 1); stA(1, 0, 1); stB(1, 1, 1);
  RD_B(bgA, 0, 0);
  RD_A(af0, 0, 0, 0);

// Phase: [issue reads for p+1 | stage 1 half-tile] -> barrier ->
//   lgkmcnt(c_p) (prev phase's reads done, this phase's may fly) ->
//   setprio(1) 16xMFMA setprio(0) -> [vmcnt(8) at odd phases] -> barrier
#define PH(RDS, CNT, STG, BGR, AFR, MH, VM)                                    \
  {                                                                            \
    RDS;                                                                       \
    STG;                                                                       \
    __builtin_amdgcn_s_barrier();                                              \
    asm volatile("s_waitcnt lgkmcnt(" #CNT ")" ::: "memory");                  \
    __builtin_amdgcn_sched_barrier(0);                                         \
    __builtin_amdgcn_s_setprio(1);                                             \
    _Pragma("unroll") for (int m = 0; m < 4; ++m)                              \
      _Pragma("unroll") for (int n = 0; n < 4; ++n)                            \
          acc[(MH)*4 + m][n] = __builtin_amdgcn_mfma_f32_16x16x32_bf16(        \
              AFR[m], BGR[n], acc[(MH)*4 + m][n], 0, 0, 0);                    \
    __builtin_amdgcn_s_setprio(0);                                             \
    __builtin_amdgcn_sched_barrier(0);                                         \
    if constexpr (VM) asm volatile("s_waitcnt vmcnt(8)" ::: "memory");         \
    __builtin_amdgcn_s_barrier();                                              \
  }

  for (int it = 0; it < (NT >> 1); ++it) {
    const int T0 = it * 2;
    const int T1 = T0 + 1;
    // tail clamps: stages become idempotent rewrites landing after last reads
    const int s1 = (T0 + 2 < NT) ? T0 + 2 : NT - 1;
    const int s2 = (T1 + 2 < NT) ? T1 + 2 : NT - 1;

    PH(RD_A(af1, 0, 0, 1), 4, stA(1, 1, T1), bgA, af0, 0, true)   // PH1
    PH(RD_B(bgB, 0, 1); RD_A(af0, 0, 1, 0), 8, stB(0, 0, s1), bgA, af1, 1,
       false)                                                      // PH2
    PH(RD_A(af1, 0, 1, 1), 4, stA(0, 0, s1), bgB, af0, 0, true)   // PH3
    PH(RD_B(bgA, 1, 0); RD_A(af0, 1, 0, 0), 8, stB(0, 1, s1), bgB, af1, 1,
       false)                                                      // PH4
    PH(RD_A(af1, 1, 0, 1), 4, stA(0, 1, s1), bgA, af0, 0, true)   // PH5
    PH(RD_B(bgB, 1, 1); RD_A(af0, 1, 1, 0), 8, stB(1, 0, s2), bgA, af1, 1,
       false)                                                      // PH6
    PH(RD_A(af1, 1, 1, 1), 4, stA(1, 0, s2), bgB, af0, 0, true)   // PH7
    PH(RD_B(bgA, 0, 0); RD_A(af0, 0, 0, 0), 8, stB(1, 1, s2), bgB, af1, 1,
       false)                                                      // PH8
  }
#undef PH
#undef RD_A
#undef RD_B

  // drain outstanding LDS-DMA and dangling tail ds_reads
  asm volatile("s_waitcnt vmcnt(0) lgkmcnt(0)" ::: "memory");

  // epilogue: C/D layout col = lane&15, row = (lane>>4)*4 + reg  [m89]
#pragma unroll
  for (int m = 0; m < 8; ++m) {
#pragma unroll
    for (int n = 0; n < 4; ++n) {
      const int col = colBase + wn + n * 16 + lr;
#pragma unroll
      for (int r = 0; r < 4; ++r) {
        const int row = rowBase + wm + m * 16 + kg * 4 + r;
        C[(size_t)row * N + col] = (bf16)acc[m][n][r];
      }
    }
  }
}

// ---------------------------------------------------------------------------
// Generic "bt" GEMM: C[M,N] = A[M,K_eff] @ B[N,K_eff]^T with row strides
// lda/ldb (elements). AF/BF: f32 operand (VGPR+cvt+ds_write staging) vs bf16
// (async global_load_lds). TM: 128 (4 waves 2x2 of 64x64) or 64 (4 waves 1x4
// of 64x32). BK=32, 256 thr, mfma_f32_16x16x32_bf16.
// EPI: 0 bf16 store | 1 f32 atomicAdd | 2 bf16 softplus(v+bias) |
//      3 f32 (v+bias) | 4 f32 store to per-z partial slab (split-K, no atomics)
// ---------------------------------------------------------------------------
template <int EPI, int AF, int BF, int TM>
__global__ __launch_bounds__(256, 4) void gemm_bt(
    const void* __restrict__ Aptr, const void* __restrict__ Bptr,
    void* __restrict__ Cout, const float* __restrict__ bias,
    int M, int N, int K, int lda, int ldb) {
  __shared__ bf16 As[TM * 32];
  __shared__ bf16 Bs[128 * 32];
  const int tid = threadIdx.x;

  const int rowBase = blockIdx.x * TM;
  const int colBase = blockIdx.y * 128;
  const int kLen = K / gridDim.z;
  const int k0 = blockIdx.z * kLen;
  const int kIters = kLen / 32;

  const int sRow = tid >> 2;
  const int sCol = (tid & 3) << 3;
  const int wave = tid >> 6;
  const int lane = tid & 63;
  constexpr int MI = 4;
  constexpr int NJ = (TM == 128) ? 4 : 2;
  const int wm = (TM == 128) ? ((wave >> 1) << 6) : 0;
  const int wn = (TM == 128) ? ((wave & 1) << 6) : (wave << 5);
  const int lr = lane & 15;
  const int kg = lane >> 4;

  floatx4 acc[MI][NJ] = {};

  for (int kt = 0; kt < kIters; ++kt) {
    const int kk = k0 + kt * 32;
    __syncthreads();  // prev iter's LDS reads done before overwrite
    if constexpr (AF) {
      const float* pa =
          (const float*)Aptr + (size_t)(rowBase + sRow) * lda + kk + sCol;
      *(bf16x8*)&As[tid * 8] = cvt8(pa);
      if constexpr (TM == 128)
        *(bf16x8*)&As[2048 + tid * 8] = cvt8(pa + (size_t)64 * lda);
    } else {
      const bf16* pa =
          (const bf16*)Aptr + (size_t)(rowBase + sRow) * lda + kk + sCol;
      async16(pa, &As[tid * 8]);
      if constexpr (TM == 128)
        async16(pa + (size_t)64 * lda, &As[2048 + tid * 8]);
    }
    if constexpr (BF) {
      const float* pb =
          (const float*)Bptr + (size_t)(colBase + sRow) * ldb + kk + sCol;
      *(bf16x8*)&Bs[tid * 8] = cvt8(pb);
      *(bf16x8*)&Bs[2048 + tid * 8] = cvt8(pb + (size_t)64 * ldb);
    } else {
      const bf16* pb =
          (const bf16*)Bptr + (size_t)(colBase + sRow) * ldb + kk + sCol;
      async16(pb, &Bs[tid * 8]);
      async16(pb + (size_t)64 * ldb, &Bs[2048 + tid * 8]);
    }
    __syncthreads();  // staging complete -> tile visible

    bf16x8 af[MI], bg[NJ];
#pragma unroll
    for (int i = 0; i < MI; ++i)
      af[i] = *(const bf16x8*)&As[(wm + i * 16 + lr) * 32 + kg * 8];
#pragma unroll
    for (int j = 0; j < NJ; ++j)
      bg[j] = *(const bf16x8*)&Bs[(wn + j * 16 + lr) * 32 + kg * 8];
#pragma unroll
    for (int i = 0; i < MI; ++i)
#pragma unroll
      for (int j = 0; j < NJ; ++j)
        acc[i][j] = __builtin_amdgcn_mfma_f32_16x16x32_bf16(af[i], bg[j],
                                                            acc[i][j], 0, 0, 0);
  }

  // epilogue: C/D layout col = lane&15, row = (lane>>4)*4 + reg  [m89]
#pragma unroll
  for (int i = 0; i < MI; ++i) {
#pragma unroll
    for (int j = 0; j < NJ; ++j) {
      const int col = colBase + wn + j * 16 + lr;
      float bv = 0.f;
      if constexpr (EPI == 2 || EPI == 3) bv = bias[col];
#pragma unroll
      for (int r = 0; r < 4; ++r) {
        const int row = rowBase + wm + i * 16 + kg * 4 + r;
        const size_t idx = (size_t)row * N + col;
        float v = acc[i][j][r];
        if constexpr (EPI == 0) {
          ((bf16*)Cout)[idx] = (bf16)v;
        } else if constexpr (EPI == 1) {
          atomicAdd((float*)Cout + idx, v);
        } else if constexpr (EPI == 2) {
          v += bv;
          // softplus = ln(1+e^v); for v>20, ln(1+e^v)==v to f32 precision.
          const float t = __expf(v);
          const float sp = (v > 20.f) ? v : __logf(1.f + t);
          ((bf16*)Cout)[idx] = (bf16)sp;
        } else if constexpr (EPI == 3) {
          ((float*)Cout)[idx] = v + bv;
        } else {
          // split-K partial: distinct slab per z, no contention
          ((float*)Cout)[(size_t)blockIdx.z * 524288 + idx] = v;
        }
      }
    }
  }
}

// sum 8 split-K partial slabs -> XDBL (2048x256 f32)
__global__ __launch_bounds__(256) void reduce_xdbl(
    const float* __restrict__ part, float* __restrict__ xdbl) {
  const size_t i4 = ((size_t)blockIdx.x * 256 + threadIdx.x) * 4;  // 524288/4
  floatx4 s = {};
#pragma unroll
  for (int z = 0; z < 8; ++z) {
    const floatx4 v = *(const floatx4*)&part[(size_t)z * 524288 + i4];
    s[0] += v[0]; s[1] += v[1]; s[2] += v[2]; s[3] += v[3];
  }
  *(floatx4*)&xdbl[i4] = s;
}

// ---------------------------------------------------------------------------
// Fused prep: f32->bf16 casts (hidden|W_in|W_dt|W_out) + W_x pad-cast.
// ---------------------------------------------------------------------------
#define PC0 524288UL    // hidden chunks
#define PC1 2621440UL   // +W_in
#define PC2 2686976UL   // +W_dt
#define PC3 3735552UL   // +W_out
#define PC4 3866624UL   // +WXPAD (dest 256x4096)
__global__ __launch_bounds__(256) void prep_all(
    const float* __restrict__ h, const float* __restrict__ wi,
    const float* __restrict__ wd, const float* __restrict__ wo,
    const float* __restrict__ wx, bf16* __restrict__ hb,
    bf16* __restrict__ wib, bf16* __restrict__ wdb, bf16* __restrict__ wob,
    bf16* __restrict__ wxp) {
  const size_t c = (size_t)blockIdx.x * 256 + threadIdx.x;
  if (c < PC0) {
    const size_t e = c * 8;
    *(bf16x8*)&hb[e] = cvt8(&h[e]);
  } else if (c < PC1) {
    const size_t e = (c - PC0) * 8;
    *(bf16x8*)&wib[e] = cvt8(&wi[e]);
  } else if (c < PC2) {
    const size_t e = (c - PC1) * 8;
    *(bf16x8*)&wdb[e] = cvt8(&wd[e]);
  } else if (c < PC3) {
    const size_t e = (c - PC2) * 8;
    *(bf16x8*)&wob[e] = cvt8(&wo[e]);
  } else if (c < PC4) {
    const size_t e = (c - PC3) * 8;
    if ((e >> 12) < 160) {
      *(bf16x8*)&wxp[e] = cvt8(&wx[e]);
    } else {
      bf16x8 z = {};
      *(bf16x8*)&wxp[e] = z;
    }
  }
}

// W_x pad (fallback path only)
__global__ void wxpad_prep(const float* __restrict__ Wx,
                           bf16* __restrict__ WXPAD) {
  const int idx = blockIdx.x * 256 + threadIdx.x;
  const int row = idx >> 12;
  WXPAD[idx] = (row < 160) ? (bf16)Wx[idx] : (bf16)0.f;
}

// Depthwise causal conv (K=4) + bias + SiLU; fused conv_state output.
__global__ void conv_kernel(const bf16* __restrict__ XZ,
                            const float* __restrict__ conv_w,
                            const float* __restrict__ conv_b,
                            bf16* __restrict__ XC,
                            float* __restrict__ outConv) {
  const int idx = blockIdx.x * 256 + threadIdx.x;  // 2048*4096
  const int d = idx & 4095;
  const int row = idx >> 12;
  const int l = row & 1023;
  float acc = conv_b[d];
#pragma unroll
  for (int k = 0; k < 4; ++k) {
    if (l - 3 + k >= 0)
      acc += conv_w[d * 4 + k] * (float)XZ[(size_t)(row - 3 + k) * 8192 + d];
  }
  const float s = acc / (1.f + __expf(-acc));
  XC[(size_t)row * 4096 + d] = (bf16)s;
  if (idx < 32768) {  // conv_state: out[b,dd,k] = x[b, 1020+k, dd]
    const int k = idx & 3;
    const int dd = (idx >> 2) & 4095;
    const int b = idx >> 14;
    outConv[idx] = (float)XZ[(size_t)(b * 1024 + 1020 + k) * 8192 + dd];
  }
}

// ---------------------------------------------------------------------------
// Chunked parallel scan (32 chunks of 32).
// ---------------------------------------------------------------------------
#define NCH 32
#define CLEN 32
#define LOG2E 1.44269504088896f

__global__ __launch_bounds__(256) void scan_phase1(
    const bf16* __restrict__ DELTA, const bf16* __restrict__ XC,
    const float* __restrict__ XDBL, const float* __restrict__ A_log,
    bf16* __restrict__ P, bf16* __restrict__ Lc) {
  const int bd = blockIdx.x * 256 + threadIdx.x;  // 0..8191
  const int c = blockIdx.y;
  const int b = bd >> 12;
  const int d = bd & 4095;
  float A2[16], st[16], p[16];
#pragma unroll
  for (int n = 0; n < 16; ++n) {
    A2[n] = -__expf(A_log[d * 16 + n]) * LOG2E;
    st[n] = 0.f;
    p[n] = 1.f;
  }
  size_t row = (size_t)b * 1024 + (size_t)c * CLEN;
  for (int t = 0; t < CLEN; ++t, ++row) {
    const float dlt = (float)DELTA[row * 4096 + d];
    const float u = (float)XC[row * 4096 + d];
    const float* __restrict__ Bp = XDBL + row * 256 + 128;  // wave-uniform
    const float du = dlt * u;
#pragma unroll
    for (int n = 0; n < 16; ++n) {
      const float dA = exp2f(dlt * A2[n]);
      st[n] = dA * st[n] + du * Bp[n];
      p[n] *= dA;
    }
  }
  const size_t o = ((size_t)c * 8192 + bd) * 16;
  bf16x8 pk[2], lk[2];
#pragma unroll
  for (int n = 0; n < 16; ++n) {
    pk[n >> 3][n & 7] = (bf16)p[n];
    lk[n >> 3][n & 7] = (bf16)st[n];
  }
  *(bf16x8*)&P[o] = pk[0];
  *(bf16x8*)&P[o + 8] = pk[1];
  *(bf16x8*)&Lc[o] = lk[0];
  *(bf16x8*)&Lc[o + 8] = lk[1];
}

__global__ __launch_bounds__(64) void scan_phase2(
    const bf16* __restrict__ P, const bf16* __restrict__ Lc,
    float* __restrict__ In, float* __restrict__ lastOut) {
  // 128 blocks x 64 thr (was 32x256): 4x the CUs for this latency-bound,
  // serial-over-chunks kernel.
  const int bd = blockIdx.x * 64 + threadIdx.x;  // 0..8191
  float st[16] = {};
  for (int c = 0; c < NCH; ++c) {
    const size_t o = ((size_t)c * 8192 + bd) * 16;
    const bf16x8 p0 = *(const bf16x8*)&P[o];
    const bf16x8 p1 = *(const bf16x8*)&P[o + 8];
    const bf16x8 l0 = *(const bf16x8*)&Lc[o];
    const bf16x8 l1 = *(const bf16x8*)&Lc[o + 8];
    floatx4 w[4];
#pragma unroll
    for (int n = 0; n < 16; ++n) w[n >> 2][n & 3] = st[n];
#pragma unroll
    for (int q = 0; q < 4; ++q) *(floatx4*)&In[o + q * 4] = w[q];
#pragma unroll
    for (int n = 0; n < 8; ++n) {
      st[n] = (float)p0[n] * st[n] + (float)l0[n];
      st[8 + n] = (float)p1[n] * st[8 + n] + (float)l1[n];
    }
  }
  const int b = bd >> 12;
  const int d = bd & 4095;
#pragma unroll
  for (int n = 0; n < 16; ++n)
    lastOut[(size_t)b * 65536 + d * 16 + n] = st[n];
}

__global__ __launch_bounds__(256) void scan_phase3(
    const bf16* __restrict__ DELTA, const bf16* __restrict__ XC,
    const bf16* __restrict__ XZ, const float* __restrict__ XDBL,
    const float* __restrict__ A_log, const float* __restrict__ Dp,
    const float* __restrict__ In, bf16* __restrict__ Y) {
  const int bd = blockIdx.x * 256 + threadIdx.x;
  const int c = blockIdx.y;
  const int b = bd >> 12;
  const int d = bd & 4095;
  float A2[16], st[16];
  const size_t o = ((size_t)c * 8192 + bd) * 16;
#pragma unroll
  for (int q = 0; q < 4; ++q) {
    const floatx4 v = *(const floatx4*)&In[o + q * 4];
#pragma unroll
    for (int j = 0; j < 4; ++j) st[q * 4 + j] = v[j];
  }
#pragma unroll
  for (int n = 0; n < 16; ++n)
    A2[n] = -__expf(A_log[d * 16 + n]) * LOG2E;
  const float Dd = Dp[d];
  size_t row = (size_t)b * 1024 + (size_t)c * CLEN;
  for (int t = 0; t < CLEN; ++t, ++row) {
    const float dlt = (float)DELTA[row * 4096 + d];
    const float u = (float)XC[row * 4096 + d];
    const float z = (float)XZ[row * 8192 + 4096 + d];
    const float* __restrict__ Bp = XDBL + row * 256 + 128;
    const float du = dlt * u;
    float y = 0.f;
#pragma unroll
    for (int n = 0; n < 16; ++n) {
      const float dA = exp2f(dlt * A2[n]);
      st[n] = dA * st[n] + du * Bp[n];
      y += st[n] * Bp[16 + n];
    }
    const float sig = 1.f / (1.f + __expf(-z));
    Y[row * 4096 + d] = (bf16)((y + Dd * u) * (z * sig));
  }
}

// ---------------------------------------------------------------------------
// Workspace layout (bytes). DELTA slot holds bf16 DELTA (lower 16.8 MB) and
// the GEMM2 split-K partials (upper 16.8 MB; 8 slabs x 2 MB) — partials are
// consumed by reduce_xdbl before DELTA is written.
// ---------------------------------------------------------------------------
#define OFF_XZ 0UL                 // bf16 2048x8192
#define OFF_XC 33554432UL          // bf16 2048x4096
#define OFF_DELTA 50331648UL       // bf16 2048x4096 | +16777216: PART f32 8x524288
#define OFF_Y 83886080UL           // bf16 2048x4096
#define OFF_XDBL 100663296UL       // f32  2048x256
#define OFF_WXPAD 103284736UL      // bf16 256x4096
#define OFF_P 105381888UL          // bf16 32x8192x16
#define OFF_L 113770496UL          // bf16 32x8192x16
#define OFF_HBF 122159104UL        // bf16 2048x2048
#define OFF_WINBF 130547712UL      // bf16 8192x2048
#define OFF_WDTBF 164102144UL      // bf16 4096x128
#define OFF_WOUTBF 165150720UL     // bf16 2048x4096
#define WS_NEED_CAST 181927936UL   // ~173.5 MB

extern "C" void kernel_launch(void* const* d_in, const int* in_sizes, int n_in,
                              void* d_out, int out_size, void* d_ws,
                              size_t ws_size, hipStream_t stream) {
  const float* hidden = (const float*)d_in[0];
  const float* W_in = (const float*)d_in[1];
  const float* conv_w = (const float*)d_in[2];
  const float* conv_b = (const float*)d_in[3];
  const float* W_x = (const float*)d_in[4];
  const float* W_dt = (const float*)d_in[5];
  const float* b_dt = (const float*)d_in[6];
  const float* A_log = (const float*)d_in[7];
  const float* Dvec = (const float*)d_in[8];
  const float* W_out = (const float*)d_in[9];
  const float* b_out = (const float*)d_in[10];

  char* ws = (char*)d_ws;
  bf16* XZ = (bf16*)(ws + OFF_XZ);
  bf16* XC = (bf16*)(ws + OFF_XC);
  bf16* DELTA = (bf16*)(ws + OFF_DELTA);
  float* PART = (float*)(ws + OFF_DELTA + 16777216UL);
  bf16* Y = (bf16*)(ws + OFF_Y);
  float* XDBL = (float*)(ws + OFF_XDBL);
  bf16* WXPAD = (bf16*)(ws + OFF_WXPAD);
  bf16* P = (bf16*)(ws + OFF_P);
  bf16* Lc = (bf16*)(ws + OFF_L);

  float* out = (float*)d_out;             // (2,1024,2048) = 4194304 f32
  float* out_conv = out + 4194304;        // (2,4096,4)
  float* out_last = out + 4227072;        // (2,4096,16)
  // In (f32, 16.78 MB) parks in the `out` region: written by phase2, read by
  // phase3, then fully overwritten by GEMM3 (same-stream ordering).
  float* In = out;

  const bool castOK = ws_size >= WS_NEED_CAST;
  if (castOK) {
    bf16* HBF = (bf16*)(ws + OFF_HBF);
    bf16* WINBF = (bf16*)(ws + OFF_WINBF);
    bf16* WDTBF = (bf16*)(ws + OFF_WDTBF);
    bf16* WOUTBF = (bf16*)(ws + OFF_WOUTBF);
    prep_all<<<15104, 256, 0, stream>>>(hidden, W_in, W_dt, W_out, W_x, HBF,
                                        WINBF, WDTBF, WOUTBF, WXPAD);
    // GEMM1: XZ = HBF @ WINBF^T — 8-phase 256^2 template, 256 WGs (1/CU)
    gemm256_8p<<<dim3(256), 512, 0, stream>>>(HBF, WINBF, XZ, 2048, 8192,
                                              2048, 2048, 2048);
    conv_kernel<<<32768, 256, 0, stream>>>(XZ, conv_w, conv_b, XC, out_conv);
    // GEMM2 (split-K=8 -> partial slabs, no atomics): PART[z] = XC @ WXPAD^T
    gemm_bt<4, 0, 0, 64><<<dim3(32, 2, 8), 256, 0, stream>>>(
        XC, WXPAD, PART, nullptr, 2048, 256, 4096, 4096, 4096);
    reduce_xdbl<<<512, 256, 0, stream>>>(PART, XDBL);
    // GEMM_dt (TM=64, A = XDBL dt-cols f32 lda=256): DELTA = softplus(.)
    gemm_bt<2, 1, 0, 64><<<dim3(32, 32, 1), 256, 0, stream>>>(
        XDBL, WDTBF, DELTA, b_dt, 2048, 4096, 128, 256, 128);
    scan_phase1<<<dim3(32, NCH), 256, 0, stream>>>(DELTA, XC, XDBL, A_log, P,
                                                   Lc);
    scan_phase2<<<128, 64, 0, stream>>>(P, Lc, In, out_last);
    scan_phase3<<<dim3(32, NCH), 256, 0, stream>>>(DELTA, XC, XZ, XDBL, A_log,
                                                   Dvec, In, Y);
    // GEMM3 (TM=64, grid 32x16 = 512 WGs -> 8 waves/CU): out = Y @ W^T + b
    gemm_bt<3, 0, 0, 64><<<dim3(32, 16, 1), 256, 0, stream>>>(
        Y, WOUTBF, out, b_out, 2048, 2048, 4096, 4096, 4096);
  } else {
    // fallback: f32-staged GEMMs, no cast buffers
    wxpad_prep<<<4096, 256, 0, stream>>>(W_x, WXPAD);
    gemm_bt<0, 1, 1, 128><<<dim3(16, 64, 1), 256, 0, stream>>>(
        hidden, W_in, XZ, nullptr, 2048, 8192, 2048, 2048, 2048);
    conv_kernel<<<32768, 256, 0, stream>>>(XZ, conv_w, conv_b, XC, out_conv);
    gemm_bt<4, 0, 0, 64><<<dim3(32, 2, 8), 256, 0, stream>>>(
        XC, WXPAD, PART, nullptr, 2048, 256, 4096, 4096, 4096);
    reduce_xdbl<<<512, 256, 0, stream>>>(PART, XDBL);
    gemm_bt<2, 1, 1, 64><<<dim3(32, 32, 1), 256, 0, stream>>>(
        XDBL, W_dt, DELTA, b_dt, 2048, 4096, 128, 256, 128);
    scan_phase1<<<dim3(32, NCH), 256, 0, stream>>>(DELTA, XC, XDBL, A_log, P,
                                                   Lc);
    scan_phase2<<<128, 64, 0, stream>>>(P, Lc, In, out_last);
    scan_phase3<<<dim3(32, NCH), 256, 0, stream>>>(DELTA, XC, XZ, XDBL, A_log,
                                                   Dvec, In, Y);
    gemm_bt<3, 0, 1, 64><<<dim3(32, 16, 1), 256, 0, stream>>>(
        Y, W_out, out, b_out, 2048, 2048, 4096, 4096, 4096);
  }
}

// Round 5
// 492.190 us; speedup vs baseline: 1.0552x; 1.0195x over previous
//
#include <hip/hip_runtime.h>
#include <stdint.h>
#include <stddef.h>

typedef __bf16 bf16;
typedef __attribute__((ext_vector_type(8))) __bf16 bf16x8;
typedef __attribute__((ext_vector_type(4))) float floatx4;

#define GAS __attribute__((address_space(1)))
#define LAS __attribute__((address_space(3)))

__device__ __forceinline__ void async16(const void* g, void* l) {
  __builtin_amdgcn_global_load_lds((const GAS void*)g, (LAS void*)l, 16, 0, 0);
}

__device__ __forceinline__ bf16x8 cvt8(const float* p) {
  floatx4 a = *(const floatx4*)p;
  floatx4 b = *(const floatx4*)(p + 4);
  bf16x8 r;
  r[0] = (bf16)a[0]; r[1] = (bf16)a[1]; r[2] = (bf16)a[2]; r[3] = (bf16)a[3];
  r[4] = (bf16)b[0]; r[5] = (bf16)b[1]; r[6] = (bf16)b[2]; r[7] = (bf16)b[3];
  return r;
}

// ---------------------------------------------------------------------------
// 256x256 8-phase GEMM, read-ahead pipelined (r3) + 2-drain vmcnt (r5):
// C[M,N](bf16) = A[M,K](bf16) @ B[N,K](bf16)^T. 512 thr = 8 waves (2M x 4N).
// BK=64 in two K-halves of 32. LDS 128 KiB: [2 dbuf][2 kh][256 rows][32 k].
// Swizzle (r2): slot ^= (row>>1)&3 on both stage-source and ds_read.
//
// READ-AHEAD (r3): frag regs double-buffered; phase p issues ds_reads for
// p+1, waits lgkmcnt(c_p) before its MFMA (LDS in-order per wave).
// Stage rotation (r1): PH1:A11(T1) PH2:B00(+2) PH3:A00(+2) PH4:B01(+2)
//   PH5:A01(+2) PH6:B10(+2) PH7:A10(+2) PH8:B11(+2).
// Ledger invariant: every region's last ds_read ISSUE is in phase q, serviced
// by q+1's lgkmcnt; its re-stage is at q+2 (after barrier2(q+1) ⟹ all waves'
// reads serviced). Verified for all 8 regions.
//
// 2-DRAIN (r5): vmcnt(2) at PH4-end and PH8-end only (was 4x vmcnt(8)).
//   end-PH4 leaves only PH4's stage outstanding ⟹ everything through PH3
//   landed: covers reads of PH5(A10@PH7'),PH6(B11@PH8',A11@PH1),PH7(A11),
//   PH8(B00@PH2,A00@PH3). end-PH8 symmetric for next-iter PH1-PH4.
//   it=0: prologue stages all 7 half-tiles + vmcnt(0)+barrier (full drain),
//   so PH4's B10/A10 reads are covered without a pre-PH4 drain.
// Requires M%256==0, N%256==0, K%128==0, gridDim.x == (M/256)*(N/256).
// ---------------------------------------------------------------------------
__global__ __launch_bounds__(512, 2) void gemm256_8p(
    const bf16* __restrict__ A, const bf16* __restrict__ B,
    bf16* __restrict__ C, int M, int N, int K, int lda, int ldb) {
  __shared__ __attribute__((aligned(16))) bf16 SA[2][2][8192];
  __shared__ __attribute__((aligned(16))) bf16 SB[2][2][8192];

  const int tid = threadIdx.x;
  const int wave = tid >> 6;
  const int lane = tid & 63;
  const int lr = lane & 15;
  const int kg = lane >> 4;
  const int wm = (wave >> 2) * 128;  // wave row-block (2)
  const int wn = (wave & 3) * 64;    // wave col-block (4)

  // XCD-aware mapping: blocks co-resident on an XCD share the A panel.
  const int tilesM = M >> 8;
  const int tm = blockIdx.x % tilesM;
  const int tn = blockIdx.x / tilesM;
  const int rowBase = tm * 256;
  const int colBase = tn * 256;

  // staging geometry: one global_load_lds = 512 thr x 16 B = 8 KB = 128 rows
  // x 32 k; source k pre-swizzled so linear LDS dest matches ds_read XOR.
  const int srow = tid >> 2;
  const int ske = (tid & 3) << 3;
  const int skel = ske ^ (((srow >> 1) & 3) << 3);
  const size_t aRow0 = (size_t)(rowBase + srow) * lda;
  const size_t aRow1 = aRow0 + (size_t)128 * lda;
  const size_t bRow0 = (size_t)(colBase + srow) * ldb;
  const size_t bRow1 = bRow0 + (size_t)128 * ldb;

  const int NT = K >> 6;  // K-tiles of 64

  // frag-read swizzled k offset within a [256][32] region
  const int keSh = (kg << 3) ^ (((lr >> 1) & 3) << 3);

  floatx4 acc[8][4] = {};
  bf16x8 af0[4], af1[4], bgA[4], bgB[4];

  auto stA = [&](int buf, int kh, int kt) {
    const int gk = kt * 64 + kh * 32 + skel;
    bf16* d = &SA[buf][kh][0];
    async16(A + aRow0 + gk, d + tid * 8);
    async16(A + aRow1 + gk, d + 4096 + tid * 8);
  };
  auto stB = [&](int buf, int kh, int kt) {
    const int gk = kt * 64 + kh * 32 + skel;
    bf16* d = &SB[buf][kh][0];
    async16(B + bRow0 + gk, d + tid * 8);
    async16(B + bRow1 + gk, d + 4096 + tid * 8);
  };

#define RD_B(DST, BUF, KH)                                                     \
  _Pragma("unroll") for (int n = 0; n < 4; ++n)                                \
      DST[n] = *(const bf16x8*)&SB[BUF][KH][(wn + n * 16 + lr) * 32 + keSh];
#define RD_A(DST, BUF, KH, MH)                                                 \
  _Pragma("unroll") for (int m = 0; m < 4; ++m)                                \
      DST[m] =                                                                 \
          *(const bf16x8*)&SA[BUF][KH][(wm + ((MH)*4 + m) * 16 + lr) * 32 +    \
                                       keSh];

  // ---- prologue (r5): stage all 7 half-tiles, FULL drain, then pre-read
  // PH1 operands. A11(T1) is staged at it=0 PH1 (matches steady state). ----
  stB(0, 0, 0); stA(0, 0, 0); stB(0, 1, 0); stA(0, 1, 0);
  stB(1, 0, 1); stA(1, 0, 1); stB(1, 1, 1);
  asm volatile("s_waitcnt vmcnt(0)" ::: "memory");
  __builtin_amdgcn_s_barrier();
  RD_B(bgA, 0, 0);
  RD_A(af0, 0, 0, 0);

// Phase: [issue reads for p+1 | stage 1 half-tile] -> barrier ->
//   lgkmcnt(c_p) (prev phase's reads done, this phase's may fly) ->
//   setprio(1) 16xMFMA setprio(0) -> [vmcnt(2) at PH4/PH8] -> barrier
#define PH(RDS, CNT, STG, BGR, AFR, MH, VM)                                    \
  {                                                                            \
    RDS;                                                                       \
    STG;                                                                       \
    __builtin_amdgcn_s_barrier();                                              \
    asm volatile("s_waitcnt lgkmcnt(" #CNT ")" ::: "memory");                  \
    __builtin_amdgcn_sched_barrier(0);                                         \
    __builtin_amdgcn_s_setprio(1);                                             \
    _Pragma("unroll") for (int m = 0; m < 4; ++m)                              \
      _Pragma("unroll") for (int n = 0; n < 4; ++n)                            \
          acc[(MH)*4 + m][n] = __builtin_amdgcn_mfma_f32_16x16x32_bf16(        \
              AFR[m], BGR[n], acc[(MH)*4 + m][n], 0, 0, 0);                    \
    __builtin_amdgcn_s_setprio(0);                                             \
    __builtin_amdgcn_sched_barrier(0);                                         \
    if constexpr (VM) asm volatile("s_waitcnt vmcnt(2)" ::: "memory");         \
    __builtin_amdgcn_s_barrier();                                              \
  }

  for (int it = 0; it < (NT >> 1); ++it) {
    const int T0 = it * 2;
    const int T1 = T0 + 1;
    // tail clamps: stages become idempotent rewrites landing after last reads
    const int s1 = (T0 + 2 < NT) ? T0 + 2 : NT - 1;
    const int s2 = (T1 + 2 < NT) ? T1 + 2 : NT - 1;

    PH(RD_A(af1, 0, 0, 1), 4, stA(1, 1, T1), bgA, af0, 0, false)  // PH1
    PH(RD_B(bgB, 0, 1); RD_A(af0, 0, 1, 0), 8, stB(0, 0, s1), bgA, af1, 1,
       false)                                                      // PH2
    PH(RD_A(af1, 0, 1, 1), 4, stA(0, 0, s1), bgB, af0, 0, false)  // PH3
    PH(RD_B(bgA, 1, 0); RD_A(af0, 1, 0, 0), 8, stB(0, 1, s1), bgB, af1, 1,
       true)                                                       // PH4
    PH(RD_A(af1, 1, 0, 1), 4, stA(0, 1, s1), bgA, af0, 0, false)  // PH5
    PH(RD_B(bgB, 1, 1); RD_A(af0, 1, 1, 0), 8, stB(1, 0, s2), bgA, af1, 1,
       false)                                                      // PH6
    PH(RD_A(af1, 1, 1, 1), 4, stA(1, 0, s2), bgB, af0, 0, false)  // PH7
    PH(RD_B(bgA, 0, 0); RD_A(af0, 0, 0, 0), 8, stB(1, 1, s2), bgB, af1, 1,
       true)                                                       // PH8
  }
#undef PH
#undef RD_A
#undef RD_B

  // drain outstanding LDS-DMA and dangling tail ds_reads
  asm volatile("s_waitcnt vmcnt(0) lgkmcnt(0)" ::: "memory");

  // epilogue: C/D layout col = lane&15, row = (lane>>4)*4 + reg  [m89]
#pragma unroll
  for (int m = 0; m < 8; ++m) {
#pragma unroll
    for (int n = 0; n < 4; ++n) {
      const int col = colBase + wn + n * 16 + lr;
#pragma unroll
      for (int r = 0; r < 4; ++r) {
        const int row = rowBase + wm + m * 16 + kg * 4 + r;
        C[(size_t)row * N + col] = (bf16)acc[m][n][r];
      }
    }
  }
}

// ---------------------------------------------------------------------------
// Generic "bt" GEMM: C[M,N] = A[M,K_eff] @ B[N,K_eff]^T with row strides
// lda/ldb (elements). AF/BF: f32 operand (VGPR+cvt+ds_write staging) vs bf16
// (async global_load_lds). TM: 128 (4 waves 2x2 of 64x64) or 64 (4 waves 1x4
// of 64x32). BK=32, 256 thr, mfma_f32_16x16x32_bf16.
// EPI: 0 bf16 store | 1 f32 atomicAdd | 2 bf16 softplus(v+bias) |
//      3 f32 (v+bias) | 4 f32 per-z slab stride 524288 (GEMM2 split-K) |
//      5 f32 per-z slab stride 4194304 (GEMM3 split-K)
// ---------------------------------------------------------------------------
template <int EPI, int AF, int BF, int TM>
__global__ __launch_bounds__(256, 4) void gemm_bt(
    const void* __restrict__ Aptr, const void* __restrict__ Bptr,
    void* __restrict__ Cout, const float* __restrict__ bias,
    int M, int N, int K, int lda, int ldb) {
  __shared__ bf16 As[TM * 32];
  __shared__ bf16 Bs[128 * 32];
  const int tid = threadIdx.x;

  const int rowBase = blockIdx.x * TM;
  const int colBase = blockIdx.y * 128;
  const int kLen = K / gridDim.z;
  const int k0 = blockIdx.z * kLen;
  const int kIters = kLen / 32;

  const int sRow = tid >> 2;
  const int sCol = (tid & 3) << 3;
  const int wave = tid >> 6;
  const int lane = tid & 63;
  constexpr int MI = 4;
  constexpr int NJ = (TM == 128) ? 4 : 2;
  const int wm = (TM == 128) ? ((wave >> 1) << 6) : 0;
  const int wn = (TM == 128) ? ((wave & 1) << 6) : (wave << 5);
  const int lr = lane & 15;
  const int kg = lane >> 4;

  floatx4 acc[MI][NJ] = {};

  for (int kt = 0; kt < kIters; ++kt) {
    const int kk = k0 + kt * 32;
    __syncthreads();  // prev iter's LDS reads done before overwrite
    if constexpr (AF) {
      const float* pa =
          (const float*)Aptr + (size_t)(rowBase + sRow) * lda + kk + sCol;
      *(bf16x8*)&As[tid * 8] = cvt8(pa);
      if constexpr (TM == 128)
        *(bf16x8*)&As[2048 + tid * 8] = cvt8(pa + (size_t)64 * lda);
    } else {
      const bf16* pa =
          (const bf16*)Aptr + (size_t)(rowBase + sRow) * lda + kk + sCol;
      async16(pa, &As[tid * 8]);
      if constexpr (TM == 128)
        async16(pa + (size_t)64 * lda, &As[2048 + tid * 8]);
    }
    if constexpr (BF) {
      const float* pb =
          (const float*)Bptr + (size_t)(colBase + sRow) * ldb + kk + sCol;
      *(bf16x8*)&Bs[tid * 8] = cvt8(pb);
      *(bf16x8*)&Bs[2048 + tid * 8] = cvt8(pb + (size_t)64 * ldb);
    } else {
      const bf16* pb =
          (const bf16*)Bptr + (size_t)(colBase + sRow) * ldb + kk + sCol;
      async16(pb, &Bs[tid * 8]);
      async16(pb + (size_t)64 * ldb, &Bs[2048 + tid * 8]);
    }
    __syncthreads();  // staging complete -> tile visible

    bf16x8 af[MI], bg[NJ];
#pragma unroll
    for (int i = 0; i < MI; ++i)
      af[i] = *(const bf16x8*)&As[(wm + i * 16 + lr) * 32 + kg * 8];
#pragma unroll
    for (int j = 0; j < NJ; ++j)
      bg[j] = *(const bf16x8*)&Bs[(wn + j * 16 + lr) * 32 + kg * 8];
#pragma unroll
    for (int i = 0; i < MI; ++i)
#pragma unroll
      for (int j = 0; j < NJ; ++j)
        acc[i][j] = __builtin_amdgcn_mfma_f32_16x16x32_bf16(af[i], bg[j],
                                                            acc[i][j], 0, 0, 0);
  }

  // epilogue: C/D layout col = lane&15, row = (lane>>4)*4 + reg  [m89]
#pragma unroll
  for (int i = 0; i < MI; ++i) {
#pragma unroll
    for (int j = 0; j < NJ; ++j) {
      const int col = colBase + wn + j * 16 + lr;
      float bv = 0.f;
      if constexpr (EPI == 2 || EPI == 3) bv = bias[col];
#pragma unroll
      for (int r = 0; r < 4; ++r) {
        const int row = rowBase + wm + i * 16 + kg * 4 + r;
        const size_t idx = (size_t)row * N + col;
        float v = acc[i][j][r];
        if constexpr (EPI == 0) {
          ((bf16*)Cout)[idx] = (bf16)v;
        } else if constexpr (EPI == 1) {
          atomicAdd((float*)Cout + idx, v);
        } else if constexpr (EPI == 2) {
          v += bv;
          // softplus = ln(1+e^v); for v>20, ln(1+e^v)==v to f32 precision.
          const float t = __expf(v);
          const float sp = (v > 20.f) ? v : __logf(1.f + t);
          ((bf16*)Cout)[idx] = (bf16)sp;
        } else if constexpr (EPI == 3) {
          ((float*)Cout)[idx] = v + bv;
        } else if constexpr (EPI == 4) {
          // split-K partial: distinct slab per z, no contention
          ((float*)Cout)[(size_t)blockIdx.z * 524288 + idx] = v;
        } else {
          ((float*)Cout)[(size_t)blockIdx.z * 4194304 + idx] = v;
        }
      }
    }
  }
}

// sum 8 split-K partial slabs -> XDBL (2048x256 f32)
__global__ __launch_bounds__(256) void reduce_xdbl(
    const float* __restrict__ part, float* __restrict__ xdbl) {
  const size_t i4 = ((size_t)blockIdx.x * 256 + threadIdx.x) * 4;  // 524288/4
  floatx4 s = {};
#pragma unroll
  for (int z = 0; z < 8; ++z) {
    const floatx4 v = *(const floatx4*)&part[(size_t)z * 524288 + i4];
    s[0] += v[0]; s[1] += v[1]; s[2] += v[2]; s[3] += v[3];
  }
  *(floatx4*)&xdbl[i4] = s;
}

// sum 2 GEMM3 split-K slabs + bias -> out (2048x2048 f32)
__global__ __launch_bounds__(256) void reduce_out(
    const float* __restrict__ part, const float* __restrict__ bias,
    float* __restrict__ outp) {
  const size_t i4 = ((size_t)blockIdx.x * 256 + threadIdx.x) * 4;  // 4194304/4
  const floatx4 a = *(const floatx4*)&part[i4];
  const floatx4 b = *(const floatx4*)&part[4194304 + i4];
  const floatx4 bv = *(const floatx4*)&bias[i4 & 2047];
  floatx4 s;
  s[0] = a[0] + b[0] + bv[0];
  s[1] = a[1] + b[1] + bv[1];
  s[2] = a[2] + b[2] + bv[2];
  s[3] = a[3] + b[3] + bv[3];
  *(floatx4*)&outp[i4] = s;
}

// ---------------------------------------------------------------------------
// Fused prep: f32->bf16 casts (hidden|W_in|W_dt|W_out) + W_x pad-cast.
// ---------------------------------------------------------------------------
#define PC0 524288UL    // hidden chunks
#define PC1 2621440UL   // +W_in
#define PC2 2686976UL   // +W_dt
#define PC3 3735552UL   // +W_out
#define PC4 3866624UL   // +WXPAD (dest 256x4096)
__global__ __launch_bounds__(256) void prep_all(
    const float* __restrict__ h, const float* __restrict__ wi,
    const float* __restrict__ wd, const float* __restrict__ wo,
    const float* __restrict__ wx, bf16* __restrict__ hb,
    bf16* __restrict__ wib, bf16* __restrict__ wdb, bf16* __restrict__ wob,
    bf16* __restrict__ wxp) {
  const size_t c = (size_t)blockIdx.x * 256 + threadIdx.x;
  if (c < PC0) {
    const size_t e = c * 8;
    *(bf16x8*)&hb[e] = cvt8(&h[e]);
  } else if (c < PC1) {
    const size_t e = (c - PC0) * 8;
    *(bf16x8*)&wib[e] = cvt8(&wi[e]);
  } else if (c < PC2) {
    const size_t e = (c - PC1) * 8;
    *(bf16x8*)&wdb[e] = cvt8(&wd[e]);
  } else if (c < PC3) {
    const size_t e = (c - PC2) * 8;
    *(bf16x8*)&wob[e] = cvt8(&wo[e]);
  } else if (c < PC4) {
    const size_t e = (c - PC3) * 8;
    if ((e >> 12) < 160) {
      *(bf16x8*)&wxp[e] = cvt8(&wx[e]);
    } else {
      bf16x8 z = {};
      *(bf16x8*)&wxp[e] = z;
    }
  }
}

// W_x pad (fallback path only)
__global__ void wxpad_prep(const float* __restrict__ Wx,
                           bf16* __restrict__ WXPAD) {
  const int idx = blockIdx.x * 256 + threadIdx.x;
  const int row = idx >> 12;
  WXPAD[idx] = (row < 160) ? (bf16)Wx[idx] : (bf16)0.f;
}

// Depthwise causal conv (K=4) + bias + SiLU; fused conv_state output.
__global__ void conv_kernel(const bf16* __restrict__ XZ,
                            const float* __restrict__ conv_w,
                            const float* __restrict__ conv_b,
                            bf16* __restrict__ XC,
                            float* __restrict__ outConv) {
  const int idx = blockIdx.x * 256 + threadIdx.x;  // 2048*4096
  const int d = idx & 4095;
  const int row = idx >> 12;
  const int l = row & 1023;
  float acc = conv_b[d];
#pragma unroll
  for (int k = 0; k < 4; ++k) {
    if (l - 3 + k >= 0)
      acc += conv_w[d * 4 + k] * (float)XZ[(size_t)(row - 3 + k) * 8192 + d];
  }
  const float s = acc / (1.f + __expf(-acc));
  XC[(size_t)row * 4096 + d] = (bf16)s;
  if (idx < 32768) {  // conv_state: out[b,dd,k] = x[b, 1020+k, dd]
    const int k = idx & 3;
    const int dd = (idx >> 2) & 4095;
    const int b = idx >> 14;
    outConv[idx] = (float)XZ[(size_t)(b * 1024 + 1020 + k) * 8192 + dd];
  }
}

// ---------------------------------------------------------------------------
// Chunked parallel scan (32 chunks of 32).
// ---------------------------------------------------------------------------
#define NCH 32
#define CLEN 32
#define LOG2E 1.44269504088896f

__global__ __launch_bounds__(256) void scan_phase1(
    const bf16* __restrict__ DELTA, const bf16* __restrict__ XC,
    const float* __restrict__ XDBL, const float* __restrict__ A_log,
    bf16* __restrict__ P, bf16* __restrict__ Lc) {
  const int bd = blockIdx.x * 256 + threadIdx.x;  // 0..8191
  const int c = blockIdx.y;
  const int b = bd >> 12;
  const int d = bd & 4095;
  float A2[16], st[16], p[16];
#pragma unroll
  for (int n = 0; n < 16; ++n) {
    A2[n] = -__expf(A_log[d * 16 + n]) * LOG2E;
    st[n] = 0.f;
    p[n] = 1.f;
  }
  size_t row = (size_t)b * 1024 + (size_t)c * CLEN;
  for (int t = 0; t < CLEN; ++t, ++row) {
    const float dlt = (float)DELTA[row * 4096 + d];
    const float u = (float)XC[row * 4096 + d];
    const float* __restrict__ Bp = XDBL + row * 256 + 128;  // wave-uniform
    const float du = dlt * u;
#pragma unroll
    for (int n = 0; n < 16; ++n) {
      const float dA = exp2f(dlt * A2[n]);
      st[n] = dA * st[n] + du * Bp[n];
      p[n] *= dA;
    }
  }
  const size_t o = ((size_t)c * 8192 + bd) * 16;
  bf16x8 pk[2], lk[2];
#pragma unroll
  for (int n = 0; n < 16; ++n) {
    pk[n >> 3][n & 7] = (bf16)p[n];
    lk[n >> 3][n & 7] = (bf16)st[n];
  }
  *(bf16x8*)&P[o] = pk[0];
  *(bf16x8*)&P[o + 8] = pk[1];
  *(bf16x8*)&Lc[o] = lk[0];
  *(bf16x8*)&Lc[o + 8] = lk[1];
}

__global__ __launch_bounds__(64) void scan_phase2(
    const bf16* __restrict__ P, const bf16* __restrict__ Lc,
    float* __restrict__ In, float* __restrict__ lastOut) {
  // 128 blocks x 64 thr: 4x the CUs for this latency-bound serial kernel.
  const int bd = blockIdx.x * 64 + threadIdx.x;  // 0..8191
  float st[16] = {};
  for (int c = 0; c < NCH; ++c) {
    const size_t o = ((size_t)c * 8192 + bd) * 16;
    const bf16x8 p0 = *(const bf16x8*)&P[o];
    const bf16x8 p1 = *(const bf16x8*)&P[o + 8];
    const bf16x8 l0 = *(const bf16x8*)&Lc[o];
    const bf16x8 l1 = *(const bf16x8*)&Lc[o + 8];
    floatx4 w[4];
#pragma unroll
    for (int n = 0; n < 16; ++n) w[n >> 2][n & 3] = st[n];
#pragma unroll
    for (int q = 0; q < 4; ++q) *(floatx4*)&In[o + q * 4] = w[q];
#pragma unroll
    for (int n = 0; n < 8; ++n) {
      st[n] = (float)p0[n] * st[n] + (float)l0[n];
      st[8 + n] = (float)p1[n] * st[8 + n] + (float)l1[n];
    }
  }
  const int b = bd >> 12;
  const int d = bd & 4095;
#pragma unroll
  for (int n = 0; n < 16; ++n)
    lastOut[(size_t)b * 65536 + d * 16 + n] = st[n];
}

__global__ __launch_bounds__(256) void scan_phase3(
    const bf16* __restrict__ DELTA, const bf16* __restrict__ XC,
    const bf16* __restrict__ XZ, const float* __restrict__ XDBL,
    const float* __restrict__ A_log, const float* __restrict__ Dp,
    const float* __restrict__ In, bf16* __restrict__ Y) {
  const int bd = blockIdx.x * 256 + threadIdx.x;
  const int c = blockIdx.y;
  const int b = bd >> 12;
  const int d = bd & 4095;
  float A2[16], st[16];
  const size_t o = ((size_t)c * 8192 + bd) * 16;
#pragma unroll
  for (int q = 0; q < 4; ++q) {
    const floatx4 v = *(const floatx4*)&In[o + q * 4];
#pragma unroll
    for (int j = 0; j < 4; ++j) st[q * 4 + j] = v[j];
  }
#pragma unroll
  for (int n = 0; n < 16; ++n)
    A2[n] = -__expf(A_log[d * 16 + n]) * LOG2E;
  const float Dd = Dp[d];
  size_t row = (size_t)b * 1024 + (size_t)c * CLEN;
  for (int t = 0; t < CLEN; ++t, ++row) {
    const float dlt = (float)DELTA[row * 4096 + d];
    const float u = (float)XC[row * 4096 + d];
    const float z = (float)XZ[row * 8192 + 4096 + d];
    const float* __restrict__ Bp = XDBL + row * 256 + 128;
    const float du = dlt * u;
    float y = 0.f;
#pragma unroll
    for (int n = 0; n < 16; ++n) {
      const float dA = exp2f(dlt * A2[n]);
      st[n] = dA * st[n] + du * Bp[n];
      y += st[n] * Bp[16 + n];
    }
    const float sig = 1.f / (1.f + __expf(-z));
    Y[row * 4096 + d] = (bf16)((y + Dd * u) * (z * sig));
  }
}

// ---------------------------------------------------------------------------
// Workspace layout (bytes). DELTA slot holds bf16 DELTA (lower 16.8 MB) and
// the GEMM2 split-K partials (upper 16.8 MB); after scan_phase3 the full
// 33.5 MB DELTA+PART region is dead and is reused as GEMM3's 2 split-K slabs.
// ---------------------------------------------------------------------------
#define OFF_XZ 0UL                 // bf16 2048x8192
#define OFF_XC 33554432UL          // bf16 2048x4096
#define OFF_DELTA 50331648UL       // bf16 2048x4096 | +16777216: PART f32 8x524288
#define OFF_Y 83886080UL           // bf16 2048x4096
#define OFF_XDBL 100663296UL       // f32  2048x256
#define OFF_WXPAD 103284736UL      // bf16 256x4096
#define OFF_P 105381888UL          // bf16 32x8192x16
#define OFF_L 113770496UL          // bf16 32x8192x16
#define OFF_HBF 122159104UL        // bf16 2048x2048
#define OFF_WINBF 130547712UL      // bf16 8192x2048
#define OFF_WDTBF 164102144UL      // bf16 4096x128
#define OFF_WOUTBF 165150720UL     // bf16 2048x4096
#define WS_NEED_CAST 181927936UL   // ~173.5 MB

extern "C" void kernel_launch(void* const* d_in, const int* in_sizes, int n_in,
                              void* d_out, int out_size, void* d_ws,
                              size_t ws_size, hipStream_t stream) {
  const float* hidden = (const float*)d_in[0];
  const float* W_in = (const float*)d_in[1];
  const float* conv_w = (const float*)d_in[2];
  const float* conv_b = (const float*)d_in[3];
  const float* W_x = (const float*)d_in[4];
  const float* W_dt = (const float*)d_in[5];
  const float* b_dt = (const float*)d_in[6];
  const float* A_log = (const float*)d_in[7];
  const float* Dvec = (const float*)d_in[8];
  const float* W_out = (const float*)d_in[9];
  const float* b_out = (const float*)d_in[10];

  char* ws = (char*)d_ws;
  bf16* XZ = (bf16*)(ws + OFF_XZ);
  bf16* XC = (bf16*)(ws + OFF_XC);
  bf16* DELTA = (bf16*)(ws + OFF_DELTA);
  float* PART = (float*)(ws + OFF_DELTA + 16777216UL);
  float* SLAB3 = (float*)(ws + OFF_DELTA);  // 33.5 MB, dead after scan3
  bf16* Y = (bf16*)(ws + OFF_Y);
  float* XDBL = (float*)(ws + OFF_XDBL);
  bf16* WXPAD = (bf16*)(ws + OFF_WXPAD);
  bf16* P = (bf16*)(ws + OFF_P);
  bf16* Lc = (bf16*)(ws + OFF_L);

  float* out = (float*)d_out;             // (2,1024,2048) = 4194304 f32
  float* out_conv = out + 4194304;        // (2,4096,4)
  float* out_last = out + 4227072;        // (2,4096,16)
  // In (f32, 16.78 MB) parks in the `out` region: written by phase2, read by
  // phase3, then fully overwritten by reduce_out (same-stream ordering).
  float* In = out;

  const bool castOK = ws_size >= WS_NEED_CAST;
  if (castOK) {
    bf16* HBF = (bf16*)(ws + OFF_HBF);
    bf16* WINBF = (bf16*)(ws + OFF_WINBF);
    bf16* WDTBF = (bf16*)(ws + OFF_WDTBF);
    bf16* WOUTBF = (bf16*)(ws + OFF_WOUTBF);
    prep_all<<<15104, 256, 0, stream>>>(hidden, W_in, W_dt, W_out, W_x, HBF,
                                        WINBF, WDTBF, WOUTBF, WXPAD);
    // GEMM1: XZ = HBF @ WINBF^T — 8-phase 256^2 template, 256 WGs (1/CU)
    gemm256_8p<<<dim3(256), 512, 0, stream>>>(HBF, WINBF, XZ, 2048, 8192,
                                              2048, 2048, 2048);
    conv_kernel<<<32768, 256, 0, stream>>>(XZ, conv_w, conv_b, XC, out_conv);
    // GEMM2 (split-K=8 -> partial slabs, no atomics): PART[z] = XC @ WXPAD^T
    gemm_bt<4, 0, 0, 64><<<dim3(32, 2, 8), 256, 0, stream>>>(
        XC, WXPAD, PART, nullptr, 2048, 256, 4096, 4096, 4096);
    reduce_xdbl<<<512, 256, 0, stream>>>(PART, XDBL);
    // GEMM_dt (TM=64, A = XDBL dt-cols f32 lda=256): DELTA = softplus(.)
    gemm_bt<2, 1, 0, 64><<<dim3(32, 32, 1), 256, 0, stream>>>(
        XDBL, WDTBF, DELTA, b_dt, 2048, 4096, 128, 256, 128);
    scan_phase1<<<dim3(32, NCH), 256, 0, stream>>>(DELTA, XC, XDBL, A_log, P,
                                                   Lc);
    scan_phase2<<<128, 64, 0, stream>>>(P, Lc, In, out_last);
    scan_phase3<<<dim3(32, NCH), 256, 0, stream>>>(DELTA, XC, XZ, XDBL, A_log,
                                                   Dvec, In, Y);
    // GEMM3 split-K=2 (1024 WGs = 4 WGs/CU): SLAB3[z] = Y @ WOUTBF^T halves,
    // then reduce_out adds slabs + bias -> out.
    gemm_bt<5, 0, 0, 64><<<dim3(32, 16, 2), 256, 0, stream>>>(
        Y, WOUTBF, SLAB3, nullptr, 2048, 2048, 4096, 4096, 4096);
    reduce_out<<<4096, 256, 0, stream>>>(SLAB3, b_out, out);
  } else {
    // fallback: f32-staged GEMMs, no cast buffers
    wxpad_prep<<<4096, 256, 0, stream>>>(W_x, WXPAD);
    gemm_bt<0, 1, 1, 128><<<dim3(16, 64, 1), 256, 0, stream>>>(
        hidden, W_in, XZ, nullptr, 2048, 8192, 2048, 2048, 2048);
    conv_kernel<<<32768, 256, 0, stream>>>(XZ, conv_w, conv_b, XC, out_conv);
    gemm_bt<4, 0, 0, 64><<<dim3(32, 2, 8), 256, 0, stream>>>(
        XC, WXPAD, PART, nullptr, 2048, 256, 4096, 4096, 4096);
    reduce_xdbl<<<512, 256, 0, stream>>>(PART, XDBL);
    gemm_bt<2, 1, 1, 64><<<dim3(32, 32, 1), 256, 0, stream>>>(
        XDBL, W_dt, DELTA, b_dt, 2048, 4096, 128, 256, 128);
    scan_phase1<<<dim3(32, NCH), 256, 0, stream>>>(DELTA, XC, XDBL, A_log, P,
                                                   Lc);
    scan_phase2<<<128, 64, 0, stream>>>(P, Lc, In, out_last);
    scan_phase3<<<dim3(32, NCH), 256, 0, stream>>>(DELTA, XC, XZ, XDBL, A_log,
                                                   Dvec, In, Y);
    gemm_bt<3, 0, 1, 64><<<dim3(32, 16, 1), 256, 0, stream>>>(
        Y, W_out, out, b_out, 2048, 2048, 4096, 4096, 4096);
  }
}

// Round 6
// 477.571 us; speedup vs baseline: 1.0875x; 1.0306x over previous
//
#include <hip/hip_runtime.h>
#include <stdint.h>
#include <stddef.h>

typedef __bf16 bf16;
typedef __attribute__((ext_vector_type(8))) __bf16 bf16x8;
typedef __attribute__((ext_vector_type(4))) float floatx4;

#define GAS __attribute__((address_space(1)))
#define LAS __attribute__((address_space(3)))

__device__ __forceinline__ void async16(const void* g, void* l) {
  __builtin_amdgcn_global_load_lds((const GAS void*)g, (LAS void*)l, 16, 0, 0);
}

__device__ __forceinline__ bf16x8 cvt8(const float* p) {
  floatx4 a = *(const floatx4*)p;
  floatx4 b = *(const floatx4*)(p + 4);
  bf16x8 r;
  r[0] = (bf16)a[0]; r[1] = (bf16)a[1]; r[2] = (bf16)a[2]; r[3] = (bf16)a[3];
  r[4] = (bf16)b[0]; r[5] = (bf16)b[1]; r[6] = (bf16)b[2]; r[7] = (bf16)b[3];
  return r;
}

// ---------------------------------------------------------------------------
// 256x256 8-phase GEMM (r5 frozen: verified 77.7 us, MfmaUtil 35%, 0 bank
// conflicts). Phase cost = sum(MFMA 620 + LDS 576 + DMA 128 + sync) — three
// schedule variants (burst-read, read-ahead, 2-drain) all null, so this is
// the structure's floor at 1 WG/CU; do not re-tune the schedule.
// ---------------------------------------------------------------------------
__global__ __launch_bounds__(512, 2) void gemm256_8p(
    const bf16* __restrict__ A, const bf16* __restrict__ B,
    bf16* __restrict__ C, int M, int N, int K, int lda, int ldb) {
  __shared__ __attribute__((aligned(16))) bf16 SA[2][2][8192];
  __shared__ __attribute__((aligned(16))) bf16 SB[2][2][8192];

  const int tid = threadIdx.x;
  const int wave = tid >> 6;
  const int lane = tid & 63;
  const int lr = lane & 15;
  const int kg = lane >> 4;
  const int wm = (wave >> 2) * 128;  // wave row-block (2)
  const int wn = (wave & 3) * 64;    // wave col-block (4)

  // XCD-aware mapping: blocks co-resident on an XCD share the A panel.
  const int tilesM = M >> 8;
  const int tm = blockIdx.x % tilesM;
  const int tn = blockIdx.x / tilesM;
  const int rowBase = tm * 256;
  const int colBase = tn * 256;

  // staging geometry: one global_load_lds = 512 thr x 16 B = 8 KB = 128 rows
  // x 32 k; source k pre-swizzled so linear LDS dest matches ds_read XOR.
  const int srow = tid >> 2;
  const int ske = (tid & 3) << 3;
  const int skel = ske ^ (((srow >> 1) & 3) << 3);
  const size_t aRow0 = (size_t)(rowBase + srow) * lda;
  const size_t aRow1 = aRow0 + (size_t)128 * lda;
  const size_t bRow0 = (size_t)(colBase + srow) * ldb;
  const size_t bRow1 = bRow0 + (size_t)128 * ldb;

  const int NT = K >> 6;  // K-tiles of 64

  // frag-read swizzled k offset within a [256][32] region
  const int keSh = (kg << 3) ^ (((lr >> 1) & 3) << 3);

  floatx4 acc[8][4] = {};
  bf16x8 af0[4], af1[4], bgA[4], bgB[4];

  auto stA = [&](int buf, int kh, int kt) {
    const int gk = kt * 64 + kh * 32 + skel;
    bf16* d = &SA[buf][kh][0];
    async16(A + aRow0 + gk, d + tid * 8);
    async16(A + aRow1 + gk, d + 4096 + tid * 8);
  };
  auto stB = [&](int buf, int kh, int kt) {
    const int gk = kt * 64 + kh * 32 + skel;
    bf16* d = &SB[buf][kh][0];
    async16(B + bRow0 + gk, d + tid * 8);
    async16(B + bRow1 + gk, d + 4096 + tid * 8);
  };

#define RD_B(DST, BUF, KH)                                                     \
  _Pragma("unroll") for (int n = 0; n < 4; ++n)                                \
      DST[n] = *(const bf16x8*)&SB[BUF][KH][(wn + n * 16 + lr) * 32 + keSh];
#define RD_A(DST, BUF, KH, MH)                                                 \
  _Pragma("unroll") for (int m = 0; m < 4; ++m)                                \
      DST[m] =                                                                 \
          *(const bf16x8*)&SA[BUF][KH][(wm + ((MH)*4 + m) * 16 + lr) * 32 +    \
                                       keSh];

  // ---- prologue: stage all 7 half-tiles, FULL drain, pre-read PH1 operands.
  stB(0, 0, 0); stA(0, 0, 0); stB(0, 1, 0); stA(0, 1, 0);
  stB(1, 0, 1); stA(1, 0, 1); stB(1, 1, 1);
  asm volatile("s_waitcnt vmcnt(0)" ::: "memory");
  __builtin_amdgcn_s_barrier();
  RD_B(bgA, 0, 0);
  RD_A(af0, 0, 0, 0);

#define PH(RDS, CNT, STG, BGR, AFR, MH, VM)                                    \
  {                                                                            \
    RDS;                                                                       \
    STG;                                                                       \
    __builtin_amdgcn_s_barrier();                                              \
    asm volatile("s_waitcnt lgkmcnt(" #CNT ")" ::: "memory");                  \
    __builtin_amdgcn_sched_barrier(0);                                         \
    __builtin_amdgcn_s_setprio(1);                                             \
    _Pragma("unroll") for (int m = 0; m < 4; ++m)                              \
      _Pragma("unroll") for (int n = 0; n < 4; ++n)                            \
          acc[(MH)*4 + m][n] = __builtin_amdgcn_mfma_f32_16x16x32_bf16(        \
              AFR[m], BGR[n], acc[(MH)*4 + m][n], 0, 0, 0);                    \
    __builtin_amdgcn_s_setprio(0);                                             \
    __builtin_amdgcn_sched_barrier(0);                                         \
    if constexpr (VM) asm volatile("s_waitcnt vmcnt(2)" ::: "memory");         \
    __builtin_amdgcn_s_barrier();                                              \
  }

  for (int it = 0; it < (NT >> 1); ++it) {
    const int T0 = it * 2;
    const int T1 = T0 + 1;
    const int s1 = (T0 + 2 < NT) ? T0 + 2 : NT - 1;
    const int s2 = (T1 + 2 < NT) ? T1 + 2 : NT - 1;

    PH(RD_A(af1, 0, 0, 1), 4, stA(1, 1, T1), bgA, af0, 0, false)  // PH1
    PH(RD_B(bgB, 0, 1); RD_A(af0, 0, 1, 0), 8, stB(0, 0, s1), bgA, af1, 1,
       false)                                                      // PH2
    PH(RD_A(af1, 0, 1, 1), 4, stA(0, 0, s1), bgB, af0, 0, false)  // PH3
    PH(RD_B(bgA, 1, 0); RD_A(af0, 1, 0, 0), 8, stB(0, 1, s1), bgB, af1, 1,
       true)                                                       // PH4
    PH(RD_A(af1, 1, 0, 1), 4, stA(0, 1, s1), bgA, af0, 0, false)  // PH5
    PH(RD_B(bgB, 1, 1); RD_A(af0, 1, 1, 0), 8, stB(1, 0, s2), bgA, af1, 1,
       false)                                                      // PH6
    PH(RD_A(af1, 1, 1, 1), 4, stA(1, 0, s2), bgB, af0, 0, false)  // PH7
    PH(RD_B(bgA, 0, 0); RD_A(af0, 0, 0, 0), 8, stB(1, 1, s2), bgB, af1, 1,
       true)                                                       // PH8
  }
#undef PH
#undef RD_A
#undef RD_B

  asm volatile("s_waitcnt vmcnt(0) lgkmcnt(0)" ::: "memory");

  // epilogue: C/D layout col = lane&15, row = (lane>>4)*4 + reg  [m89]
#pragma unroll
  for (int m = 0; m < 8; ++m) {
#pragma unroll
    for (int n = 0; n < 4; ++n) {
      const int col = colBase + wn + n * 16 + lr;
#pragma unroll
      for (int r = 0; r < 4; ++r) {
        const int row = rowBase + wm + m * 16 + kg * 4 + r;
        C[(size_t)row * N + col] = (bf16)acc[m][n][r];
      }
    }
  }
}

// ---------------------------------------------------------------------------
// Generic "bt" GEMM: C[M,N] = A[M,K_eff] @ B[N,K_eff]^T with row strides
// lda/ldb (elements). AF/BF: f32 operand (VGPR+cvt+ds_write staging) vs bf16
// (async global_load_lds). TM: 128 (4 waves 2x2 of 64x64) or 64 (4 waves 1x4
// of 64x32). BK=32, 256 thr, mfma_f32_16x16x32_bf16.
// EPI: 0 bf16 store | 1 f32 atomicAdd | 2 bf16 softplus(v+bias) |
//      3 f32 (v+bias) | 4 f32 per-z slab stride 524288 (GEMM2 split-K) |
//      5 f32 per-z slab stride 4194304 (GEMM3 split-K)
// ---------------------------------------------------------------------------
template <int EPI, int AF, int BF, int TM>
__global__ __launch_bounds__(256, 4) void gemm_bt(
    const void* __restrict__ Aptr, const void* __restrict__ Bptr,
    void* __restrict__ Cout, const float* __restrict__ bias,
    int M, int N, int K, int lda, int ldb) {
  __shared__ bf16 As[TM * 32];
  __shared__ bf16 Bs[128 * 32];
  const int tid = threadIdx.x;

  const int rowBase = blockIdx.x * TM;
  const int colBase = blockIdx.y * 128;
  const int kLen = K / gridDim.z;
  const int k0 = blockIdx.z * kLen;
  const int kIters = kLen / 32;

  const int sRow = tid >> 2;
  const int sCol = (tid & 3) << 3;
  const int wave = tid >> 6;
  const int lane = tid & 63;
  constexpr int MI = 4;
  constexpr int NJ = (TM == 128) ? 4 : 2;
  const int wm = (TM == 128) ? ((wave >> 1) << 6) : 0;
  const int wn = (TM == 128) ? ((wave & 1) << 6) : (wave << 5);
  const int lr = lane & 15;
  const int kg = lane >> 4;

  floatx4 acc[MI][NJ] = {};

  for (int kt = 0; kt < kIters; ++kt) {
    const int kk = k0 + kt * 32;
    __syncthreads();  // prev iter's LDS reads done before overwrite
    if constexpr (AF) {
      const float* pa =
          (const float*)Aptr + (size_t)(rowBase + sRow) * lda + kk + sCol;
      *(bf16x8*)&As[tid * 8] = cvt8(pa);
      if constexpr (TM == 128)
        *(bf16x8*)&As[2048 + tid * 8] = cvt8(pa + (size_t)64 * lda);
    } else {
      const bf16* pa =
          (const bf16*)Aptr + (size_t)(rowBase + sRow) * lda + kk + sCol;
      async16(pa, &As[tid * 8]);
      if constexpr (TM == 128)
        async16(pa + (size_t)64 * lda, &As[2048 + tid * 8]);
    }
    if constexpr (BF) {
      const float* pb =
          (const float*)Bptr + (size_t)(colBase + sRow) * ldb + kk + sCol;
      *(bf16x8*)&Bs[tid * 8] = cvt8(pb);
      *(bf16x8*)&Bs[2048 + tid * 8] = cvt8(pb + (size_t)64 * ldb);
    } else {
      const bf16* pb =
          (const bf16*)Bptr + (size_t)(colBase + sRow) * ldb + kk + sCol;
      async16(pb, &Bs[tid * 8]);
      async16(pb + (size_t)64 * ldb, &Bs[2048 + tid * 8]);
    }
    __syncthreads();  // staging complete -> tile visible

    bf16x8 af[MI], bg[NJ];
#pragma unroll
    for (int i = 0; i < MI; ++i)
      af[i] = *(const bf16x8*)&As[(wm + i * 16 + lr) * 32 + kg * 8];
#pragma unroll
    for (int j = 0; j < NJ; ++j)
      bg[j] = *(const bf16x8*)&Bs[(wn + j * 16 + lr) * 32 + kg * 8];
#pragma unroll
    for (int i = 0; i < MI; ++i)
#pragma unroll
      for (int j = 0; j < NJ; ++j)
        acc[i][j] = __builtin_amdgcn_mfma_f32_16x16x32_bf16(af[i], bg[j],
                                                            acc[i][j], 0, 0, 0);
  }

  // epilogue: C/D layout col = lane&15, row = (lane>>4)*4 + reg  [m89]
#pragma unroll
  for (int i = 0; i < MI; ++i) {
#pragma unroll
    for (int j = 0; j < NJ; ++j) {
      const int col = colBase + wn + j * 16 + lr;
      float bv = 0.f;
      if constexpr (EPI == 2 || EPI == 3) bv = bias[col];
#pragma unroll
      for (int r = 0; r < 4; ++r) {
        const int row = rowBase + wm + i * 16 + kg * 4 + r;
        const size_t idx = (size_t)row * N + col;
        float v = acc[i][j][r];
        if constexpr (EPI == 0) {
          ((bf16*)Cout)[idx] = (bf16)v;
        } else if constexpr (EPI == 1) {
          atomicAdd((float*)Cout + idx, v);
        } else if constexpr (EPI == 2) {
          v += bv;
          // softplus = ln(1+e^v); for v>20, ln(1+e^v)==v to f32 precision.
          const float t = __expf(v);
          const float sp = (v > 20.f) ? v : __logf(1.f + t);
          ((bf16*)Cout)[idx] = (bf16)sp;
        } else if constexpr (EPI == 3) {
          ((float*)Cout)[idx] = v + bv;
        } else if constexpr (EPI == 4) {
          // split-K partial: distinct slab per z, no contention
          ((float*)Cout)[(size_t)blockIdx.z * 524288 + idx] = v;
        } else {
          ((float*)Cout)[(size_t)blockIdx.z * 4194304 + idx] = v;
        }
      }
    }
  }
}

// sum 8 split-K partial slabs -> XDBL (2048x256 f32)
__global__ __launch_bounds__(256) void reduce_xdbl(
    const float* __restrict__ part, float* __restrict__ xdbl) {
  const size_t i4 = ((size_t)blockIdx.x * 256 + threadIdx.x) * 4;  // 524288/4
  floatx4 s = {};
#pragma unroll
  for (int z = 0; z < 8; ++z) {
    const floatx4 v = *(const floatx4*)&part[(size_t)z * 524288 + i4];
    s[0] += v[0]; s[1] += v[1]; s[2] += v[2]; s[3] += v[3];
  }
  *(floatx4*)&xdbl[i4] = s;
}

// sum 4 GEMM3 split-K slabs + bias -> out (2048x2048 f32)
__global__ __launch_bounds__(256) void reduce_out4(
    const float* __restrict__ part, const float* __restrict__ bias,
    float* __restrict__ outp) {
  const size_t i4 = ((size_t)blockIdx.x * 256 + threadIdx.x) * 4;  // 4194304/4
  floatx4 s = *(const floatx4*)&bias[i4 & 2047];
#pragma unroll
  for (int z = 0; z < 4; ++z) {
    const floatx4 v = *(const floatx4*)&part[(size_t)z * 4194304 + i4];
    s[0] += v[0]; s[1] += v[1]; s[2] += v[2]; s[3] += v[3];
  }
  *(floatx4*)&outp[i4] = s;
}

// ---------------------------------------------------------------------------
// Fused prep: f32->bf16 casts (hidden|W_in|W_dt|W_out) + W_x pad-cast.
// ---------------------------------------------------------------------------
#define PC0 524288UL    // hidden chunks
#define PC1 2621440UL   // +W_in
#define PC2 2686976UL   // +W_dt
#define PC3 3735552UL   // +W_out
#define PC4 3866624UL   // +WXPAD (dest 256x4096)
__global__ __launch_bounds__(256) void prep_all(
    const float* __restrict__ h, const float* __restrict__ wi,
    const float* __restrict__ wd, const float* __restrict__ wo,
    const float* __restrict__ wx, bf16* __restrict__ hb,
    bf16* __restrict__ wib, bf16* __restrict__ wdb, bf16* __restrict__ wob,
    bf16* __restrict__ wxp) {
  const size_t c = (size_t)blockIdx.x * 256 + threadIdx.x;
  if (c < PC0) {
    const size_t e = c * 8;
    *(bf16x8*)&hb[e] = cvt8(&h[e]);
  } else if (c < PC1) {
    const size_t e = (c - PC0) * 8;
    *(bf16x8*)&wib[e] = cvt8(&wi[e]);
  } else if (c < PC2) {
    const size_t e = (c - PC1) * 8;
    *(bf16x8*)&wdb[e] = cvt8(&wd[e]);
  } else if (c < PC3) {
    const size_t e = (c - PC2) * 8;
    *(bf16x8*)&wob[e] = cvt8(&wo[e]);
  } else if (c < PC4) {
    const size_t e = (c - PC3) * 8;
    if ((e >> 12) < 160) {
      *(bf16x8*)&wxp[e] = cvt8(&wx[e]);
    } else {
      bf16x8 z = {};
      *(bf16x8*)&wxp[e] = z;
    }
  }
}

// W_x pad (fallback path only)
__global__ void wxpad_prep(const float* __restrict__ Wx,
                           bf16* __restrict__ WXPAD) {
  const int idx = blockIdx.x * 256 + threadIdx.x;
  const int row = idx >> 12;
  WXPAD[idx] = (row < 160) ? (bf16)Wx[idx] : (bf16)0.f;
}

// Depthwise causal conv (K=4) + bias + SiLU, x8-vectorized (G13: bf16x8
// loads/stores, 16 B/lane). Each thread: 8 consecutive d at one row.
// Fused conv_state output unchanged.
__global__ __launch_bounds__(256) void conv_v8(
    const bf16* __restrict__ XZ, const float* __restrict__ conv_w,
    const float* __restrict__ conv_b, bf16* __restrict__ XC,
    float* __restrict__ outConv) {
  const int idx = blockIdx.x * 256 + threadIdx.x;  // 0..1048575
  const int d8 = (idx & 511) << 3;
  const int row = idx >> 9;
  const int l = row & 1023;
  float acc[8];
  {
    const floatx4 cb0 = *(const floatx4*)&conv_b[d8];
    const floatx4 cb1 = *(const floatx4*)&conv_b[d8 + 4];
#pragma unroll
    for (int j = 0; j < 4; ++j) { acc[j] = cb0[j]; acc[4 + j] = cb1[j]; }
  }
  float w[8][4];
#pragma unroll
  for (int j = 0; j < 8; ++j) {
    const floatx4 cw = *(const floatx4*)&conv_w[(d8 + j) * 4];
#pragma unroll
    for (int k = 0; k < 4; ++k) w[j][k] = cw[k];
  }
  if (l >= 3) {  // fast path: all 4 taps valid
#pragma unroll
    for (int k = 0; k < 4; ++k) {
      const bf16x8 x = *(const bf16x8*)&XZ[(size_t)(row - 3 + k) * 8192 + d8];
#pragma unroll
      for (int j = 0; j < 8; ++j) acc[j] += w[j][k] * (float)x[j];
    }
  } else {
#pragma unroll
    for (int k = 0; k < 4; ++k) {
      if (l - 3 + k >= 0) {
        const bf16x8 x = *(const bf16x8*)&XZ[(size_t)(row - 3 + k) * 8192 + d8];
#pragma unroll
        for (int j = 0; j < 8; ++j) acc[j] += w[j][k] * (float)x[j];
      }
    }
  }
  bf16x8 o;
#pragma unroll
  for (int j = 0; j < 8; ++j)
    o[j] = (bf16)(acc[j] / (1.f + __expf(-acc[j])));
  *(bf16x8*)&XC[(size_t)row * 4096 + d8] = o;
  if (idx < 4096) {  // conv_state: out[b,dd,k] = x[b, 1020+k, dd]
#pragma unroll
    for (int j = 0; j < 8; ++j) {
      const int e = idx * 8 + j;  // 0..32767
      const int k = e & 3;
      const int dd = (e >> 2) & 4095;
      const int b = e >> 14;
      outConv[e] = (float)XZ[(size_t)(b * 1024 + 1020 + k) * 8192 + dd];
    }
  }
}

// ---------------------------------------------------------------------------
// Chunked parallel scan (32 chunks of 32).
// ---------------------------------------------------------------------------
#define NCH 32
#define CLEN 32
#define LOG2E 1.44269504088896f

__global__ __launch_bounds__(256) void scan_phase1(
    const bf16* __restrict__ DELTA, const bf16* __restrict__ XC,
    const float* __restrict__ XDBL, const float* __restrict__ A_log,
    bf16* __restrict__ P, bf16* __restrict__ Lc) {
  const int bd = blockIdx.x * 256 + threadIdx.x;  // 0..8191
  const int c = blockIdx.y;
  const int b = bd >> 12;
  const int d = bd & 4095;
  float A2[16], st[16], p[16];
#pragma unroll
  for (int n = 0; n < 16; ++n) {
    A2[n] = -__expf(A_log[d * 16 + n]) * LOG2E;
    st[n] = 0.f;
    p[n] = 1.f;
  }
  size_t row = (size_t)b * 1024 + (size_t)c * CLEN;
  for (int t = 0; t < CLEN; ++t, ++row) {
    const float dlt = (float)DELTA[row * 4096 + d];
    const float u = (float)XC[row * 4096 + d];
    const float* __restrict__ Bp = XDBL + row * 256 + 128;  // wave-uniform
    const float du = dlt * u;
#pragma unroll
    for (int n = 0; n < 16; ++n) {
      const float dA = exp2f(dlt * A2[n]);
      st[n] = dA * st[n] + du * Bp[n];
      p[n] *= dA;
    }
  }
  const size_t o = ((size_t)c * 8192 + bd) * 16;
  bf16x8 pk[2], lk[2];
#pragma unroll
  for (int n = 0; n < 16; ++n) {
    pk[n >> 3][n & 7] = (bf16)p[n];
    lk[n >> 3][n & 7] = (bf16)st[n];
  }
  *(bf16x8*)&P[o] = pk[0];
  *(bf16x8*)&P[o + 8] = pk[1];
  *(bf16x8*)&Lc[o] = lk[0];
  *(bf16x8*)&Lc[o + 8] = lk[1];
}

__global__ __launch_bounds__(64) void scan_phase2(
    const bf16* __restrict__ P, const bf16* __restrict__ Lc,
    float* __restrict__ In, float* __restrict__ lastOut) {
  // 128 blocks x 64 thr: 4x the CUs for this latency-bound serial kernel.
  const int bd = blockIdx.x * 64 + threadIdx.x;  // 0..8191
  float st[16] = {};
  for (int c = 0; c < NCH; ++c) {
    const size_t o = ((size_t)c * 8192 + bd) * 16;
    const bf16x8 p0 = *(const bf16x8*)&P[o];
    const bf16x8 p1 = *(const bf16x8*)&P[o + 8];
    const bf16x8 l0 = *(const bf16x8*)&Lc[o];
    const bf16x8 l1 = *(const bf16x8*)&Lc[o + 8];
    floatx4 w[4];
#pragma unroll
    for (int n = 0; n < 16; ++n) w[n >> 2][n & 3] = st[n];
#pragma unroll
    for (int q = 0; q < 4; ++q) *(floatx4*)&In[o + q * 4] = w[q];
#pragma unroll
    for (int n = 0; n < 8; ++n) {
      st[n] = (float)p0[n] * st[n] + (float)l0[n];
      st[8 + n] = (float)p1[n] * st[8 + n] + (float)l1[n];
    }
  }
  const int b = bd >> 12;
  const int d = bd & 4095;
#pragma unroll
  for (int n = 0; n < 16; ++n)
    lastOut[(size_t)b * 65536 + d * 16 + n] = st[n];
}

__global__ __launch_bounds__(256) void scan_phase3(
    const bf16* __restrict__ DELTA, const bf16* __restrict__ XC,
    const bf16* __restrict__ XZ, const float* __restrict__ XDBL,
    const float* __restrict__ A_log, const float* __restrict__ Dp,
    const float* __restrict__ In, bf16* __restrict__ Y) {
  const int bd = blockIdx.x * 256 + threadIdx.x;
  const int c = blockIdx.y;
  const int b = bd >> 12;
  const int d = bd & 4095;
  float A2[16], st[16];
  const size_t o = ((size_t)c * 8192 + bd) * 16;
#pragma unroll
  for (int q = 0; q < 4; ++q) {
    const floatx4 v = *(const floatx4*)&In[o + q * 4];
#pragma unroll
    for (int j = 0; j < 4; ++j) st[q * 4 + j] = v[j];
  }
#pragma unroll
  for (int n = 0; n < 16; ++n)
    A2[n] = -__expf(A_log[d * 16 + n]) * LOG2E;
  const float Dd = Dp[d];
  size_t row = (size_t)b * 1024 + (size_t)c * CLEN;
  for (int t = 0; t < CLEN; ++t, ++row) {
    const float dlt = (float)DELTA[row * 4096 + d];
    const float u = (float)XC[row * 4096 + d];
    const float z = (float)XZ[row * 8192 + 4096 + d];
    const float* __restrict__ Bp = XDBL + row * 256 + 128;
    const float du = dlt * u;
    float y = 0.f;
#pragma unroll
    for (int n = 0; n < 16; ++n) {
      const float dA = exp2f(dlt * A2[n]);
      st[n] = dA * st[n] + du * Bp[n];
      y += st[n] * Bp[16 + n];
    }
    const float sig = 1.f / (1.f + __expf(-z));
    Y[row * 4096 + d] = (bf16)((y + Dd * u) * (z * sig));
  }
}

// ---------------------------------------------------------------------------
// Workspace layout (bytes). DELTA slot holds bf16 DELTA (lower 16.8 MB) and
// the GEMM2 split-K partials (upper 16.8 MB). After scan_phase3, the entire
// XZ+XC+DELTA+PART region (0..83.9 MB) is dead (scan3 is the last reader of
// XZ, XC, DELTA) and is reused as GEMM3's 4 split-K f32 slabs (67 MB),
// which never touch Y (at 83.9 MB, GEMM3's input).
// ---------------------------------------------------------------------------
#define OFF_XZ 0UL                 // bf16 2048x8192
#define OFF_XC 33554432UL          // bf16 2048x4096
#define OFF_DELTA 50331648UL       // bf16 2048x4096 | +16777216: PART f32 8x524288
#define OFF_Y 83886080UL           // bf16 2048x4096
#define OFF_XDBL 100663296UL       // f32  2048x256
#define OFF_WXPAD 103284736UL      // bf16 256x4096
#define OFF_P 105381888UL          // bf16 32x8192x16
#define OFF_L 113770496UL          // bf16 32x8192x16
#define OFF_HBF 122159104UL        // bf16 2048x2048
#define OFF_WINBF 130547712UL      // bf16 8192x2048
#define OFF_WDTBF 164102144UL      // bf16 4096x128
#define OFF_WOUTBF 165150720UL     // bf16 2048x4096
#define WS_NEED_CAST 181927936UL   // ~173.5 MB

extern "C" void kernel_launch(void* const* d_in, const int* in_sizes, int n_in,
                              void* d_out, int out_size, void* d_ws,
                              size_t ws_size, hipStream_t stream) {
  const float* hidden = (const float*)d_in[0];
  const float* W_in = (const float*)d_in[1];
  const float* conv_w = (const float*)d_in[2];
  const float* conv_b = (const float*)d_in[3];
  const float* W_x = (const float*)d_in[4];
  const float* W_dt = (const float*)d_in[5];
  const float* b_dt = (const float*)d_in[6];
  const float* A_log = (const float*)d_in[7];
  const float* Dvec = (const float*)d_in[8];
  const float* W_out = (const float*)d_in[9];
  const float* b_out = (const float*)d_in[10];

  char* ws = (char*)d_ws;
  bf16* XZ = (bf16*)(ws + OFF_XZ);
  bf16* XC = (bf16*)(ws + OFF_XC);
  bf16* DELTA = (bf16*)(ws + OFF_DELTA);
  float* PART = (float*)(ws + OFF_DELTA + 16777216UL);
  float* SLAB3 = (float*)(ws + OFF_XZ);  // 67 MB over dead XZ..PART region
  bf16* Y = (bf16*)(ws + OFF_Y);
  float* XDBL = (float*)(ws + OFF_XDBL);
  bf16* WXPAD = (bf16*)(ws + OFF_WXPAD);
  bf16* P = (bf16*)(ws + OFF_P);
  bf16* Lc = (bf16*)(ws + OFF_L);

  float* out = (float*)d_out;             // (2,1024,2048) = 4194304 f32
  float* out_conv = out + 4194304;        // (2,4096,4)
  float* out_last = out + 4227072;        // (2,4096,16)
  // In (f32, 16.78 MB) parks in the `out` region: written by phase2, read by
  // phase3, then fully overwritten by reduce_out4 (same-stream ordering).
  float* In = out;

  const bool castOK = ws_size >= WS_NEED_CAST;
  if (castOK) {
    bf16* HBF = (bf16*)(ws + OFF_HBF);
    bf16* WINBF = (bf16*)(ws + OFF_WINBF);
    bf16* WDTBF = (bf16*)(ws + OFF_WDTBF);
    bf16* WOUTBF = (bf16*)(ws + OFF_WOUTBF);
    prep_all<<<15104, 256, 0, stream>>>(hidden, W_in, W_dt, W_out, W_x, HBF,
                                        WINBF, WDTBF, WOUTBF, WXPAD);
    // GEMM1: XZ = HBF @ WINBF^T — 8-phase 256^2 template, 256 WGs (1/CU)
    gemm256_8p<<<dim3(256), 512, 0, stream>>>(HBF, WINBF, XZ, 2048, 8192,
                                              2048, 2048, 2048);
    conv_v8<<<4096, 256, 0, stream>>>(XZ, conv_w, conv_b, XC, out_conv);
    // GEMM2 (split-K=8 -> partial slabs, no atomics): PART[z] = XC @ WXPAD^T
    gemm_bt<4, 0, 0, 64><<<dim3(32, 2, 8), 256, 0, stream>>>(
        XC, WXPAD, PART, nullptr, 2048, 256, 4096, 4096, 4096);
    reduce_xdbl<<<512, 256, 0, stream>>>(PART, XDBL);
    // GEMM_dt (TM=64, A = XDBL dt-cols f32 lda=256): DELTA = softplus(.)
    gemm_bt<2, 1, 0, 64><<<dim3(32, 32, 1), 256, 0, stream>>>(
        XDBL, WDTBF, DELTA, b_dt, 2048, 4096, 128, 256, 128);
    scan_phase1<<<dim3(32, NCH), 256, 0, stream>>>(DELTA, XC, XDBL, A_log, P,
                                                   Lc);
    scan_phase2<<<128, 64, 0, stream>>>(P, Lc, In, out_last);
    scan_phase3<<<dim3(32, NCH), 256, 0, stream>>>(DELTA, XC, XZ, XDBL, A_log,
                                                   Dvec, In, Y);
    // GEMM3 split-K=4 (TM=128, 1024 WGs = 4 WGs/CU — r0-proven occupancy):
    // SLAB3[z] = Y @ WOUTBF^T quarters; reduce_out4 sums + bias -> out.
    gemm_bt<5, 0, 0, 128><<<dim3(16, 16, 4), 256, 0, stream>>>(
        Y, WOUTBF, SLAB3, nullptr, 2048, 2048, 4096, 4096, 4096);
    reduce_out4<<<4096, 256, 0, stream>>>(SLAB3, b_out, out);
  } else {
    // fallback: f32-staged GEMMs, no cast buffers
    wxpad_prep<<<4096, 256, 0, stream>>>(W_x, WXPAD);
    gemm_bt<0, 1, 1, 128><<<dim3(16, 64, 1), 256, 0, stream>>>(
        hidden, W_in, XZ, nullptr, 2048, 8192, 2048, 2048, 2048);
    conv_v8<<<4096, 256, 0, stream>>>(XZ, conv_w, conv_b, XC, out_conv);
    gemm_bt<4, 0, 0, 64><<<dim3(32, 2, 8), 256, 0, stream>>>(
        XC, WXPAD, PART, nullptr, 2048, 256, 4096, 4096, 4096);
    reduce_xdbl<<<512, 256, 0, stream>>>(PART, XDBL);
    gemm_bt<2, 1, 1, 64><<<dim3(32, 32, 1), 256, 0, stream>>>(
        XDBL, W_dt, DELTA, b_dt, 2048, 4096, 128, 256, 128);
    scan_phase1<<<dim3(32, NCH), 256, 0, stream>>>(DELTA, XC, XDBL, A_log, P,
                                                   Lc);
    scan_phase2<<<128, 64, 0, stream>>>(P, Lc, In, out_last);
    scan_phase3<<<dim3(32, NCH), 256, 0, stream>>>(DELTA, XC, XZ, XDBL, A_log,
                                                   Dvec, In, Y);
    gemm_bt<5, 0, 1, 128><<<dim3(16, 16, 4), 256, 0, stream>>>(
        Y, W_out, SLAB3, nullptr, 2048, 2048, 4096, 4096, 4096);
    reduce_out4<<<4096, 256, 0, stream>>>(SLAB3, b_out, out);
  }
}

// Round 7
// 470.265 us; speedup vs baseline: 1.1044x; 1.0155x over previous
//
#include <hip/hip_runtime.h>
#include <stdint.h>
#include <stddef.h>

typedef __bf16 bf16;
typedef __attribute__((ext_vector_type(8))) __bf16 bf16x8;
typedef __attribute__((ext_vector_type(4))) float floatx4;

#define GAS __attribute__((address_space(1)))
#define LAS __attribute__((address_space(3)))

__device__ __forceinline__ void async16(const void* g, void* l) {
  __builtin_amdgcn_global_load_lds((const GAS void*)g, (LAS void*)l, 16, 0, 0);
}

__device__ __forceinline__ bf16x8 cvt8(const float* p) {
  floatx4 a = *(const floatx4*)p;
  floatx4 b = *(const floatx4*)(p + 4);
  bf16x8 r;
  r[0] = (bf16)a[0]; r[1] = (bf16)a[1]; r[2] = (bf16)a[2]; r[3] = (bf16)a[3];
  r[4] = (bf16)b[0]; r[5] = (bf16)b[1]; r[6] = (bf16)b[2]; r[7] = (bf16)b[3];
  return r;
}

// ---------------------------------------------------------------------------
// 256x256 8-phase GEMM (schedule frozen since r5: 77.7 us, MfmaUtil 35%,
// 0 bank conflicts; three schedule variants null).
//
// r7: XCD-locality remap. HW XCD = blockIdx.x % 8 (round-robin). Old mapping
// (tm=bid%8) clustered A-panel sharers per XCD but spread each B-panel's 8
// sharers across ALL 8 XCDs -> 8x B refetch (FETCH_SIZE 135 MB vs 42 MB
// nominal). New mapping clusters tn-groups per XCD: each XCD owns
// tilesN/8 = 4 B-panels (4 MB = L2-sized) x all 8 tm; A (8.4 MB total) is
// L3-trivial. Pure index change; schedule untouched.
// ---------------------------------------------------------------------------
__global__ __launch_bounds__(512, 2) void gemm256_8p(
    const bf16* __restrict__ A, const bf16* __restrict__ B,
    bf16* __restrict__ C, int M, int N, int K, int lda, int ldb) {
  __shared__ __attribute__((aligned(16))) bf16 SA[2][2][8192];
  __shared__ __attribute__((aligned(16))) bf16 SB[2][2][8192];

  const int tid = threadIdx.x;
  const int wave = tid >> 6;
  const int lane = tid & 63;
  const int lr = lane & 15;
  const int kg = lane >> 4;
  const int wm = (wave >> 2) * 128;  // wave row-block (2)
  const int wn = (wave & 3) * 64;    // wave col-block (4)

  // XCD remap: xcd = bid%8 owns tn in [xcd*g, xcd*g+g), g = tilesN/8.
  const int tilesM = M >> 8;
  const int tilesN = N >> 8;
  int tm, tn;
  if ((tilesN & 7) == 0) {
    const int g = tilesN >> 3;
    const int xcd = blockIdx.x & 7;
    const int j = blockIdx.x >> 3;
    tn = xcd * g + (j % g);
    tm = j / g;
  } else {
    tm = blockIdx.x % tilesM;
    tn = blockIdx.x / tilesM;
  }
  const int rowBase = tm * 256;
  const int colBase = tn * 256;

  // staging geometry: one global_load_lds = 512 thr x 16 B = 8 KB = 128 rows
  // x 32 k; source k pre-swizzled so linear LDS dest matches ds_read XOR.
  const int srow = tid >> 2;
  const int ske = (tid & 3) << 3;
  const int skel = ske ^ (((srow >> 1) & 3) << 3);
  const size_t aRow0 = (size_t)(rowBase + srow) * lda;
  const size_t aRow1 = aRow0 + (size_t)128 * lda;
  const size_t bRow0 = (size_t)(colBase + srow) * ldb;
  const size_t bRow1 = bRow0 + (size_t)128 * ldb;

  const int NT = K >> 6;  // K-tiles of 64

  // frag-read swizzled k offset within a [256][32] region
  const int keSh = (kg << 3) ^ (((lr >> 1) & 3) << 3);

  floatx4 acc[8][4] = {};
  bf16x8 af0[4], af1[4], bgA[4], bgB[4];

  auto stA = [&](int buf, int kh, int kt) {
    const int gk = kt * 64 + kh * 32 + skel;
    bf16* d = &SA[buf][kh][0];
    async16(A + aRow0 + gk, d + tid * 8);
    async16(A + aRow1 + gk, d + 4096 + tid * 8);
  };
  auto stB = [&](int buf, int kh, int kt) {
    const int gk = kt * 64 + kh * 32 + skel;
    bf16* d = &SB[buf][kh][0];
    async16(B + bRow0 + gk, d + tid * 8);
    async16(B + bRow1 + gk, d + 4096 + tid * 8);
  };

#define RD_B(DST, BUF, KH)                                                     \
  _Pragma("unroll") for (int n = 0; n < 4; ++n)                                \
      DST[n] = *(const bf16x8*)&SB[BUF][KH][(wn + n * 16 + lr) * 32 + keSh];
#define RD_A(DST, BUF, KH, MH)                                                 \
  _Pragma("unroll") for (int m = 0; m < 4; ++m)                                \
      DST[m] =                                                                 \
          *(const bf16x8*)&SA[BUF][KH][(wm + ((MH)*4 + m) * 16 + lr) * 32 +    \
                                       keSh];

  // ---- prologue: stage all 7 half-tiles, FULL drain, pre-read PH1 operands.
  stB(0, 0, 0); stA(0, 0, 0); stB(0, 1, 0); stA(0, 1, 0);
  stB(1, 0, 1); stA(1, 0, 1); stB(1, 1, 1);
  asm volatile("s_waitcnt vmcnt(0)" ::: "memory");
  __builtin_amdgcn_s_barrier();
  RD_B(bgA, 0, 0);
  RD_A(af0, 0, 0, 0);

#define PH(RDS, CNT, STG, BGR, AFR, MH, VM)                                    \
  {                                                                            \
    RDS;                                                                       \
    STG;                                                                       \
    __builtin_amdgcn_s_barrier();                                              \
    asm volatile("s_waitcnt lgkmcnt(" #CNT ")" ::: "memory");                  \
    __builtin_amdgcn_sched_barrier(0);                                         \
    __builtin_amdgcn_s_setprio(1);                                             \
    _Pragma("unroll") for (int m = 0; m < 4; ++m)                              \
      _Pragma("unroll") for (int n = 0; n < 4; ++n)                            \
          acc[(MH)*4 + m][n] = __builtin_amdgcn_mfma_f32_16x16x32_bf16(        \
              AFR[m], BGR[n], acc[(MH)*4 + m][n], 0, 0, 0);                    \
    __builtin_amdgcn_s_setprio(0);                                             \
    __builtin_amdgcn_sched_barrier(0);                                         \
    if constexpr (VM) asm volatile("s_waitcnt vmcnt(2)" ::: "memory");         \
    __builtin_amdgcn_s_barrier();                                              \
  }

  for (int it = 0; it < (NT >> 1); ++it) {
    const int T0 = it * 2;
    const int T1 = T0 + 1;
    const int s1 = (T0 + 2 < NT) ? T0 + 2 : NT - 1;
    const int s2 = (T1 + 2 < NT) ? T1 + 2 : NT - 1;

    PH(RD_A(af1, 0, 0, 1), 4, stA(1, 1, T1), bgA, af0, 0, false)  // PH1
    PH(RD_B(bgB, 0, 1); RD_A(af0, 0, 1, 0), 8, stB(0, 0, s1), bgA, af1, 1,
       false)                                                      // PH2
    PH(RD_A(af1, 0, 1, 1), 4, stA(0, 0, s1), bgB, af0, 0, false)  // PH3
    PH(RD_B(bgA, 1, 0); RD_A(af0, 1, 0, 0), 8, stB(0, 1, s1), bgB, af1, 1,
       true)                                                       // PH4
    PH(RD_A(af1, 1, 0, 1), 4, stA(0, 1, s1), bgA, af0, 0, false)  // PH5
    PH(RD_B(bgB, 1, 1); RD_A(af0, 1, 1, 0), 8, stB(1, 0, s2), bgA, af1, 1,
       false)                                                      // PH6
    PH(RD_A(af1, 1, 1, 1), 4, stA(1, 0, s2), bgB, af0, 0, false)  // PH7
    PH(RD_B(bgA, 0, 0); RD_A(af0, 0, 0, 0), 8, stB(1, 1, s2), bgB, af1, 1,
       true)                                                       // PH8
  }
#undef PH
#undef RD_A
#undef RD_B

  asm volatile("s_waitcnt vmcnt(0) lgkmcnt(0)" ::: "memory");

  // epilogue: C/D layout col = lane&15, row = (lane>>4)*4 + reg  [m89]
#pragma unroll
  for (int m = 0; m < 8; ++m) {
#pragma unroll
    for (int n = 0; n < 4; ++n) {
      const int col = colBase + wn + n * 16 + lr;
#pragma unroll
      for (int r = 0; r < 4; ++r) {
        const int row = rowBase + wm + m * 16 + kg * 4 + r;
        C[(size_t)row * N + col] = (bf16)acc[m][n][r];
      }
    }
  }
}

// ---------------------------------------------------------------------------
// Generic "bt" GEMM: C[M,N] = A[M,K_eff] @ B[N,K_eff]^T with row strides
// lda/ldb (elements). AF/BF: f32 operand (VGPR+cvt+ds_write staging) vs bf16
// (async global_load_lds). TM: 128 (4 waves 2x2 of 64x64) or 64 (4 waves 1x4
// of 64x32). BK=32, 256 thr, mfma_f32_16x16x32_bf16.
// EPI: 0 bf16 store | 1 f32 atomicAdd | 2 bf16 softplus(v+bias) |
//      3 f32 (v+bias) | 4 f32 per-z slab stride 524288 (GEMM2 split-K) |
//      5 f32 per-z slab stride 4194304 (GEMM3 split-K, XCD-remapped)
// EPI==5 r7: remap (bx,by) so each B-panel's 16 bx-sharers sit on one XCD
// (xcd = flat%8, independent of z since 256z == 0 mod 8). Requires
// gridDim.y % 8 == 0 (GEMM3: 16).
// ---------------------------------------------------------------------------
template <int EPI, int AF, int BF, int TM>
__global__ __launch_bounds__(256, 4) void gemm_bt(
    const void* __restrict__ Aptr, const void* __restrict__ Bptr,
    void* __restrict__ Cout, const float* __restrict__ bias,
    int M, int N, int K, int lda, int ldb) {
  __shared__ bf16 As[TM * 32];
  __shared__ bf16 Bs[128 * 32];
  const int tid = threadIdx.x;

  int bx = blockIdx.x, by = blockIdx.y;
  if constexpr (EPI == 5) {
    const int f = blockIdx.x + gridDim.x * blockIdx.y;
    const int gy = gridDim.y >> 3;
    const int i = f >> 3;
    by = (f & 7) * gy + (i % gy);
    bx = i / gy;
  }
  const int rowBase = bx * TM;
  const int colBase = by * 128;
  const int kLen = K / gridDim.z;
  const int k0 = blockIdx.z * kLen;
  const int kIters = kLen / 32;

  const int sRow = tid >> 2;
  const int sCol = (tid & 3) << 3;
  const int wave = tid >> 6;
  const int lane = tid & 63;
  constexpr int MI = 4;
  constexpr int NJ = (TM == 128) ? 4 : 2;
  const int wm = (TM == 128) ? ((wave >> 1) << 6) : 0;
  const int wn = (TM == 128) ? ((wave & 1) << 6) : (wave << 5);
  const int lr = lane & 15;
  const int kg = lane >> 4;

  floatx4 acc[MI][NJ] = {};

  for (int kt = 0; kt < kIters; ++kt) {
    const int kk = k0 + kt * 32;
    __syncthreads();  // prev iter's LDS reads done before overwrite
    if constexpr (AF) {
      const float* pa =
          (const float*)Aptr + (size_t)(rowBase + sRow) * lda + kk + sCol;
      *(bf16x8*)&As[tid * 8] = cvt8(pa);
      if constexpr (TM == 128)
        *(bf16x8*)&As[2048 + tid * 8] = cvt8(pa + (size_t)64 * lda);
    } else {
      const bf16* pa =
          (const bf16*)Aptr + (size_t)(rowBase + sRow) * lda + kk + sCol;
      async16(pa, &As[tid * 8]);
      if constexpr (TM == 128)
        async16(pa + (size_t)64 * lda, &As[2048 + tid * 8]);
    }
    if constexpr (BF) {
      const float* pb =
          (const float*)Bptr + (size_t)(colBase + sRow) * ldb + kk + sCol;
      *(bf16x8*)&Bs[tid * 8] = cvt8(pb);
      *(bf16x8*)&Bs[2048 + tid * 8] = cvt8(pb + (size_t)64 * ldb);
    } else {
      const bf16* pb =
          (const bf16*)Bptr + (size_t)(colBase + sRow) * ldb + kk + sCol;
      async16(pb, &Bs[tid * 8]);
      async16(pb + (size_t)64 * ldb, &Bs[2048 + tid * 8]);
    }
    __syncthreads();  // staging complete -> tile visible

    bf16x8 af[MI], bg[NJ];
#pragma unroll
    for (int i = 0; i < MI; ++i)
      af[i] = *(const bf16x8*)&As[(wm + i * 16 + lr) * 32 + kg * 8];
#pragma unroll
    for (int j = 0; j < NJ; ++j)
      bg[j] = *(const bf16x8*)&Bs[(wn + j * 16 + lr) * 32 + kg * 8];
#pragma unroll
    for (int i = 0; i < MI; ++i)
#pragma unroll
      for (int j = 0; j < NJ; ++j)
        acc[i][j] = __builtin_amdgcn_mfma_f32_16x16x32_bf16(af[i], bg[j],
                                                            acc[i][j], 0, 0, 0);
  }

  // epilogue: C/D layout col = lane&15, row = (lane>>4)*4 + reg  [m89]
#pragma unroll
  for (int i = 0; i < MI; ++i) {
#pragma unroll
    for (int j = 0; j < NJ; ++j) {
      const int col = colBase + wn + j * 16 + lr;
      float bv = 0.f;
      if constexpr (EPI == 2 || EPI == 3) bv = bias[col];
#pragma unroll
      for (int r = 0; r < 4; ++r) {
        const int row = rowBase + wm + i * 16 + kg * 4 + r;
        const size_t idx = (size_t)row * N + col;
        float v = acc[i][j][r];
        if constexpr (EPI == 0) {
          ((bf16*)Cout)[idx] = (bf16)v;
        } else if constexpr (EPI == 1) {
          atomicAdd((float*)Cout + idx, v);
        } else if constexpr (EPI == 2) {
          v += bv;
          // softplus = ln(1+e^v); for v>20, ln(1+e^v)==v to f32 precision.
          const float t = __expf(v);
          const float sp = (v > 20.f) ? v : __logf(1.f + t);
          ((bf16*)Cout)[idx] = (bf16)sp;
        } else if constexpr (EPI == 3) {
          ((float*)Cout)[idx] = v + bv;
        } else if constexpr (EPI == 4) {
          // split-K partial: distinct slab per z, no contention
          ((float*)Cout)[(size_t)blockIdx.z * 524288 + idx] = v;
        } else {
          ((float*)Cout)[(size_t)blockIdx.z * 4194304 + idx] = v;
        }
      }
    }
  }
}

// sum 8 split-K partial slabs -> XDBL (2048x256 f32)
__global__ __launch_bounds__(256) void reduce_xdbl(
    const float* __restrict__ part, float* __restrict__ xdbl) {
  const size_t i4 = ((size_t)blockIdx.x * 256 + threadIdx.x) * 4;  // 524288/4
  floatx4 s = {};
#pragma unroll
  for (int z = 0; z < 8; ++z) {
    const floatx4 v = *(const floatx4*)&part[(size_t)z * 524288 + i4];
    s[0] += v[0]; s[1] += v[1]; s[2] += v[2]; s[3] += v[3];
  }
  *(floatx4*)&xdbl[i4] = s;
}

// sum 4 GEMM3 split-K slabs + bias -> out (2048x2048 f32)
__global__ __launch_bounds__(256) void reduce_out4(
    const float* __restrict__ part, const float* __restrict__ bias,
    float* __restrict__ outp) {
  const size_t i4 = ((size_t)blockIdx.x * 256 + threadIdx.x) * 4;  // 4194304/4
  floatx4 s = *(const floatx4*)&bias[i4 & 2047];
#pragma unroll
  for (int z = 0; z < 4; ++z) {
    const floatx4 v = *(const floatx4*)&part[(size_t)z * 4194304 + i4];
    s[0] += v[0]; s[1] += v[1]; s[2] += v[2]; s[3] += v[3];
  }
  *(floatx4*)&outp[i4] = s;
}

// ---------------------------------------------------------------------------
// Fused prep: f32->bf16 casts (hidden|W_in|W_dt|W_out) + W_x pad-cast.
// ---------------------------------------------------------------------------
#define PC0 524288UL    // hidden chunks
#define PC1 2621440UL   // +W_in
#define PC2 2686976UL   // +W_dt
#define PC3 3735552UL   // +W_out
#define PC4 3866624UL   // +WXPAD (dest 256x4096)
__global__ __launch_bounds__(256) void prep_all(
    const float* __restrict__ h, const float* __restrict__ wi,
    const float* __restrict__ wd, const float* __restrict__ wo,
    const float* __restrict__ wx, bf16* __restrict__ hb,
    bf16* __restrict__ wib, bf16* __restrict__ wdb, bf16* __restrict__ wob,
    bf16* __restrict__ wxp) {
  const size_t c = (size_t)blockIdx.x * 256 + threadIdx.x;
  if (c < PC0) {
    const size_t e = c * 8;
    *(bf16x8*)&hb[e] = cvt8(&h[e]);
  } else if (c < PC1) {
    const size_t e = (c - PC0) * 8;
    *(bf16x8*)&wib[e] = cvt8(&wi[e]);
  } else if (c < PC2) {
    const size_t e = (c - PC1) * 8;
    *(bf16x8*)&wdb[e] = cvt8(&wd[e]);
  } else if (c < PC3) {
    const size_t e = (c - PC2) * 8;
    *(bf16x8*)&wob[e] = cvt8(&wo[e]);
  } else if (c < PC4) {
    const size_t e = (c - PC3) * 8;
    if ((e >> 12) < 160) {
      *(bf16x8*)&wxp[e] = cvt8(&wx[e]);
    } else {
      bf16x8 z = {};
      *(bf16x8*)&wxp[e] = z;
    }
  }
}

// W_x pad (fallback path only)
__global__ void wxpad_prep(const float* __restrict__ Wx,
                           bf16* __restrict__ WXPAD) {
  const int idx = blockIdx.x * 256 + threadIdx.x;
  const int row = idx >> 12;
  WXPAD[idx] = (row < 160) ? (bf16)Wx[idx] : (bf16)0.f;
}

// Depthwise causal conv (K=4) + bias + SiLU, x8-vectorized (G13: bf16x8
// loads/stores, 16 B/lane). Each thread: 8 consecutive d at one row.
// Fused conv_state output unchanged.
__global__ __launch_bounds__(256) void conv_v8(
    const bf16* __restrict__ XZ, const float* __restrict__ conv_w,
    const float* __restrict__ conv_b, bf16* __restrict__ XC,
    float* __restrict__ outConv) {
  const int idx = blockIdx.x * 256 + threadIdx.x;  // 0..1048575
  const int d8 = (idx & 511) << 3;
  const int row = idx >> 9;
  const int l = row & 1023;
  float acc[8];
  {
    const floatx4 cb0 = *(const floatx4*)&conv_b[d8];
    const floatx4 cb1 = *(const floatx4*)&conv_b[d8 + 4];
#pragma unroll
    for (int j = 0; j < 4; ++j) { acc[j] = cb0[j]; acc[4 + j] = cb1[j]; }
  }
  float w[8][4];
#pragma unroll
  for (int j = 0; j < 8; ++j) {
    const floatx4 cw = *(const floatx4*)&conv_w[(d8 + j) * 4];
#pragma unroll
    for (int k = 0; k < 4; ++k) w[j][k] = cw[k];
  }
  if (l >= 3) {  // fast path: all 4 taps valid
#pragma unroll
    for (int k = 0; k < 4; ++k) {
      const bf16x8 x = *(const bf16x8*)&XZ[(size_t)(row - 3 + k) * 8192 + d8];
#pragma unroll
      for (int j = 0; j < 8; ++j) acc[j] += w[j][k] * (float)x[j];
    }
  } else {
#pragma unroll
    for (int k = 0; k < 4; ++k) {
      if (l - 3 + k >= 0) {
        const bf16x8 x = *(const bf16x8*)&XZ[(size_t)(row - 3 + k) * 8192 + d8];
#pragma unroll
        for (int j = 0; j < 8; ++j) acc[j] += w[j][k] * (float)x[j];
      }
    }
  }
  bf16x8 o;
#pragma unroll
  for (int j = 0; j < 8; ++j)
    o[j] = (bf16)(acc[j] / (1.f + __expf(-acc[j])));
  *(bf16x8*)&XC[(size_t)row * 4096 + d8] = o;
  if (idx < 4096) {  // conv_state: out[b,dd,k] = x[b, 1020+k, dd]
#pragma unroll
    for (int j = 0; j < 8; ++j) {
      const int e = idx * 8 + j;  // 0..32767
      const int k = e & 3;
      const int dd = (e >> 2) & 4095;
      const int b = e >> 14;
      outConv[e] = (float)XZ[(size_t)(b * 1024 + 1020 + k) * 8192 + dd];
    }
  }
}

// ---------------------------------------------------------------------------
// Chunked parallel scan (32 chunks of 32).
// ---------------------------------------------------------------------------
#define NCH 32
#define CLEN 32
#define LOG2E 1.44269504088896f

__global__ __launch_bounds__(256) void scan_phase1(
    const bf16* __restrict__ DELTA, const bf16* __restrict__ XC,
    const float* __restrict__ XDBL, const float* __restrict__ A_log,
    bf16* __restrict__ P, bf16* __restrict__ Lc) {
  const int bd = blockIdx.x * 256 + threadIdx.x;  // 0..8191
  const int c = blockIdx.y;
  const int b = bd >> 12;
  const int d = bd & 4095;
  float A2[16], st[16], p[16];
#pragma unroll
  for (int n = 0; n < 16; ++n) {
    A2[n] = -__expf(A_log[d * 16 + n]) * LOG2E;
    st[n] = 0.f;
    p[n] = 1.f;
  }
  size_t row = (size_t)b * 1024 + (size_t)c * CLEN;
  for (int t = 0; t < CLEN; ++t, ++row) {
    const float dlt = (float)DELTA[row * 4096 + d];
    const float u = (float)XC[row * 4096 + d];
    const float* __restrict__ Bp = XDBL + row * 256 + 128;  // wave-uniform
    const float du = dlt * u;
#pragma unroll
    for (int n = 0; n < 16; ++n) {
      const float dA = exp2f(dlt * A2[n]);
      st[n] = dA * st[n] + du * Bp[n];
      p[n] *= dA;
    }
  }
  const size_t o = ((size_t)c * 8192 + bd) * 16;
  bf16x8 pk[2], lk[2];
#pragma unroll
  for (int n = 0; n < 16; ++n) {
    pk[n >> 3][n & 7] = (bf16)p[n];
    lk[n >> 3][n & 7] = (bf16)st[n];
  }
  *(bf16x8*)&P[o] = pk[0];
  *(bf16x8*)&P[o + 8] = pk[1];
  *(bf16x8*)&Lc[o] = lk[0];
  *(bf16x8*)&Lc[o + 8] = lk[1];
}

__global__ __launch_bounds__(64) void scan_phase2(
    const bf16* __restrict__ P, const bf16* __restrict__ Lc,
    float* __restrict__ In, float* __restrict__ lastOut) {
  // 128 blocks x 64 thr: 4x the CUs for this latency-bound serial kernel.
  const int bd = blockIdx.x * 64 + threadIdx.x;  // 0..8191
  float st[16] = {};
  for (int c = 0; c < NCH; ++c) {
    const size_t o = ((size_t)c * 8192 + bd) * 16;
    const bf16x8 p0 = *(const bf16x8*)&P[o];
    const bf16x8 p1 = *(const bf16x8*)&P[o + 8];
    const bf16x8 l0 = *(const bf16x8*)&Lc[o];
    const bf16x8 l1 = *(const bf16x8*)&Lc[o + 8];
    floatx4 w[4];
#pragma unroll
    for (int n = 0; n < 16; ++n) w[n >> 2][n & 3] = st[n];
#pragma unroll
    for (int q = 0; q < 4; ++q) *(floatx4*)&In[o + q * 4] = w[q];
#pragma unroll
    for (int n = 0; n < 8; ++n) {
      st[n] = (float)p0[n] * st[n] + (float)l0[n];
      st[8 + n] = (float)p1[n] * st[8 + n] + (float)l1[n];
    }
  }
  const int b = bd >> 12;
  const int d = bd & 4095;
#pragma unroll
  for (int n = 0; n < 16; ++n)
    lastOut[(size_t)b * 65536 + d * 16 + n] = st[n];
}

__global__ __launch_bounds__(256) void scan_phase3(
    const bf16* __restrict__ DELTA, const bf16* __restrict__ XC,
    const bf16* __restrict__ XZ, const float* __restrict__ XDBL,
    const float* __restrict__ A_log, const float* __restrict__ Dp,
    const float* __restrict__ In, bf16* __restrict__ Y) {
  const int bd = blockIdx.x * 256 + threadIdx.x;
  const int c = blockIdx.y;
  const int b = bd >> 12;
  const int d = bd & 4095;
  float A2[16], st[16];
  const size_t o = ((size_t)c * 8192 + bd) * 16;
#pragma unroll
  for (int q = 0; q < 4; ++q) {
    const floatx4 v = *(const floatx4*)&In[o + q * 4];
#pragma unroll
    for (int j = 0; j < 4; ++j) st[q * 4 + j] = v[j];
  }
#pragma unroll
  for (int n = 0; n < 16; ++n)
    A2[n] = -__expf(A_log[d * 16 + n]) * LOG2E;
  const float Dd = Dp[d];
  size_t row = (size_t)b * 1024 + (size_t)c * CLEN;
  for (int t = 0; t < CLEN; ++t, ++row) {
    const float dlt = (float)DELTA[row * 4096 + d];
    const float u = (float)XC[row * 4096 + d];
    const float z = (float)XZ[row * 8192 + 4096 + d];
    const float* __restrict__ Bp = XDBL + row * 256 + 128;
    const float du = dlt * u;
    float y = 0.f;
#pragma unroll
    for (int n = 0; n < 16; ++n) {
      const float dA = exp2f(dlt * A2[n]);
      st[n] = dA * st[n] + du * Bp[n];
      y += st[n] * Bp[16 + n];
    }
    const float sig = 1.f / (1.f + __expf(-z));
    Y[row * 4096 + d] = (bf16)((y + Dd * u) * (z * sig));
  }
}

// ---------------------------------------------------------------------------
// Workspace layout (bytes). DELTA slot holds bf16 DELTA (lower 16.8 MB) and
// the GEMM2 split-K partials (upper 16.8 MB). After scan_phase3, the entire
// XZ+XC+DELTA+PART region (0..83.9 MB) is dead (scan3 is the last reader of
// XZ, XC, DELTA) and is reused as GEMM3's 4 split-K f32 slabs (67 MB),
// which never touch Y (at 83.9 MB, GEMM3's input).
// ---------------------------------------------------------------------------
#define OFF_XZ 0UL                 // bf16 2048x8192
#define OFF_XC 33554432UL          // bf16 2048x4096
#define OFF_DELTA 50331648UL       // bf16 2048x4096 | +16777216: PART f32 8x524288
#define OFF_Y 83886080UL           // bf16 2048x4096
#define OFF_XDBL 100663296UL       // f32  2048x256
#define OFF_WXPAD 103284736UL      // bf16 256x4096
#define OFF_P 105381888UL          // bf16 32x8192x16
#define OFF_L 113770496UL          // bf16 32x8192x16
#define OFF_HBF 122159104UL        // bf16 2048x2048
#define OFF_WINBF 130547712UL      // bf16 8192x2048
#define OFF_WDTBF 164102144UL      // bf16 4096x128
#define OFF_WOUTBF 165150720UL     // bf16 2048x4096
#define WS_NEED_CAST 181927936UL   // ~173.5 MB

extern "C" void kernel_launch(void* const* d_in, const int* in_sizes, int n_in,
                              void* d_out, int out_size, void* d_ws,
                              size_t ws_size, hipStream_t stream) {
  const float* hidden = (const float*)d_in[0];
  const float* W_in = (const float*)d_in[1];
  const float* conv_w = (const float*)d_in[2];
  const float* conv_b = (const float*)d_in[3];
  const float* W_x = (const float*)d_in[4];
  const float* W_dt = (const float*)d_in[5];
  const float* b_dt = (const float*)d_in[6];
  const float* A_log = (const float*)d_in[7];
  const float* Dvec = (const float*)d_in[8];
  const float* W_out = (const float*)d_in[9];
  const float* b_out = (const float*)d_in[10];

  char* ws = (char*)d_ws;
  bf16* XZ = (bf16*)(ws + OFF_XZ);
  bf16* XC = (bf16*)(ws + OFF_XC);
  bf16* DELTA = (bf16*)(ws + OFF_DELTA);
  float* PART = (float*)(ws + OFF_DELTA + 16777216UL);
  float* SLAB3 = (float*)(ws + OFF_XZ);  // 67 MB over dead XZ..PART region
  bf16* Y = (bf16*)(ws + OFF_Y);
  float* XDBL = (float*)(ws + OFF_XDBL);
  bf16* WXPAD = (bf16*)(ws + OFF_WXPAD);
  bf16* P = (bf16*)(ws + OFF_P);
  bf16* Lc = (bf16*)(ws + OFF_L);

  float* out = (float*)d_out;             // (2,1024,2048) = 4194304 f32
  float* out_conv = out + 4194304;        // (2,4096,4)
  float* out_last = out + 4227072;        // (2,4096,16)
  // In (f32, 16.78 MB) parks in the `out` region: written by phase2, read by
  // phase3, then fully overwritten by reduce_out4 (same-stream ordering).
  float* In = out;

  const bool castOK = ws_size >= WS_NEED_CAST;
  if (castOK) {
    bf16* HBF = (bf16*)(ws + OFF_HBF);
    bf16* WINBF = (bf16*)(ws + OFF_WINBF);
    bf16* WDTBF = (bf16*)(ws + OFF_WDTBF);
    bf16* WOUTBF = (bf16*)(ws + OFF_WOUTBF);
    prep_all<<<15104, 256, 0, stream>>>(hidden, W_in, W_dt, W_out, W_x, HBF,
                                        WINBF, WDTBF, WOUTBF, WXPAD);
    // GEMM1: XZ = HBF @ WINBF^T — 8-phase 256^2 template, 256 WGs (1/CU)
    gemm256_8p<<<dim3(256), 512, 0, stream>>>(HBF, WINBF, XZ, 2048, 8192,
                                              2048, 2048, 2048);
    conv_v8<<<4096, 256, 0, stream>>>(XZ, conv_w, conv_b, XC, out_conv);
    // GEMM2 (split-K=8 -> partial slabs, no atomics): PART[z] = XC @ WXPAD^T
    gemm_bt<4, 0, 0, 64><<<dim3(32, 2, 8), 256, 0, stream>>>(
        XC, WXPAD, PART, nullptr, 2048, 256, 4096, 4096, 4096);
    reduce_xdbl<<<512, 256, 0, stream>>>(PART, XDBL);
    // GEMM_dt (TM=64, A = XDBL dt-cols f32 lda=256): DELTA = softplus(.)
    gemm_bt<2, 1, 0, 64><<<dim3(32, 32, 1), 256, 0, stream>>>(
        XDBL, WDTBF, DELTA, b_dt, 2048, 4096, 128, 256, 128);
    scan_phase1<<<dim3(32, NCH), 256, 0, stream>>>(DELTA, XC, XDBL, A_log, P,
                                                   Lc);
    scan_phase2<<<128, 64, 0, stream>>>(P, Lc, In, out_last);
    scan_phase3<<<dim3(32, NCH), 256, 0, stream>>>(DELTA, XC, XZ, XDBL, A_log,
                                                   Dvec, In, Y);
    // GEMM3 split-K=4 (TM=128, 1024 WGs = 4 WGs/CU, XCD-remapped EPI=5):
    // SLAB3[z] = Y @ WOUTBF^T quarters; reduce_out4 sums + bias -> out.
    gemm_bt<5, 0, 0, 128><<<dim3(16, 16, 4), 256, 0, stream>>>(
        Y, WOUTBF, SLAB3, nullptr, 2048, 2048, 4096, 4096, 4096);
    reduce_out4<<<4096, 256, 0, stream>>>(SLAB3, b_out, out);
  } else {
    // fallback: f32-staged GEMMs, no cast buffers
    wxpad_prep<<<4096, 256, 0, stream>>>(W_x, WXPAD);
    gemm_bt<0, 1, 1, 128><<<dim3(16, 64, 1), 256, 0, stream>>>(
        hidden, W_in, XZ, nullptr, 2048, 8192, 2048, 2048, 2048);
    conv_v8<<<4096, 256, 0, stream>>>(XZ, conv_w, conv_b, XC, out_conv);
    gemm_bt<4, 0, 0, 64><<<dim3(32, 2, 8), 256, 0, stream>>>(
        XC, WXPAD, PART, nullptr, 2048, 256, 4096, 4096, 4096);
    reduce_xdbl<<<512, 256, 0, stream>>>(PART, XDBL);
    gemm_bt<2, 1, 1, 64><<<dim3(32, 32, 1), 256, 0, stream>>>(
        XDBL, W_dt, DELTA, b_dt, 2048, 4096, 128, 256, 128);
    scan_phase1<<<dim3(32, NCH), 256, 0, stream>>>(DELTA, XC, XDBL, A_log, P,
                                                   Lc);
    scan_phase2<<<128, 64, 0, stream>>>(P, Lc, In, out_last);
    scan_phase3<<<dim3(32, NCH), 256, 0, stream>>>(DELTA, XC, XZ, XDBL, A_log,
                                                   Dvec, In, Y);
    gemm_bt<5, 0, 1, 128><<<dim3(16, 16, 4), 256, 0, stream>>>(
        Y, W_out, SLAB3, nullptr, 2048, 2048, 4096, 4096, 4096);
    reduce_out4<<<4096, 256, 0, stream>>>(SLAB3, b_out, out);
  }
}

// Round 8
// 469.345 us; speedup vs baseline: 1.1066x; 1.0020x over previous
//
#include <hip/hip_runtime.h>
#include <stdint.h>
#include <stddef.h>

typedef __bf16 bf16;
typedef __attribute__((ext_vector_type(8))) __bf16 bf16x8;
typedef __attribute__((ext_vector_type(4))) float floatx4;

#define GAS __attribute__((address_space(1)))
#define LAS __attribute__((address_space(3)))

__device__ __forceinline__ void async16(const void* g, void* l) {
  __builtin_amdgcn_global_load_lds((const GAS void*)g, (LAS void*)l, 16, 0, 0);
}

__device__ __forceinline__ bf16x8 cvt8(const float* p) {
  floatx4 a = *(const floatx4*)p;
  floatx4 b = *(const floatx4*)(p + 4);
  bf16x8 r;
  r[0] = (bf16)a[0]; r[1] = (bf16)a[1]; r[2] = (bf16)a[2]; r[3] = (bf16)a[3];
  r[4] = (bf16)b[0]; r[5] = (bf16)b[1]; r[6] = (bf16)b[2]; r[7] = (bf16)b[3];
  return r;
}

// ---------------------------------------------------------------------------
// 256x256 8-phase GEMM engine (schedule frozen since r5: 77.7 us @862 TF,
// MfmaUtil 35%, 0 bank conflicts; three schedule variants null).
// r8: (a) mapping reverted to tm=bid%tilesM (r7's B-cluster remap cut FETCH
// 135->49 MB but COST 6% time — GEMM1 is not BW-bound; A-panel XCD clustering
// is what matters). (b) templated on EPI + K-split via blockIdx.y:
//   EPI=0: bf16 C store, full K (GEMM1).
//   EPI=5: f32 slab store at z*4194304, K split gridDim.y ways (GEMM3).
// Only k0 staging offset + epilogue differ; schedule/swizzle/ledger untouched
// (ledger is K-offset-invariant; NT must be even — GEMM1 NT=32, GEMM3 NT=16).
// ---------------------------------------------------------------------------
template <int EPI>
__global__ __launch_bounds__(512, 2) void gemm256_8p(
    const bf16* __restrict__ A, const bf16* __restrict__ B,
    void* __restrict__ C, int M, int N, int K, int lda, int ldb) {
  __shared__ __attribute__((aligned(16))) bf16 SA[2][2][8192];
  __shared__ __attribute__((aligned(16))) bf16 SB[2][2][8192];

  const int tid = threadIdx.x;
  const int wave = tid >> 6;
  const int lane = tid & 63;
  const int lr = lane & 15;
  const int kg = lane >> 4;
  const int wm = (wave >> 2) * 128;  // wave row-block (2)
  const int wn = (wave & 3) * 64;    // wave col-block (4)

  // XCD mapping (measured-fast r5 form): HW XCD = flat%8; tm=bid%8 clusters
  // each A-panel's sharers on one XCD. (For EPI=5, flat = x + 64*y keeps
  // xcd = x%8 = tm — same clustering, z-independent.)
  const int tilesM = M >> 8;
  const int tm = blockIdx.x % tilesM;
  const int tn = blockIdx.x / tilesM;
  const int rowBase = tm * 256;
  const int colBase = tn * 256;

  // K-split (EPI=5): z = blockIdx.y
  const int kLen = K / gridDim.y;
  const int k0 = blockIdx.y * kLen;
  const int NT = kLen >> 6;  // K-tiles of 64 (must be even)

  // staging geometry: one global_load_lds = 512 thr x 16 B = 8 KB = 128 rows
  // x 32 k; source k pre-swizzled so linear LDS dest matches ds_read XOR.
  const int srow = tid >> 2;
  const int ske = (tid & 3) << 3;
  const int skel = ske ^ (((srow >> 1) & 3) << 3);
  const size_t aRow0 = (size_t)(rowBase + srow) * lda;
  const size_t aRow1 = aRow0 + (size_t)128 * lda;
  const size_t bRow0 = (size_t)(colBase + srow) * ldb;
  const size_t bRow1 = bRow0 + (size_t)128 * ldb;

  // frag-read swizzled k offset within a [256][32] region
  const int keSh = (kg << 3) ^ (((lr >> 1) & 3) << 3);

  floatx4 acc[8][4] = {};
  bf16x8 af0[4], af1[4], bgA[4], bgB[4];

  auto stA = [&](int buf, int kh, int kt) {
    const int gk = k0 + kt * 64 + kh * 32 + skel;
    bf16* d = &SA[buf][kh][0];
    async16(A + aRow0 + gk, d + tid * 8);
    async16(A + aRow1 + gk, d + 4096 + tid * 8);
  };
  auto stB = [&](int buf, int kh, int kt) {
    const int gk = k0 + kt * 64 + kh * 32 + skel;
    bf16* d = &SB[buf][kh][0];
    async16(B + bRow0 + gk, d + tid * 8);
    async16(B + bRow1 + gk, d + 4096 + tid * 8);
  };

#define RD_B(DST, BUF, KH)                                                     \
  _Pragma("unroll") for (int n = 0; n < 4; ++n)                                \
      DST[n] = *(const bf16x8*)&SB[BUF][KH][(wn + n * 16 + lr) * 32 + keSh];
#define RD_A(DST, BUF, KH, MH)                                                 \
  _Pragma("unroll") for (int m = 0; m < 4; ++m)                                \
      DST[m] =                                                                 \
          *(const bf16x8*)&SA[BUF][KH][(wm + ((MH)*4 + m) * 16 + lr) * 32 +    \
                                       keSh];

  // ---- prologue: stage all 7 half-tiles, FULL drain, pre-read PH1 operands.
  stB(0, 0, 0); stA(0, 0, 0); stB(0, 1, 0); stA(0, 1, 0);
  stB(1, 0, 1); stA(1, 0, 1); stB(1, 1, 1);
  asm volatile("s_waitcnt vmcnt(0)" ::: "memory");
  __builtin_amdgcn_s_barrier();
  RD_B(bgA, 0, 0);
  RD_A(af0, 0, 0, 0);

#define PH(RDS, CNT, STG, BGR, AFR, MH, VM)                                    \
  {                                                                            \
    RDS;                                                                       \
    STG;                                                                       \
    __builtin_amdgcn_s_barrier();                                              \
    asm volatile("s_waitcnt lgkmcnt(" #CNT ")" ::: "memory");                  \
    __builtin_amdgcn_sched_barrier(0);                                         \
    __builtin_amdgcn_s_setprio(1);                                             \
    _Pragma("unroll") for (int m = 0; m < 4; ++m)                              \
      _Pragma("unroll") for (int n = 0; n < 4; ++n)                            \
          acc[(MH)*4 + m][n] = __builtin_amdgcn_mfma_f32_16x16x32_bf16(        \
              AFR[m], BGR[n], acc[(MH)*4 + m][n], 0, 0, 0);                    \
    __builtin_amdgcn_s_setprio(0);                                             \
    __builtin_amdgcn_sched_barrier(0);                                         \
    if constexpr (VM) asm volatile("s_waitcnt vmcnt(2)" ::: "memory");         \
    __builtin_amdgcn_s_barrier();                                              \
  }

  for (int it = 0; it < (NT >> 1); ++it) {
    const int T0 = it * 2;
    const int T1 = T0 + 1;
    const int s1 = (T0 + 2 < NT) ? T0 + 2 : NT - 1;
    const int s2 = (T1 + 2 < NT) ? T1 + 2 : NT - 1;

    PH(RD_A(af1, 0, 0, 1), 4, stA(1, 1, T1), bgA, af0, 0, false)  // PH1
    PH(RD_B(bgB, 0, 1); RD_A(af0, 0, 1, 0), 8, stB(0, 0, s1), bgA, af1, 1,
       false)                                                      // PH2
    PH(RD_A(af1, 0, 1, 1), 4, stA(0, 0, s1), bgB, af0, 0, false)  // PH3
    PH(RD_B(bgA, 1, 0); RD_A(af0, 1, 0, 0), 8, stB(0, 1, s1), bgB, af1, 1,
       true)                                                       // PH4
    PH(RD_A(af1, 1, 0, 1), 4, stA(0, 1, s1), bgA, af0, 0, false)  // PH5
    PH(RD_B(bgB, 1, 1); RD_A(af0, 1, 1, 0), 8, stB(1, 0, s2), bgA, af1, 1,
       false)                                                      // PH6
    PH(RD_A(af1, 1, 1, 1), 4, stA(1, 0, s2), bgB, af0, 0, false)  // PH7
    PH(RD_B(bgA, 0, 0); RD_A(af0, 0, 0, 0), 8, stB(1, 1, s2), bgB, af1, 1,
       true)                                                       // PH8
  }
#undef PH
#undef RD_A
#undef RD_B

  asm volatile("s_waitcnt vmcnt(0) lgkmcnt(0)" ::: "memory");

  // epilogue: C/D layout col = lane&15, row = (lane>>4)*4 + reg  [m89]
#pragma unroll
  for (int m = 0; m < 8; ++m) {
#pragma unroll
    for (int n = 0; n < 4; ++n) {
      const int col = colBase + wn + n * 16 + lr;
#pragma unroll
      for (int r = 0; r < 4; ++r) {
        const int row = rowBase + wm + m * 16 + kg * 4 + r;
        const size_t idx = (size_t)row * N + col;
        if constexpr (EPI == 0) {
          ((bf16*)C)[idx] = (bf16)acc[m][n][r];
        } else {
          ((float*)C)[(size_t)blockIdx.y * 4194304 + idx] = acc[m][n][r];
        }
      }
    }
  }
}

// ---------------------------------------------------------------------------
// Generic "bt" GEMM: C[M,N] = A[M,K_eff] @ B[N,K_eff]^T with row strides
// lda/ldb (elements). AF/BF: f32 operand (VGPR+cvt+ds_write staging) vs bf16
// (async global_load_lds). TM: 128 (4 waves 2x2 of 64x64) or 64 (4 waves 1x4
// of 64x32). BK=32, 256 thr, mfma_f32_16x16x32_bf16.
// EPI: 0 bf16 store | 1 f32 atomicAdd | 2 bf16 softplus(v+bias) |
//      3 f32 (v+bias) | 4 f32 per-z slab stride 524288 (GEMM2 split-K) |
//      5 f32 per-z slab stride 4194304 (fallback GEMM3 split-K, XCD-remapped)
// ---------------------------------------------------------------------------
template <int EPI, int AF, int BF, int TM>
__global__ __launch_bounds__(256, 4) void gemm_bt(
    const void* __restrict__ Aptr, const void* __restrict__ Bptr,
    void* __restrict__ Cout, const float* __restrict__ bias,
    int M, int N, int K, int lda, int ldb) {
  __shared__ bf16 As[TM * 32];
  __shared__ bf16 Bs[128 * 32];
  const int tid = threadIdx.x;

  int bx = blockIdx.x, by = blockIdx.y;
  if constexpr (EPI == 5) {
    const int f = blockIdx.x + gridDim.x * blockIdx.y;
    const int gy = gridDim.y >> 3;
    const int i = f >> 3;
    by = (f & 7) * gy + (i % gy);
    bx = i / gy;
  }
  const int rowBase = bx * TM;
  const int colBase = by * 128;
  const int kLen = K / gridDim.z;
  const int k0 = blockIdx.z * kLen;
  const int kIters = kLen / 32;

  const int sRow = tid >> 2;
  const int sCol = (tid & 3) << 3;
  const int wave = tid >> 6;
  const int lane = tid & 63;
  constexpr int MI = 4;
  constexpr int NJ = (TM == 128) ? 4 : 2;
  const int wm = (TM == 128) ? ((wave >> 1) << 6) : 0;
  const int wn = (TM == 128) ? ((wave & 1) << 6) : (wave << 5);
  const int lr = lane & 15;
  const int kg = lane >> 4;

  floatx4 acc[MI][NJ] = {};

  for (int kt = 0; kt < kIters; ++kt) {
    const int kk = k0 + kt * 32;
    __syncthreads();  // prev iter's LDS reads done before overwrite
    if constexpr (AF) {
      const float* pa =
          (const float*)Aptr + (size_t)(rowBase + sRow) * lda + kk + sCol;
      *(bf16x8*)&As[tid * 8] = cvt8(pa);
      if constexpr (TM == 128)
        *(bf16x8*)&As[2048 + tid * 8] = cvt8(pa + (size_t)64 * lda);
    } else {
      const bf16* pa =
          (const bf16*)Aptr + (size_t)(rowBase + sRow) * lda + kk + sCol;
      async16(pa, &As[tid * 8]);
      if constexpr (TM == 128)
        async16(pa + (size_t)64 * lda, &As[2048 + tid * 8]);
    }
    if constexpr (BF) {
      const float* pb =
          (const float*)Bptr + (size_t)(colBase + sRow) * ldb + kk + sCol;
      *(bf16x8*)&Bs[tid * 8] = cvt8(pb);
      *(bf16x8*)&Bs[2048 + tid * 8] = cvt8(pb + (size_t)64 * ldb);
    } else {
      const bf16* pb =
          (const bf16*)Bptr + (size_t)(colBase + sRow) * ldb + kk + sCol;
      async16(pb, &Bs[tid * 8]);
      async16(pb + (size_t)64 * ldb, &Bs[2048 + tid * 8]);
    }
    __syncthreads();  // staging complete -> tile visible

    bf16x8 af[MI], bg[NJ];
#pragma unroll
    for (int i = 0; i < MI; ++i)
      af[i] = *(const bf16x8*)&As[(wm + i * 16 + lr) * 32 + kg * 8];
#pragma unroll
    for (int j = 0; j < NJ; ++j)
      bg[j] = *(const bf16x8*)&Bs[(wn + j * 16 + lr) * 32 + kg * 8];
#pragma unroll
    for (int i = 0; i < MI; ++i)
#pragma unroll
      for (int j = 0; j < NJ; ++j)
        acc[i][j] = __builtin_amdgcn_mfma_f32_16x16x32_bf16(af[i], bg[j],
                                                            acc[i][j], 0, 0, 0);
  }

  // epilogue: C/D layout col = lane&15, row = (lane>>4)*4 + reg  [m89]
#pragma unroll
  for (int i = 0; i < MI; ++i) {
#pragma unroll
    for (int j = 0; j < NJ; ++j) {
      const int col = colBase + wn + j * 16 + lr;
      float bv = 0.f;
      if constexpr (EPI == 2 || EPI == 3) bv = bias[col];
#pragma unroll
      for (int r = 0; r < 4; ++r) {
        const int row = rowBase + wm + i * 16 + kg * 4 + r;
        const size_t idx = (size_t)row * N + col;
        float v = acc[i][j][r];
        if constexpr (EPI == 0) {
          ((bf16*)Cout)[idx] = (bf16)v;
        } else if constexpr (EPI == 1) {
          atomicAdd((float*)Cout + idx, v);
        } else if constexpr (EPI == 2) {
          v += bv;
          // softplus = ln(1+e^v); for v>20, ln(1+e^v)==v to f32 precision.
          const float t = __expf(v);
          const float sp = (v > 20.f) ? v : __logf(1.f + t);
          ((bf16*)Cout)[idx] = (bf16)sp;
        } else if constexpr (EPI == 3) {
          ((float*)Cout)[idx] = v + bv;
        } else if constexpr (EPI == 4) {
          // split-K partial: distinct slab per z, no contention
          ((float*)Cout)[(size_t)blockIdx.z * 524288 + idx] = v;
        } else {
          ((float*)Cout)[(size_t)blockIdx.z * 4194304 + idx] = v;
        }
      }
    }
  }
}

// sum 8 split-K partial slabs -> XDBL (2048x256 f32)
__global__ __launch_bounds__(256) void reduce_xdbl(
    const float* __restrict__ part, float* __restrict__ xdbl) {
  const size_t i4 = ((size_t)blockIdx.x * 256 + threadIdx.x) * 4;  // 524288/4
  floatx4 s = {};
#pragma unroll
  for (int z = 0; z < 8; ++z) {
    const floatx4 v = *(const floatx4*)&part[(size_t)z * 524288 + i4];
    s[0] += v[0]; s[1] += v[1]; s[2] += v[2]; s[3] += v[3];
  }
  *(floatx4*)&xdbl[i4] = s;
}

// sum 4 GEMM3 split-K slabs + bias -> out (2048x2048 f32)
__global__ __launch_bounds__(256) void reduce_out4(
    const float* __restrict__ part, const float* __restrict__ bias,
    float* __restrict__ outp) {
  const size_t i4 = ((size_t)blockIdx.x * 256 + threadIdx.x) * 4;  // 4194304/4
  floatx4 s = *(const floatx4*)&bias[i4 & 2047];
#pragma unroll
  for (int z = 0; z < 4; ++z) {
    const floatx4 v = *(const floatx4*)&part[(size_t)z * 4194304 + i4];
    s[0] += v[0]; s[1] += v[1]; s[2] += v[2]; s[3] += v[3];
  }
  *(floatx4*)&outp[i4] = s;
}

// ---------------------------------------------------------------------------
// Fused prep: f32->bf16 casts (hidden|W_in|W_dt|W_out) + W_x pad-cast.
// ---------------------------------------------------------------------------
#define PC0 524288UL    // hidden chunks
#define PC1 2621440UL   // +W_in
#define PC2 2686976UL   // +W_dt
#define PC3 3735552UL   // +W_out
#define PC4 3866624UL   // +WXPAD (dest 256x4096)
__global__ __launch_bounds__(256) void prep_all(
    const float* __restrict__ h, const float* __restrict__ wi,
    const float* __restrict__ wd, const float* __restrict__ wo,
    const float* __restrict__ wx, bf16* __restrict__ hb,
    bf16* __restrict__ wib, bf16* __restrict__ wdb, bf16* __restrict__ wob,
    bf16* __restrict__ wxp) {
  const size_t c = (size_t)blockIdx.x * 256 + threadIdx.x;
  if (c < PC0) {
    const size_t e = c * 8;
    *(bf16x8*)&hb[e] = cvt8(&h[e]);
  } else if (c < PC1) {
    const size_t e = (c - PC0) * 8;
    *(bf16x8*)&wib[e] = cvt8(&wi[e]);
  } else if (c < PC2) {
    const size_t e = (c - PC1) * 8;
    *(bf16x8*)&wdb[e] = cvt8(&wd[e]);
  } else if (c < PC3) {
    const size_t e = (c - PC2) * 8;
    *(bf16x8*)&wob[e] = cvt8(&wo[e]);
  } else if (c < PC4) {
    const size_t e = (c - PC3) * 8;
    if ((e >> 12) < 160) {
      *(bf16x8*)&wxp[e] = cvt8(&wx[e]);
    } else {
      bf16x8 z = {};
      *(bf16x8*)&wxp[e] = z;
    }
  }
}

// W_x pad (fallback path only)
__global__ void wxpad_prep(const float* __restrict__ Wx,
                           bf16* __restrict__ WXPAD) {
  const int idx = blockIdx.x * 256 + threadIdx.x;
  const int row = idx >> 12;
  WXPAD[idx] = (row < 160) ? (bf16)Wx[idx] : (bf16)0.f;
}

// Depthwise causal conv (K=4) + bias + SiLU, x8-vectorized (G13: bf16x8
// loads/stores, 16 B/lane). Each thread: 8 consecutive d at one row.
// Fused conv_state output unchanged.
__global__ __launch_bounds__(256) void conv_v8(
    const bf16* __restrict__ XZ, const float* __restrict__ conv_w,
    const float* __restrict__ conv_b, bf16* __restrict__ XC,
    float* __restrict__ outConv) {
  const int idx = blockIdx.x * 256 + threadIdx.x;  // 0..1048575
  const int d8 = (idx & 511) << 3;
  const int row = idx >> 9;
  const int l = row & 1023;
  float acc[8];
  {
    const floatx4 cb0 = *(const floatx4*)&conv_b[d8];
    const floatx4 cb1 = *(const floatx4*)&conv_b[d8 + 4];
#pragma unroll
    for (int j = 0; j < 4; ++j) { acc[j] = cb0[j]; acc[4 + j] = cb1[j]; }
  }
  float w[8][4];
#pragma unroll
  for (int j = 0; j < 8; ++j) {
    const floatx4 cw = *(const floatx4*)&conv_w[(d8 + j) * 4];
#pragma unroll
    for (int k = 0; k < 4; ++k) w[j][k] = cw[k];
  }
  if (l >= 3) {  // fast path: all 4 taps valid
#pragma unroll
    for (int k = 0; k < 4; ++k) {
      const bf16x8 x = *(const bf16x8*)&XZ[(size_t)(row - 3 + k) * 8192 + d8];
#pragma unroll
      for (int j = 0; j < 8; ++j) acc[j] += w[j][k] * (float)x[j];
    }
  } else {
#pragma unroll
    for (int k = 0; k < 4; ++k) {
      if (l - 3 + k >= 0) {
        const bf16x8 x = *(const bf16x8*)&XZ[(size_t)(row - 3 + k) * 8192 + d8];
#pragma unroll
        for (int j = 0; j < 8; ++j) acc[j] += w[j][k] * (float)x[j];
      }
    }
  }
  bf16x8 o;
#pragma unroll
  for (int j = 0; j < 8; ++j)
    o[j] = (bf16)(acc[j] / (1.f + __expf(-acc[j])));
  *(bf16x8*)&XC[(size_t)row * 4096 + d8] = o;
  if (idx < 4096) {  // conv_state: out[b,dd,k] = x[b, 1020+k, dd]
#pragma unroll
    for (int j = 0; j < 8; ++j) {
      const int e = idx * 8 + j;  // 0..32767
      const int k = e & 3;
      const int dd = (e >> 2) & 4095;
      const int b = e >> 14;
      outConv[e] = (float)XZ[(size_t)(b * 1024 + 1020 + k) * 8192 + dd];
    }
  }
}

// ---------------------------------------------------------------------------
// Chunked parallel scan (32 chunks of 32).
// ---------------------------------------------------------------------------
#define NCH 32
#define CLEN 32
#define LOG2E 1.44269504088896f

__global__ __launch_bounds__(256) void scan_phase1(
    const bf16* __restrict__ DELTA, const bf16* __restrict__ XC,
    const float* __restrict__ XDBL, const float* __restrict__ A_log,
    bf16* __restrict__ P, bf16* __restrict__ Lc) {
  const int bd = blockIdx.x * 256 + threadIdx.x;  // 0..8191
  const int c = blockIdx.y;
  const int b = bd >> 12;
  const int d = bd & 4095;
  float A2[16], st[16], p[16];
#pragma unroll
  for (int n = 0; n < 16; ++n) {
    A2[n] = -__expf(A_log[d * 16 + n]) * LOG2E;
    st[n] = 0.f;
    p[n] = 1.f;
  }
  size_t row = (size_t)b * 1024 + (size_t)c * CLEN;
  for (int t = 0; t < CLEN; ++t, ++row) {
    const float dlt = (float)DELTA[row * 4096 + d];
    const float u = (float)XC[row * 4096 + d];
    const float* __restrict__ Bp = XDBL + row * 256 + 128;  // wave-uniform
    const float du = dlt * u;
#pragma unroll
    for (int n = 0; n < 16; ++n) {
      const float dA = exp2f(dlt * A2[n]);
      st[n] = dA * st[n] + du * Bp[n];
      p[n] *= dA;
    }
  }
  const size_t o = ((size_t)c * 8192 + bd) * 16;
  bf16x8 pk[2], lk[2];
#pragma unroll
  for (int n = 0; n < 16; ++n) {
    pk[n >> 3][n & 7] = (bf16)p[n];
    lk[n >> 3][n & 7] = (bf16)st[n];
  }
  *(bf16x8*)&P[o] = pk[0];
  *(bf16x8*)&P[o + 8] = pk[1];
  *(bf16x8*)&Lc[o] = lk[0];
  *(bf16x8*)&Lc[o + 8] = lk[1];
}

__global__ __launch_bounds__(64) void scan_phase2(
    const bf16* __restrict__ P, const bf16* __restrict__ Lc,
    float* __restrict__ In, float* __restrict__ lastOut) {
  // 128 blocks x 64 thr: 4x the CUs for this latency-bound serial kernel.
  const int bd = blockIdx.x * 64 + threadIdx.x;  // 0..8191
  float st[16] = {};
  for (int c = 0; c < NCH; ++c) {
    const size_t o = ((size_t)c * 8192 + bd) * 16;
    const bf16x8 p0 = *(const bf16x8*)&P[o];
    const bf16x8 p1 = *(const bf16x8*)&P[o + 8];
    const bf16x8 l0 = *(const bf16x8*)&Lc[o];
    const bf16x8 l1 = *(const bf16x8*)&Lc[o + 8];
    floatx4 w[4];
#pragma unroll
    for (int n = 0; n < 16; ++n) w[n >> 2][n & 3] = st[n];
#pragma unroll
    for (int q = 0; q < 4; ++q) *(floatx4*)&In[o + q * 4] = w[q];
#pragma unroll
    for (int n = 0; n < 8; ++n) {
      st[n] = (float)p0[n] * st[n] + (float)l0[n];
      st[8 + n] = (float)p1[n] * st[8 + n] + (float)l1[n];
    }
  }
  const int b = bd >> 12;
  const int d = bd & 4095;
#pragma unroll
  for (int n = 0; n < 16; ++n)
    lastOut[(size_t)b * 65536 + d * 16 + n] = st[n];
}

__global__ __launch_bounds__(256) void scan_phase3(
    const bf16* __restrict__ DELTA, const bf16* __restrict__ XC,
    const bf16* __restrict__ XZ, const float* __restrict__ XDBL,
    const float* __restrict__ A_log, const float* __restrict__ Dp,
    const float* __restrict__ In, bf16* __restrict__ Y) {
  const int bd = blockIdx.x * 256 + threadIdx.x;
  const int c = blockIdx.y;
  const int b = bd >> 12;
  const int d = bd & 4095;
  float A2[16], st[16];
  const size_t o = ((size_t)c * 8192 + bd) * 16;
#pragma unroll
  for (int q = 0; q < 4; ++q) {
    const floatx4 v = *(const floatx4*)&In[o + q * 4];
#pragma unroll
    for (int j = 0; j < 4; ++j) st[q * 4 + j] = v[j];
  }
#pragma unroll
  for (int n = 0; n < 16; ++n)
    A2[n] = -__expf(A_log[d * 16 + n]) * LOG2E;
  const float Dd = Dp[d];
  size_t row = (size_t)b * 1024 + (size_t)c * CLEN;
  for (int t = 0; t < CLEN; ++t, ++row) {
    const float dlt = (float)DELTA[row * 4096 + d];
    const float u = (float)XC[row * 4096 + d];
    const float z = (float)XZ[row * 8192 + 4096 + d];
    const float* __restrict__ Bp = XDBL + row * 256 + 128;
    const float du = dlt * u;
    float y = 0.f;
#pragma unroll
    for (int n = 0; n < 16; ++n) {
      const float dA = exp2f(dlt * A2[n]);
      st[n] = dA * st[n] + du * Bp[n];
      y += st[n] * Bp[16 + n];
    }
    const float sig = 1.f / (1.f + __expf(-z));
    Y[row * 4096 + d] = (bf16)((y + Dd * u) * (z * sig));
  }
}

// ---------------------------------------------------------------------------
// Workspace layout (bytes). DELTA slot holds bf16 DELTA (lower 16.8 MB) and
// the GEMM2 split-K partials (upper 16.8 MB). After scan_phase3, the entire
// XZ+XC+DELTA+PART region (0..83.9 MB) is dead (scan3 is the last reader of
// XZ, XC, DELTA) and is reused as GEMM3's 4 split-K f32 slabs (67 MB),
// which never touch Y (at 83.9 MB, GEMM3's input).
// ---------------------------------------------------------------------------
#define OFF_XZ 0UL                 // bf16 2048x8192
#define OFF_XC 33554432UL          // bf16 2048x4096
#define OFF_DELTA 50331648UL       // bf16 2048x4096 | +16777216: PART f32 8x524288
#define OFF_Y 83886080UL           // bf16 2048x4096
#define OFF_XDBL 100663296UL       // f32  2048x256
#define OFF_WXPAD 103284736UL      // bf16 256x4096
#define OFF_P 105381888UL          // bf16 32x8192x16
#define OFF_L 113770496UL          // bf16 32x8192x16
#define OFF_HBF 122159104UL        // bf16 2048x2048
#define OFF_WINBF 130547712UL      // bf16 8192x2048
#define OFF_WDTBF 164102144UL      // bf16 4096x128
#define OFF_WOUTBF 165150720UL     // bf16 2048x4096
#define WS_NEED_CAST 181927936UL   // ~173.5 MB

extern "C" void kernel_launch(void* const* d_in, const int* in_sizes, int n_in,
                              void* d_out, int out_size, void* d_ws,
                              size_t ws_size, hipStream_t stream) {
  const float* hidden = (const float*)d_in[0];
  const float* W_in = (const float*)d_in[1];
  const float* conv_w = (const float*)d_in[2];
  const float* conv_b = (const float*)d_in[3];
  const float* W_x = (const float*)d_in[4];
  const float* W_dt = (const float*)d_in[5];
  const float* b_dt = (const float*)d_in[6];
  const float* A_log = (const float*)d_in[7];
  const float* Dvec = (const float*)d_in[8];
  const float* W_out = (const float*)d_in[9];
  const float* b_out = (const float*)d_in[10];

  char* ws = (char*)d_ws;
  bf16* XZ = (bf16*)(ws + OFF_XZ);
  bf16* XC = (bf16*)(ws + OFF_XC);
  bf16* DELTA = (bf16*)(ws + OFF_DELTA);
  float* PART = (float*)(ws + OFF_DELTA + 16777216UL);
  float* SLAB3 = (float*)(ws + OFF_XZ);  // 67 MB over dead XZ..PART region
  bf16* Y = (bf16*)(ws + OFF_Y);
  float* XDBL = (float*)(ws + OFF_XDBL);
  bf16* WXPAD = (bf16*)(ws + OFF_WXPAD);
  bf16* P = (bf16*)(ws + OFF_P);
  bf16* Lc = (bf16*)(ws + OFF_L);

  float* out = (float*)d_out;             // (2,1024,2048) = 4194304 f32
  float* out_conv = out + 4194304;        // (2,4096,4)
  float* out_last = out + 4227072;        // (2,4096,16)
  // In (f32, 16.78 MB) parks in the `out` region: written by phase2, read by
  // phase3, then fully overwritten by reduce_out4 (same-stream ordering).
  float* In = out;

  const bool castOK = ws_size >= WS_NEED_CAST;
  if (castOK) {
    bf16* HBF = (bf16*)(ws + OFF_HBF);
    bf16* WINBF = (bf16*)(ws + OFF_WINBF);
    bf16* WDTBF = (bf16*)(ws + OFF_WDTBF);
    bf16* WOUTBF = (bf16*)(ws + OFF_WOUTBF);
    prep_all<<<15104, 256, 0, stream>>>(hidden, W_in, W_dt, W_out, W_x, HBF,
                                        WINBF, WDTBF, WOUTBF, WXPAD);
    // GEMM1: XZ = HBF @ WINBF^T — 8-phase 256^2 engine, 256 WGs (1/CU)
    gemm256_8p<0><<<dim3(256, 1), 512, 0, stream>>>(HBF, WINBF, XZ, 2048,
                                                    8192, 2048, 2048, 2048);
    conv_v8<<<4096, 256, 0, stream>>>(XZ, conv_w, conv_b, XC, out_conv);
    // GEMM2 (split-K=8 -> partial slabs, no atomics): PART[z] = XC @ WXPAD^T
    gemm_bt<4, 0, 0, 64><<<dim3(32, 2, 8), 256, 0, stream>>>(
        XC, WXPAD, PART, nullptr, 2048, 256, 4096, 4096, 4096);
    reduce_xdbl<<<512, 256, 0, stream>>>(PART, XDBL);
    // GEMM_dt (TM=64, A = XDBL dt-cols f32 lda=256): DELTA = softplus(.)
    gemm_bt<2, 1, 0, 64><<<dim3(32, 32, 1), 256, 0, stream>>>(
        XDBL, WDTBF, DELTA, b_dt, 2048, 4096, 128, 256, 128);
    scan_phase1<<<dim3(32, NCH), 256, 0, stream>>>(DELTA, XC, XDBL, A_log, P,
                                                   Lc);
    scan_phase2<<<128, 64, 0, stream>>>(P, Lc, In, out_last);
    scan_phase3<<<dim3(32, NCH), 256, 0, stream>>>(DELTA, XC, XZ, XDBL, A_log,
                                                   Dvec, In, Y);
    // GEMM3 on the 8-phase engine, split-K=4 via blockIdx.y (64 tiles x 4 z
    // = 256 WGs, kLen=1024, NT=16): SLAB3[z] = Y @ WOUTBF^T quarters;
    // reduce_out4 sums + bias -> out.
    gemm256_8p<5><<<dim3(64, 4), 512, 0, stream>>>(Y, WOUTBF, SLAB3, 2048,
                                                   2048, 4096, 4096, 4096);
    reduce_out4<<<4096, 256, 0, stream>>>(SLAB3, b_out, out);
  } else {
    // fallback: f32-staged GEMMs, no cast buffers
    wxpad_prep<<<4096, 256, 0, stream>>>(W_x, WXPAD);
    gemm_bt<0, 1, 1, 128><<<dim3(16, 64, 1), 256, 0, stream>>>(
        hidden, W_in, XZ, nullptr, 2048, 8192, 2048, 2048, 2048);
    conv_v8<<<4096, 256, 0, stream>>>(XZ, conv_w, conv_b, XC, out_conv);
    gemm_bt<4, 0, 0, 64><<<dim3(32, 2, 8), 256, 0, stream>>>(
        XC, WXPAD, PART, nullptr, 2048, 256, 4096, 4096, 4096);
    reduce_xdbl<<<512, 256, 0, stream>>>(PART, XDBL);
    gemm_bt<2, 1, 1, 64><<<dim3(32, 32, 1), 256, 0, stream>>>(
        XDBL, W_dt, DELTA, b_dt, 2048, 4096, 128, 256, 128);
    scan_phase1<<<dim3(32, NCH), 256, 0, stream>>>(DELTA, XC, XDBL, A_log, P,
                                                   Lc);
    scan_phase2<<<128, 64, 0, stream>>>(P, Lc, In, out_last);
    scan_phase3<<<dim3(32, NCH), 256, 0, stream>>>(DELTA, XC, XZ, XDBL, A_log,
                                                   Dvec, In, Y);
    gemm_bt<5, 0, 1, 128><<<dim3(16, 16, 4), 256, 0, stream>>>(
        Y, W_out, SLAB3, nullptr, 2048, 2048, 4096, 4096, 4096);
    reduce_out4<<<4096, 256, 0, stream>>>(SLAB3, b_out, out);
  }
}

// Round 9
// 441.034 us; speedup vs baseline: 1.1776x; 1.0642x over previous
//
#include <hip/hip_runtime.h>
#include <stdint.h>
#include <stddef.h>

typedef __bf16 bf16;
typedef __attribute__((ext_vector_type(2))) __bf16 bf16x2;
typedef __attribute__((ext_vector_type(4))) __bf16 bf16x4;
typedef __attribute__((ext_vector_type(8))) __bf16 bf16x8;
typedef __attribute__((ext_vector_type(4))) float floatx4;

#define GAS __attribute__((address_space(1)))
#define LAS __attribute__((address_space(3)))

__device__ __forceinline__ void async16(const void* g, void* l) {
  __builtin_amdgcn_global_load_lds((const GAS void*)g, (LAS void*)l, 16, 0, 0);
}

__device__ __forceinline__ bf16x8 cvt8(const float* p) {
  floatx4 a = *(const floatx4*)p;
  floatx4 b = *(const floatx4*)(p + 4);
  bf16x8 r;
  r[0] = (bf16)a[0]; r[1] = (bf16)a[1]; r[2] = (bf16)a[2]; r[3] = (bf16)a[3];
  r[4] = (bf16)b[0]; r[5] = (bf16)b[1]; r[6] = (bf16)b[2]; r[7] = (bf16)b[3];
  return r;
}

// ---------------------------------------------------------------------------
// 256x256 8-phase GEMM engine (schedule frozen since r5: 77.7 us @862 TF,
// MfmaUtil 35%, 0 bank conflicts; three schedule variants null; r7 B-cluster
// remap cut FETCH 135->49 MB but cost 6% — NOT BW-bound, keep tm=bid%8).
// EPI=0: bf16 C store, full K (GEMM1).
// EPI=6: bf16 slab store at z*4194304, K split gridDim.y ways (GEMM3) —
//        bf16 partials halve slab traffic; error ≤0.005 vs 0.079 threshold.
// ---------------------------------------------------------------------------
template <int EPI>
__global__ __launch_bounds__(512, 2) void gemm256_8p(
    const bf16* __restrict__ A, const bf16* __restrict__ B,
    void* __restrict__ C, int M, int N, int K, int lda, int ldb) {
  __shared__ __attribute__((aligned(16))) bf16 SA[2][2][8192];
  __shared__ __attribute__((aligned(16))) bf16 SB[2][2][8192];

  const int tid = threadIdx.x;
  const int wave = tid >> 6;
  const int lane = tid & 63;
  const int lr = lane & 15;
  const int kg = lane >> 4;
  const int wm = (wave >> 2) * 128;  // wave row-block (2)
  const int wn = (wave & 3) * 64;    // wave col-block (4)

  // XCD mapping (measured-fast r5 form): HW XCD = flat%8; tm=bid%8 clusters
  // each A-panel's sharers on one XCD. (EPI=6: flat = x + 64*y keeps
  // xcd = x%8 = tm — same clustering, z-independent.)
  const int tilesM = M >> 8;
  const int tm = blockIdx.x % tilesM;
  const int tn = blockIdx.x / tilesM;
  const int rowBase = tm * 256;
  const int colBase = tn * 256;

  // K-split (EPI=6): z = blockIdx.y
  const int kLen = K / gridDim.y;
  const int k0 = blockIdx.y * kLen;
  const int NT = kLen >> 6;  // K-tiles of 64 (must be even)

  // staging geometry: one global_load_lds = 512 thr x 16 B = 8 KB = 128 rows
  // x 32 k; source k pre-swizzled so linear LDS dest matches ds_read XOR.
  const int srow = tid >> 2;
  const int ske = (tid & 3) << 3;
  const int skel = ske ^ (((srow >> 1) & 3) << 3);
  const size_t aRow0 = (size_t)(rowBase + srow) * lda;
  const size_t aRow1 = aRow0 + (size_t)128 * lda;
  const size_t bRow0 = (size_t)(colBase + srow) * ldb;
  const size_t bRow1 = bRow0 + (size_t)128 * ldb;

  // frag-read swizzled k offset within a [256][32] region
  const int keSh = (kg << 3) ^ (((lr >> 1) & 3) << 3);

  floatx4 acc[8][4] = {};
  bf16x8 af0[4], af1[4], bgA[4], bgB[4];

  auto stA = [&](int buf, int kh, int kt) {
    const int gk = k0 + kt * 64 + kh * 32 + skel;
    bf16* d = &SA[buf][kh][0];
    async16(A + aRow0 + gk, d + tid * 8);
    async16(A + aRow1 + gk, d + 4096 + tid * 8);
  };
  auto stB = [&](int buf, int kh, int kt) {
    const int gk = k0 + kt * 64 + kh * 32 + skel;
    bf16* d = &SB[buf][kh][0];
    async16(B + bRow0 + gk, d + tid * 8);
    async16(B + bRow1 + gk, d + 4096 + tid * 8);
  };

#define RD_B(DST, BUF, KH)                                                     \
  _Pragma("unroll") for (int n = 0; n < 4; ++n)                                \
      DST[n] = *(const bf16x8*)&SB[BUF][KH][(wn + n * 16 + lr) * 32 + keSh];
#define RD_A(DST, BUF, KH, MH)                                                 \
  _Pragma("unroll") for (int m = 0; m < 4; ++m)                                \
      DST[m] =                                                                 \
          *(const bf16x8*)&SA[BUF][KH][(wm + ((MH)*4 + m) * 16 + lr) * 32 +    \
                                       keSh];

  // ---- prologue: stage all 7 half-tiles, FULL drain, pre-read PH1 operands.
  stB(0, 0, 0); stA(0, 0, 0); stB(0, 1, 0); stA(0, 1, 0);
  stB(1, 0, 1); stA(1, 0, 1); stB(1, 1, 1);
  asm volatile("s_waitcnt vmcnt(0)" ::: "memory");
  __builtin_amdgcn_s_barrier();
  RD_B(bgA, 0, 0);
  RD_A(af0, 0, 0, 0);

#define PH(RDS, CNT, STG, BGR, AFR, MH, VM)                                    \
  {                                                                            \
    RDS;                                                                       \
    STG;                                                                       \
    __builtin_amdgcn_s_barrier();                                              \
    asm volatile("s_waitcnt lgkmcnt(" #CNT ")" ::: "memory");                  \
    __builtin_amdgcn_sched_barrier(0);                                         \
    __builtin_amdgcn_s_setprio(1);                                             \
    _Pragma("unroll") for (int m = 0; m < 4; ++m)                              \
      _Pragma("unroll") for (int n = 0; n < 4; ++n)                            \
          acc[(MH)*4 + m][n] = __builtin_amdgcn_mfma_f32_16x16x32_bf16(        \
              AFR[m], BGR[n], acc[(MH)*4 + m][n], 0, 0, 0);                    \
    __builtin_amdgcn_s_setprio(0);                                             \
    __builtin_amdgcn_sched_barrier(0);                                         \
    if constexpr (VM) asm volatile("s_waitcnt vmcnt(2)" ::: "memory");         \
    __builtin_amdgcn_s_barrier();                                              \
  }

  for (int it = 0; it < (NT >> 1); ++it) {
    const int T0 = it * 2;
    const int T1 = T0 + 1;
    const int s1 = (T0 + 2 < NT) ? T0 + 2 : NT - 1;
    const int s2 = (T1 + 2 < NT) ? T1 + 2 : NT - 1;

    PH(RD_A(af1, 0, 0, 1), 4, stA(1, 1, T1), bgA, af0, 0, false)  // PH1
    PH(RD_B(bgB, 0, 1); RD_A(af0, 0, 1, 0), 8, stB(0, 0, s1), bgA, af1, 1,
       false)                                                      // PH2
    PH(RD_A(af1, 0, 1, 1), 4, stA(0, 0, s1), bgB, af0, 0, false)  // PH3
    PH(RD_B(bgA, 1, 0); RD_A(af0, 1, 0, 0), 8, stB(0, 1, s1), bgB, af1, 1,
       true)                                                       // PH4
    PH(RD_A(af1, 1, 0, 1), 4, stA(0, 1, s1), bgA, af0, 0, false)  // PH5
    PH(RD_B(bgB, 1, 1); RD_A(af0, 1, 1, 0), 8, stB(1, 0, s2), bgA, af1, 1,
       false)                                                      // PH6
    PH(RD_A(af1, 1, 1, 1), 4, stA(1, 0, s2), bgB, af0, 0, false)  // PH7
    PH(RD_B(bgA, 0, 0); RD_A(af0, 0, 0, 0), 8, stB(1, 1, s2), bgB, af1, 1,
       true)                                                       // PH8
  }
#undef PH
#undef RD_A
#undef RD_B

  asm volatile("s_waitcnt vmcnt(0) lgkmcnt(0)" ::: "memory");

  // epilogue: C/D layout col = lane&15, row = (lane>>4)*4 + reg  [m89]
#pragma unroll
  for (int m = 0; m < 8; ++m) {
#pragma unroll
    for (int n = 0; n < 4; ++n) {
      const int col = colBase + wn + n * 16 + lr;
#pragma unroll
      for (int r = 0; r < 4; ++r) {
        const int row = rowBase + wm + m * 16 + kg * 4 + r;
        const size_t idx = (size_t)row * N + col;
        if constexpr (EPI == 0) {
          ((bf16*)C)[idx] = (bf16)acc[m][n][r];
        } else {
          ((bf16*)C)[(size_t)blockIdx.y * 4194304 + idx] = (bf16)acc[m][n][r];
        }
      }
    }
  }
}

// ---------------------------------------------------------------------------
// Generic "bt" GEMM: C[M,N] = A[M,K_eff] @ B[N,K_eff]^T with row strides
// lda/ldb (elements). AF/BF: f32 operand (VGPR+cvt+ds_write staging) vs bf16
// (async global_load_lds). TM: 128 (4 waves 2x2 of 64x64) or 64 (4 waves 1x4
// of 64x32). BK=32, 256 thr, mfma_f32_16x16x32_bf16.
// EPI: 0 bf16 store | 1 f32 atomicAdd | 2 bf16 softplus(v+bias) |
//      3 f32 (v+bias) | 4 f32 per-z slab stride 524288 (GEMM2 split-K) |
//      6 bf16 per-z slab stride 4194304 (fallback GEMM3 split-K)
// ---------------------------------------------------------------------------
template <int EPI, int AF, int BF, int TM>
__global__ __launch_bounds__(256, 4) void gemm_bt(
    const void* __restrict__ Aptr, const void* __restrict__ Bptr,
    void* __restrict__ Cout, const float* __restrict__ bias,
    int M, int N, int K, int lda, int ldb) {
  __shared__ bf16 As[TM * 32];
  __shared__ bf16 Bs[128 * 32];
  const int tid = threadIdx.x;

  int bx = blockIdx.x, by = blockIdx.y;
  if constexpr (EPI == 6) {
    const int f = blockIdx.x + gridDim.x * blockIdx.y;
    const int gy = gridDim.y >> 3;
    const int i = f >> 3;
    by = (f & 7) * gy + (i % gy);
    bx = i / gy;
  }
  const int rowBase = bx * TM;
  const int colBase = by * 128;
  const int kLen = K / gridDim.z;
  const int k0 = blockIdx.z * kLen;
  const int kIters = kLen / 32;

  const int sRow = tid >> 2;
  const int sCol = (tid & 3) << 3;
  const int wave = tid >> 6;
  const int lane = tid & 63;
  constexpr int MI = 4;
  constexpr int NJ = (TM == 128) ? 4 : 2;
  const int wm = (TM == 128) ? ((wave >> 1) << 6) : 0;
  const int wn = (TM == 128) ? ((wave & 1) << 6) : (wave << 5);
  const int lr = lane & 15;
  const int kg = lane >> 4;

  floatx4 acc[MI][NJ] = {};

  for (int kt = 0; kt < kIters; ++kt) {
    const int kk = k0 + kt * 32;
    __syncthreads();  // prev iter's LDS reads done before overwrite
    if constexpr (AF) {
      const float* pa =
          (const float*)Aptr + (size_t)(rowBase + sRow) * lda + kk + sCol;
      *(bf16x8*)&As[tid * 8] = cvt8(pa);
      if constexpr (TM == 128)
        *(bf16x8*)&As[2048 + tid * 8] = cvt8(pa + (size_t)64 * lda);
    } else {
      const bf16* pa =
          (const bf16*)Aptr + (size_t)(rowBase + sRow) * lda + kk + sCol;
      async16(pa, &As[tid * 8]);
      if constexpr (TM == 128)
        async16(pa + (size_t)64 * lda, &As[2048 + tid * 8]);
    }
    if constexpr (BF) {
      const float* pb =
          (const float*)Bptr + (size_t)(colBase + sRow) * ldb + kk + sCol;
      *(bf16x8*)&Bs[tid * 8] = cvt8(pb);
      *(bf16x8*)&Bs[2048 + tid * 8] = cvt8(pb + (size_t)64 * ldb);
    } else {
      const bf16* pb =
          (const bf16*)Bptr + (size_t)(colBase + sRow) * ldb + kk + sCol;
      async16(pb, &Bs[tid * 8]);
      async16(pb + (size_t)64 * ldb, &Bs[2048 + tid * 8]);
    }
    __syncthreads();  // staging complete -> tile visible

    bf16x8 af[MI], bg[NJ];
#pragma unroll
    for (int i = 0; i < MI; ++i)
      af[i] = *(const bf16x8*)&As[(wm + i * 16 + lr) * 32 + kg * 8];
#pragma unroll
    for (int j = 0; j < NJ; ++j)
      bg[j] = *(const bf16x8*)&Bs[(wn + j * 16 + lr) * 32 + kg * 8];
#pragma unroll
    for (int i = 0; i < MI; ++i)
#pragma unroll
      for (int j = 0; j < NJ; ++j)
        acc[i][j] = __builtin_amdgcn_mfma_f32_16x16x32_bf16(af[i], bg[j],
                                                            acc[i][j], 0, 0, 0);
  }

  // epilogue: C/D layout col = lane&15, row = (lane>>4)*4 + reg  [m89]
#pragma unroll
  for (int i = 0; i < MI; ++i) {
#pragma unroll
    for (int j = 0; j < NJ; ++j) {
      const int col = colBase + wn + j * 16 + lr;
      float bv = 0.f;
      if constexpr (EPI == 2 || EPI == 3) bv = bias[col];
#pragma unroll
      for (int r = 0; r < 4; ++r) {
        const int row = rowBase + wm + i * 16 + kg * 4 + r;
        const size_t idx = (size_t)row * N + col;
        float v = acc[i][j][r];
        if constexpr (EPI == 0) {
          ((bf16*)Cout)[idx] = (bf16)v;
        } else if constexpr (EPI == 1) {
          atomicAdd((float*)Cout + idx, v);
        } else if constexpr (EPI == 2) {
          v += bv;
          // softplus = ln(1+e^v); for v>20, ln(1+e^v)==v to f32 precision.
          const float t = __expf(v);
          const float sp = (v > 20.f) ? v : __logf(1.f + t);
          ((bf16*)Cout)[idx] = (bf16)sp;
        } else if constexpr (EPI == 3) {
          ((float*)Cout)[idx] = v + bv;
        } else if constexpr (EPI == 4) {
          // split-K partial: distinct slab per z, no contention
          ((float*)Cout)[(size_t)blockIdx.z * 524288 + idx] = v;
        } else {
          ((bf16*)Cout)[(size_t)blockIdx.z * 4194304 + idx] = (bf16)v;
        }
      }
    }
  }
}

// sum 8 split-K partial slabs -> XDBL (2048x256 f32)
__global__ __launch_bounds__(256) void reduce_xdbl(
    const float* __restrict__ part, float* __restrict__ xdbl) {
  const size_t i4 = ((size_t)blockIdx.x * 256 + threadIdx.x) * 4;  // 524288/4
  floatx4 s = {};
#pragma unroll
  for (int z = 0; z < 8; ++z) {
    const floatx4 v = *(const floatx4*)&part[(size_t)z * 524288 + i4];
    s[0] += v[0]; s[1] += v[1]; s[2] += v[2]; s[3] += v[3];
  }
  *(floatx4*)&xdbl[i4] = s;
}

// sum 4 GEMM3 bf16 split-K slabs + bias -> out (2048x2048 f32)
__global__ __launch_bounds__(256) void reduce_out4(
    const bf16* __restrict__ part, const float* __restrict__ bias,
    float* __restrict__ outp) {
  const size_t i4 = ((size_t)blockIdx.x * 256 + threadIdx.x) * 4;  // 4194304/4
  floatx4 s = *(const floatx4*)&bias[i4 & 2047];
#pragma unroll
  for (int z = 0; z < 4; ++z) {
    const bf16x4 v = *(const bf16x4*)&part[(size_t)z * 4194304 + i4];
    s[0] += (float)v[0]; s[1] += (float)v[1];
    s[2] += (float)v[2]; s[3] += (float)v[3];
  }
  *(floatx4*)&outp[i4] = s;
}

// ---------------------------------------------------------------------------
// Fused prep: f32->bf16 casts (hidden|W_in|W_dt|W_out) + W_x pad-cast.
// ---------------------------------------------------------------------------
#define PC0 524288UL    // hidden chunks
#define PC1 2621440UL   // +W_in
#define PC2 2686976UL   // +W_dt
#define PC3 3735552UL   // +W_out
#define PC4 3866624UL   // +WXPAD (dest 256x4096)
__global__ __launch_bounds__(256) void prep_all(
    const float* __restrict__ h, const float* __restrict__ wi,
    const float* __restrict__ wd, const float* __restrict__ wo,
    const float* __restrict__ wx, bf16* __restrict__ hb,
    bf16* __restrict__ wib, bf16* __restrict__ wdb, bf16* __restrict__ wob,
    bf16* __restrict__ wxp) {
  const size_t c = (size_t)blockIdx.x * 256 + threadIdx.x;
  if (c < PC0) {
    const size_t e = c * 8;
    *(bf16x8*)&hb[e] = cvt8(&h[e]);
  } else if (c < PC1) {
    const size_t e = (c - PC0) * 8;
    *(bf16x8*)&wib[e] = cvt8(&wi[e]);
  } else if (c < PC2) {
    const size_t e = (c - PC1) * 8;
    *(bf16x8*)&wdb[e] = cvt8(&wd[e]);
  } else if (c < PC3) {
    const size_t e = (c - PC2) * 8;
    *(bf16x8*)&wob[e] = cvt8(&wo[e]);
  } else if (c < PC4) {
    const size_t e = (c - PC3) * 8;
    if ((e >> 12) < 160) {
      *(bf16x8*)&wxp[e] = cvt8(&wx[e]);
    } else {
      bf16x8 z = {};
      *(bf16x8*)&wxp[e] = z;
    }
  }
}

// W_x pad (fallback path only)
__global__ void wxpad_prep(const float* __restrict__ Wx,
                           bf16* __restrict__ WXPAD) {
  const int idx = blockIdx.x * 256 + threadIdx.x;
  const int row = idx >> 12;
  WXPAD[idx] = (row < 160) ? (bf16)Wx[idx] : (bf16)0.f;
}

// Depthwise causal conv (K=4) + bias + SiLU, x8-vectorized (G13).
__global__ __launch_bounds__(256) void conv_v8(
    const bf16* __restrict__ XZ, const float* __restrict__ conv_w,
    const float* __restrict__ conv_b, bf16* __restrict__ XC,
    float* __restrict__ outConv) {
  const int idx = blockIdx.x * 256 + threadIdx.x;  // 0..1048575
  const int d8 = (idx & 511) << 3;
  const int row = idx >> 9;
  const int l = row & 1023;
  float acc[8];
  {
    const floatx4 cb0 = *(const floatx4*)&conv_b[d8];
    const floatx4 cb1 = *(const floatx4*)&conv_b[d8 + 4];
#pragma unroll
    for (int j = 0; j < 4; ++j) { acc[j] = cb0[j]; acc[4 + j] = cb1[j]; }
  }
  float w[8][4];
#pragma unroll
  for (int j = 0; j < 8; ++j) {
    const floatx4 cw = *(const floatx4*)&conv_w[(d8 + j) * 4];
#pragma unroll
    for (int k = 0; k < 4; ++k) w[j][k] = cw[k];
  }
  if (l >= 3) {  // fast path: all 4 taps valid
#pragma unroll
    for (int k = 0; k < 4; ++k) {
      const bf16x8 x = *(const bf16x8*)&XZ[(size_t)(row - 3 + k) * 8192 + d8];
#pragma unroll
      for (int j = 0; j < 8; ++j) acc[j] += w[j][k] * (float)x[j];
    }
  } else {
#pragma unroll
    for (int k = 0; k < 4; ++k) {
      if (l - 3 + k >= 0) {
        const bf16x8 x = *(const bf16x8*)&XZ[(size_t)(row - 3 + k) * 8192 + d8];
#pragma unroll
        for (int j = 0; j < 8; ++j) acc[j] += w[j][k] * (float)x[j];
      }
    }
  }
  bf16x8 o;
#pragma unroll
  for (int j = 0; j < 8; ++j)
    o[j] = (bf16)(acc[j] / (1.f + __expf(-acc[j])));
  *(bf16x8*)&XC[(size_t)row * 4096 + d8] = o;
  if (idx < 4096) {  // conv_state: out[b,dd,k] = x[b, 1020+k, dd]
#pragma unroll
    for (int j = 0; j < 8; ++j) {
      const int e = idx * 8 + j;  // 0..32767
      const int k = e & 3;
      const int dd = (e >> 2) & 4095;
      const int b = e >> 14;
      outConv[e] = (float)XZ[(size_t)(b * 1024 + 1020 + k) * 8192 + dd];
    }
  }
}

// ---------------------------------------------------------------------------
// Chunked parallel scan (32 chunks of 32). r9: scan1/scan3 process a d-PAIR
// per thread (G13: 4B loads/stores instead of 2B; P/Lc/In accesses become
// 64B/thread contiguous); In is bf16 (consistent with bf16 P/Lc).
// ---------------------------------------------------------------------------
#define NCH 32
#define CLEN 32
#define LOG2E 1.44269504088896f

__global__ __launch_bounds__(256) void scan_phase1(
    const bf16* __restrict__ DELTA, const bf16* __restrict__ XC,
    const float* __restrict__ XDBL, const float* __restrict__ A_log,
    bf16* __restrict__ P, bf16* __restrict__ Lc) {
  const int pd = blockIdx.x * 256 + threadIdx.x;  // 0..4095: (b, d/2)
  const int c = blockIdx.y;
  const int b = pd >> 11;
  const int d = (pd & 2047) << 1;
  const int bd = (b << 12) + d;
  float A2[32], st[32], p[32];
#pragma unroll
  for (int n = 0; n < 32; ++n) {  // n<16: row d; n>=16: row d+1 (contiguous)
    A2[n] = -__expf(A_log[d * 16 + n]) * LOG2E;
    st[n] = 0.f;
    p[n] = 1.f;
  }
  size_t row = (size_t)b * 1024 + (size_t)c * CLEN;
  for (int t = 0; t < CLEN; ++t, ++row) {
    const bf16x2 d2 = *(const bf16x2*)&DELTA[row * 4096 + d];
    const bf16x2 u2 = *(const bf16x2*)&XC[row * 4096 + d];
    const float dlt0 = (float)d2[0], dlt1 = (float)d2[1];
    const float du0 = dlt0 * (float)u2[0], du1 = dlt1 * (float)u2[1];
    const float* __restrict__ Bp = XDBL + row * 256 + 128;  // wave-uniform
#pragma unroll
    for (int n = 0; n < 16; ++n) {
      const float Bv = Bp[n];
      const float dA0 = exp2f(dlt0 * A2[n]);
      st[n] = dA0 * st[n] + du0 * Bv;
      p[n] *= dA0;
      const float dA1 = exp2f(dlt1 * A2[16 + n]);
      st[16 + n] = dA1 * st[16 + n] + du1 * Bv;
      p[16 + n] *= dA1;
    }
  }
  const size_t o = ((size_t)c * 8192 + bd) * 16;  // 32 contiguous elements
  bf16x8 pk[4], lk[4];
#pragma unroll
  for (int n = 0; n < 32; ++n) {
    pk[n >> 3][n & 7] = (bf16)p[n];
    lk[n >> 3][n & 7] = (bf16)st[n];
  }
#pragma unroll
  for (int q = 0; q < 4; ++q) {
    *(bf16x8*)&P[o + q * 8] = pk[q];
    *(bf16x8*)&Lc[o + q * 8] = lk[q];
  }
}

__global__ __launch_bounds__(64) void scan_phase2(
    const bf16* __restrict__ P, const bf16* __restrict__ Lc,
    bf16* __restrict__ In, float* __restrict__ lastOut) {
  // 128 blocks x 64 thr: 4x the CUs for this latency-bound serial kernel.
  const int bd = blockIdx.x * 64 + threadIdx.x;  // 0..8191
  float st[16] = {};
  for (int c = 0; c < NCH; ++c) {
    const size_t o = ((size_t)c * 8192 + bd) * 16;
    const bf16x8 p0 = *(const bf16x8*)&P[o];
    const bf16x8 p1 = *(const bf16x8*)&P[o + 8];
    const bf16x8 l0 = *(const bf16x8*)&Lc[o];
    const bf16x8 l1 = *(const bf16x8*)&Lc[o + 8];
    bf16x8 w0, w1;
#pragma unroll
    for (int n = 0; n < 8; ++n) {
      w0[n] = (bf16)st[n];
      w1[n] = (bf16)st[8 + n];
    }
    *(bf16x8*)&In[o] = w0;
    *(bf16x8*)&In[o + 8] = w1;
#pragma unroll
    for (int n = 0; n < 8; ++n) {
      st[n] = (float)p0[n] * st[n] + (float)l0[n];
      st[8 + n] = (float)p1[n] * st[8 + n] + (float)l1[n];
    }
  }
  const int b = bd >> 12;
  const int d = bd & 4095;
#pragma unroll
  for (int n = 0; n < 16; ++n)
    lastOut[(size_t)b * 65536 + d * 16 + n] = st[n];
}

__global__ __launch_bounds__(256) void scan_phase3(
    const bf16* __restrict__ DELTA, const bf16* __restrict__ XC,
    const bf16* __restrict__ XZ, const float* __restrict__ XDBL,
    const float* __restrict__ A_log, const float* __restrict__ Dp,
    const bf16* __restrict__ In, bf16* __restrict__ Y) {
  const int pd = blockIdx.x * 256 + threadIdx.x;  // 0..4095: (b, d/2)
  const int c = blockIdx.y;
  const int b = pd >> 11;
  const int d = (pd & 2047) << 1;
  const int bd = (b << 12) + d;
  float A2[32], st[32];
  const size_t o = ((size_t)c * 8192 + bd) * 16;
#pragma unroll
  for (int q = 0; q < 4; ++q) {
    const bf16x8 v = *(const bf16x8*)&In[o + q * 8];
#pragma unroll
    for (int j = 0; j < 8; ++j) st[q * 8 + j] = (float)v[j];
  }
#pragma unroll
  for (int n = 0; n < 32; ++n)
    A2[n] = -__expf(A_log[d * 16 + n]) * LOG2E;
  const float Dd0 = Dp[d], Dd1 = Dp[d + 1];
  size_t row = (size_t)b * 1024 + (size_t)c * CLEN;
  for (int t = 0; t < CLEN; ++t, ++row) {
    const bf16x2 d2 = *(const bf16x2*)&DELTA[row * 4096 + d];
    const bf16x2 u2 = *(const bf16x2*)&XC[row * 4096 + d];
    const bf16x2 z2 = *(const bf16x2*)&XZ[row * 8192 + 4096 + d];
    const float dlt0 = (float)d2[0], dlt1 = (float)d2[1];
    const float u0 = (float)u2[0], u1 = (float)u2[1];
    const float du0 = dlt0 * u0, du1 = dlt1 * u1;
    const float* __restrict__ Bp = XDBL + row * 256 + 128;
    float y0 = 0.f, y1 = 0.f;
#pragma unroll
    for (int n = 0; n < 16; ++n) {
      const float Bv = Bp[n];
      const float Cv = Bp[16 + n];
      const float dA0 = exp2f(dlt0 * A2[n]);
      st[n] = dA0 * st[n] + du0 * Bv;
      y0 += st[n] * Cv;
      const float dA1 = exp2f(dlt1 * A2[16 + n]);
      st[16 + n] = dA1 * st[16 + n] + du1 * Bv;
      y1 += st[16 + n] * Cv;
    }
    const float z0 = (float)z2[0], z1 = (float)z2[1];
    const float sig0 = 1.f / (1.f + __expf(-z0));
    const float sig1 = 1.f / (1.f + __expf(-z1));
    bf16x2 yo;
    yo[0] = (bf16)((y0 + Dd0 * u0) * (z0 * sig0));
    yo[1] = (bf16)((y1 + Dd1 * u1) * (z1 * sig1));
    *(bf16x2*)&Y[row * 4096 + d] = yo;
  }
}

// ---------------------------------------------------------------------------
// Workspace layout (bytes). DELTA slot holds bf16 DELTA (lower 16.8 MB) and
// the GEMM2 split-K partials (upper 16.8 MB). After scan_phase3, the entire
// XZ+XC+DELTA+PART region (0..83.9 MB) is dead and is reused as GEMM3's 4
// split-K bf16 slabs (33.5 MB), which never touch Y (GEMM3's input).
// ---------------------------------------------------------------------------
#define OFF_XZ 0UL                 // bf16 2048x8192
#define OFF_XC 33554432UL          // bf16 2048x4096
#define OFF_DELTA 50331648UL       // bf16 2048x4096 | +16777216: PART f32 8x524288
#define OFF_Y 83886080UL           // bf16 2048x4096
#define OFF_XDBL 100663296UL       // f32  2048x256
#define OFF_WXPAD 103284736UL      // bf16 256x4096
#define OFF_P 105381888UL          // bf16 32x8192x16
#define OFF_L 113770496UL          // bf16 32x8192x16
#define OFF_HBF 122159104UL        // bf16 2048x2048
#define OFF_WINBF 130547712UL      // bf16 8192x2048
#define OFF_WDTBF 164102144UL      // bf16 4096x128
#define OFF_WOUTBF 165150720UL     // bf16 2048x4096
#define WS_NEED_CAST 181927936UL   // ~173.5 MB

extern "C" void kernel_launch(void* const* d_in, const int* in_sizes, int n_in,
                              void* d_out, int out_size, void* d_ws,
                              size_t ws_size, hipStream_t stream) {
  const float* hidden = (const float*)d_in[0];
  const float* W_in = (const float*)d_in[1];
  const float* conv_w = (const float*)d_in[2];
  const float* conv_b = (const float*)d_in[3];
  const float* W_x = (const float*)d_in[4];
  const float* W_dt = (const float*)d_in[5];
  const float* b_dt = (const float*)d_in[6];
  const float* A_log = (const float*)d_in[7];
  const float* Dvec = (const float*)d_in[8];
  const float* W_out = (const float*)d_in[9];
  const float* b_out = (const float*)d_in[10];

  char* ws = (char*)d_ws;
  bf16* XZ = (bf16*)(ws + OFF_XZ);
  bf16* XC = (bf16*)(ws + OFF_XC);
  bf16* DELTA = (bf16*)(ws + OFF_DELTA);
  float* PART = (float*)(ws + OFF_DELTA + 16777216UL);
  bf16* SLAB3 = (bf16*)(ws + OFF_XZ);  // 33.5 MB over dead XZ region
  bf16* Y = (bf16*)(ws + OFF_Y);
  float* XDBL = (float*)(ws + OFF_XDBL);
  bf16* WXPAD = (bf16*)(ws + OFF_WXPAD);
  bf16* P = (bf16*)(ws + OFF_P);
  bf16* Lc = (bf16*)(ws + OFF_L);

  float* out = (float*)d_out;             // (2,1024,2048) = 4194304 f32
  float* out_conv = out + 4194304;        // (2,4096,4)
  float* out_last = out + 4227072;        // (2,4096,16)
  // In (bf16, 8.4 MB) parks in the `out` region: written by phase2, read by
  // phase3, then fully overwritten by reduce_out4 (same-stream ordering).
  bf16* In = (bf16*)out;

  const bool castOK = ws_size >= WS_NEED_CAST;
  if (castOK) {
    bf16* HBF = (bf16*)(ws + OFF_HBF);
    bf16* WINBF = (bf16*)(ws + OFF_WINBF);
    bf16* WDTBF = (bf16*)(ws + OFF_WDTBF);
    bf16* WOUTBF = (bf16*)(ws + OFF_WOUTBF);
    prep_all<<<15104, 256, 0, stream>>>(hidden, W_in, W_dt, W_out, W_x, HBF,
                                        WINBF, WDTBF, WOUTBF, WXPAD);
    // GEMM1: XZ = HBF @ WINBF^T — 8-phase 256^2 engine, 256 WGs (1/CU)
    gemm256_8p<0><<<dim3(256, 1), 512, 0, stream>>>(HBF, WINBF, XZ, 2048,
                                                    8192, 2048, 2048, 2048);
    conv_v8<<<4096, 256, 0, stream>>>(XZ, conv_w, conv_b, XC, out_conv);
    // GEMM2 (split-K=8 -> partial slabs, no atomics): PART[z] = XC @ WXPAD^T
    gemm_bt<4, 0, 0, 64><<<dim3(32, 2, 8), 256, 0, stream>>>(
        XC, WXPAD, PART, nullptr, 2048, 256, 4096, 4096, 4096);
    reduce_xdbl<<<512, 256, 0, stream>>>(PART, XDBL);
    // GEMM_dt (TM=64, A = XDBL dt-cols f32 lda=256): DELTA = softplus(.)
    gemm_bt<2, 1, 0, 64><<<dim3(32, 32, 1), 256, 0, stream>>>(
        XDBL, WDTBF, DELTA, b_dt, 2048, 4096, 128, 256, 128);
    scan_phase1<<<dim3(16, NCH), 256, 0, stream>>>(DELTA, XC, XDBL, A_log, P,
                                                   Lc);
    scan_phase2<<<128, 64, 0, stream>>>(P, Lc, In, out_last);
    scan_phase3<<<dim3(16, NCH), 256, 0, stream>>>(DELTA, XC, XZ, XDBL, A_log,
                                                   Dvec, In, Y);
    // GEMM3 on the 8-phase engine, split-K=4 via blockIdx.y (64 tiles x 4 z
    // = 256 WGs, kLen=1024, NT=16): bf16 SLAB3[z] = Y @ WOUTBF^T quarters;
    // reduce_out4 sums + bias -> out.
    gemm256_8p<6><<<dim3(64, 4), 512, 0, stream>>>(Y, WOUTBF, SLAB3, 2048,
                                                   2048, 4096, 4096, 4096);
    reduce_out4<<<4096, 256, 0, stream>>>(SLAB3, b_out, out);
  } else {
    // fallback: f32-staged GEMMs, no cast buffers
    wxpad_prep<<<4096, 256, 0, stream>>>(W_x, WXPAD);
    gemm_bt<0, 1, 1, 128><<<dim3(16, 64, 1), 256, 0, stream>>>(
        hidden, W_in, XZ, nullptr, 2048, 8192, 2048, 2048, 2048);
    conv_v8<<<4096, 256, 0, stream>>>(XZ, conv_w, conv_b, XC, out_conv);
    gemm_bt<4, 0, 0, 64><<<dim3(32, 2, 8), 256, 0, stream>>>(
        XC, WXPAD, PART, nullptr, 2048, 256, 4096, 4096, 4096);
    reduce_xdbl<<<512, 256, 0, stream>>>(PART, XDBL);
    gemm_bt<2, 1, 1, 64><<<dim3(32, 32, 1), 256, 0, stream>>>(
        XDBL, W_dt, DELTA, b_dt, 2048, 4096, 128, 256, 128);
    scan_phase1<<<dim3(16, NCH), 256, 0, stream>>>(DELTA, XC, XDBL, A_log, P,
                                                   Lc);
    scan_phase2<<<128, 64, 0, stream>>>(P, Lc, In, out_last);
    scan_phase3<<<dim3(16, NCH), 256, 0, stream>>>(DELTA, XC, XZ, XDBL, A_log,
                                                   Dvec, In, Y);
    gemm_bt<6, 0, 1, 128><<<dim3(16, 16, 4), 256, 0, stream>>>(
        Y, W_out, SLAB3, nullptr, 2048, 2048, 4096, 4096, 4096);
    reduce_out4<<<4096, 256, 0, stream>>>(SLAB3, b_out, out);
  }
}